// Round 14
// baseline (2459.704 us; speedup 1.0000x reference)
//
#include <hip/hip_runtime.h>
#include <hip/hip_bf16.h>
#include <math.h>

typedef __bf16 bf16;
typedef bf16 bf16x8 __attribute__((ext_vector_type(8)));
typedef float f32x4 __attribute__((ext_vector_type(4)));

#define NPT 1365
#define HD 512
#define NINT 341   // internal nodes per tree (256+64+16+4+1)
#define IOU_LDS (2*192*64*2)                // 49152 B (B tiles only) -> 2+ blocks/CU
#define G128_LDS (2*128*64*2 + 2*128*64*2)  // 65536 B -> 2 blocks/CU

__device__ __forceinline__ float sigm(float x){ return 1.0f/(1.0f+__expf(-x)); }

__device__ __forceinline__ void gll16(const void* g, void* l){
  __builtin_amdgcn_global_load_lds((const __attribute__((address_space(1))) void*)g,
                                   (__attribute__((address_space(3))) void*)l, 16, 0, 0);
}

// ---------------- split fp32 -> bf16 hi/lo, 8 elems/thread ----------------
__global__ void k_split8(const float* __restrict__ s, bf16* __restrict__ hi,
                         bf16* __restrict__ lo, size_t n8){
  size_t i=(size_t)blockIdx.x*blockDim.x+threadIdx.x;
  if(i>=n8) return;
  const float4* sp=(const float4*)(s+i*8);
  float4 a=sp[0], b=sp[1];
  float v[8]={a.x,a.y,a.z,a.w,b.x,b.y,b.z,b.w};
  bf16x8 h,l;
  #pragma unroll
  for(int e=0;e<8;++e){ bf16 hh=(bf16)v[e]; h[e]=hh; l[e]=(bf16)(v[e]-(float)hh); }
  *(bf16x8*)(hi+i*8)=h;
  *(bf16x8*)(lo+i*8)=l;
}

// ---------------- generic [hi|lo] row concat ----------------
__global__ void k_catHL(const float* __restrict__ S, bf16* __restrict__ d,
                        int rows, int Ksrc){
  size_t i=(size_t)blockIdx.x*blockDim.x+threadIdx.x;
  int K=2*Ksrc;
  size_t tot=(size_t)rows*K;
  if(i>=tot) return;
  int r=(int)(i/K); int k=(int)(i-(size_t)r*K);
  float v=S[(size_t)r*Ksrc + (k<Ksrc?k:k-Ksrc)];
  bf16 h=(bf16)v;
  d[i]=(k<Ksrc)? h : (bf16)(v-(float)h);
}

// ---------------- gate-interleaved iou weights ----------------
__global__ void k_wil(const float* __restrict__ W, const float* __restrict__ U,
                      bf16* __restrict__ d, int internal){
  const int K = internal? 3840 : 2304;
  size_t i=(size_t)blockIdx.x*blockDim.x+threadIdx.x;
  size_t tot=(size_t)1536*K;
  if(i>=tot) return;
  int rp=(int)(i/K); int k=(int)(i-(size_t)rp*K);
  int f=rp>>4, rr=rp&15;
  int g=f%3, cgrp=f/3;
  int orig=g*512+cgrp*16+rr;
  float v; int lo=0;
  if(internal){
    if(k<768)        v=W[(size_t)orig*768+k];
    else if(k<1536)  v=W[(size_t)orig*768+(k-768)];
    else if(k<2048)  v=U[(size_t)orig*512+(k-1536)];
    else if(k<2560)  v=U[(size_t)orig*512+(k-2048)];
    else if(k<3328){ v=W[(size_t)orig*768+(k-2560)]; lo=1; }
    else           { v=U[(size_t)orig*512+(k-3328)]; lo=1; }
  }else{
    int kk=(k<768)?k:((k<1536)?k-768:k-1536);
    v=W[(size_t)orig*768+kk];
    lo=(k>=1536);
  }
  bf16 h=(bf16)v;
  d[i]= lo ? (bf16)(v-(float)h) : h;
}

// ---------------- old-layout concat K=3840 (level-5 64-tile iou only) ----------------
__global__ void k_concatHL3840(const float* __restrict__ W, const float* __restrict__ U,
                               bf16* __restrict__ d, int rows){
  size_t i=(size_t)blockIdx.x*blockDim.x+threadIdx.x;
  const int K=3840;
  size_t tot=(size_t)rows*K;
  if(i>=tot) return;
  int r=(int)(i/K); int k=(int)(i-(size_t)r*K);
  float v; int lo=0;
  if(k<768)        v=W[(size_t)r*768+k];
  else if(k<1536)  v=W[(size_t)r*768+(k-768)];
  else if(k<2048)  v=U[(size_t)r*512+(k-1536)];
  else if(k<2560)  v=U[(size_t)r*512+(k-2048)];
  else if(k<3328){ v=W[(size_t)r*768+(k-2560)]; lo=1; }
  else           { v=U[(size_t)r*512+(k-3328)]; lo=1; }
  bf16 h=(bf16)v;
  d[i]= lo ? (bf16)(v-(float)h) : h;
}

// ---------------- Wcomb = W_sd2 @ W_sd  (512x512, fp32 exact) ----------------
__global__ __launch_bounds__(256)
void k_wcomb(const float* __restrict__ W2, const float* __restrict__ W1,
             float* __restrict__ out){
  __shared__ float As[64][33];
  __shared__ float Bs[32][65];
  const int tid=threadIdx.x;
  const int i0=blockIdx.x*64, j0=blockIdx.y*64;
  const int tr=(tid>>4)*4, tc=(tid&15)*4;
  float acc[4][4];
  #pragma unroll
  for(int x=0;x<4;++x)
    #pragma unroll
    for(int y=0;y<4;++y) acc[x][y]=0.f;
  for(int k0=0;k0<1024;k0+=32){
    for(int l=tid;l<64*32;l+=256){ int r=l>>5,c=l&31; As[r][c]=W2[(size_t)(i0+r)*1024+k0+c]; }
    for(int l=tid;l<32*64;l+=256){ int r=l>>6,c=l&63; Bs[r][c]=W1[(size_t)(k0+r)*512+j0+c]; }
    __syncthreads();
    #pragma unroll 8
    for(int k=0;k<32;++k){
      float a[4],b[4];
      #pragma unroll
      for(int x=0;x<4;++x){ a[x]=As[tr+x][k]; b[x]=Bs[k][tc+x]; }
      #pragma unroll
      for(int x=0;x<4;++x)
        #pragma unroll
        for(int y=0;y<4;++y) acc[x][y]+=a[x]*b[y];
    }
    __syncthreads();
  }
  #pragma unroll
  for(int x=0;x<4;++x)
    #pragma unroll
    for(int y=0;y<4;++y) out[(size_t)(i0+tr+x)*512+j0+tc+y]=acc[x][y];
}

// ---------------- Wy[j,c] = Wsf[j,c] + sum_d Wsf[j,d]*Wcomb[d,c] ----------------
__global__ void k_wy(const float* __restrict__ Wsf, const float* __restrict__ Wcomb,
                     float* __restrict__ Wy){
  int idx=blockIdx.x*256+threadIdx.x;
  if(idx>=2048) return;
  int j=idx>>9, c=idx&511;
  float s=Wsf[j*512+c];
  for(int d=0;d<512;++d) s+=Wsf[j*512+d]*Wcomb[(size_t)d*512+c];
  Wy[(size_t)j*512+c]=s;
}

// ================= iou GEMM: 128 x 192, A in registers (global->reg), B via LDS dbuf =================
__global__ __launch_bounds__(256,2)
void k_iou128p(const bf16* __restrict__ fH, const bf16* __restrict__ fL,
               const bf16* __restrict__ hsH, const bf16* __restrict__ hsL,
               const bf16* __restrict__ Wil, const float* __restrict__ bias,
               const float* __restrict__ csum, bf16* __restrict__ hbuf,
               bf16* __restrict__ hlo, float* __restrict__ cbuf,
               int start_n, int shift, int internal)
{
  extern __shared__ char sm[];                 // B only: 2 x 24576
  char* Bbase=sm;
  const int tid=threadIdx.x;
  const int w=tid>>6, lane=tid&63;             // 4 waves (2M x 2N)
  const int m0=blockIdx.y*128, x=blockIdx.x;
  const int K = internal? 3840 : 2304;
  const int NT = K>>6;

  const int wr=(w>>1)*64;
  const int wcF=(w&1)*6;
  const int lr=lane&15, lg=lane>>4;

  // per-lane A fragment row bases (element offsets into fH/fL or hsH/hsL)
  unsigned aF[4], aH[4];
  #pragma unroll
  for(int mi=0;mi<4;++mi){
    int m=m0+wr+mi*16+lr;
    int t_=m>>shift, j=m-(t_<<shift);
    aF[mi]=(unsigned)(((size_t)t_*NPT+start_n+j)*768);
    aH[mi]=(unsigned)m*512u;
  }
  const unsigned acol=(unsigned)(lg*8);

  unsigned bofs[6];
  #pragma unroll
  for(int i=0;i<6;++i){
    int r=x*192+w*48+i*8+(lane>>3);
    bofs[i]=(unsigned)r*(unsigned)K;
  }
  const unsigned swz=8u*((unsigned)(lane&7)^(unsigned)(lane>>3));

  f32x4 acc[4][6];
  #pragma unroll
  for(int mi=0;mi<4;++mi)
    #pragma unroll
    for(int ni=0;ni<6;++ni) acc[mi][ni]=(f32x4){0.f,0.f,0.f,0.f};

  bf16x8 avA[4][2], avB[4][2];

  auto MAP=[&](int t, const bf16*& base, unsigned& kofs, bool& useF){
    if(internal){
      if(t<12){ base=fH; kofs=(unsigned)t*64u; useF=true; }
      else if(t<24){ base=fL; kofs=(unsigned)(t-12)*64u; useF=true; }
      else if(t<32){ base=hsH; kofs=(unsigned)(t-24)*64u; useF=false; }
      else if(t<40){ base=hsL; kofs=(unsigned)(t-32)*64u; useF=false; }
      else if(t<52){ base=fH; kofs=(unsigned)(t-40)*64u; useF=true; }
      else        { base=hsH; kofs=(unsigned)(t-52)*64u; useF=false; }
    }else{
      if(t<12){ base=fH; kofs=(unsigned)t*64u; useF=true; }
      else if(t<24){ base=fL; kofs=(unsigned)(t-12)*64u; useF=true; }
      else        { base=fH; kofs=(unsigned)(t-24)*64u; useF=true; }
    }
  };

  auto LOADA=[&](bf16x8 (&av)[4][2], int t){
    const bf16* base; unsigned kofs; bool useF;
    MAP(t,base,kofs,useF);
    #pragma unroll
    for(int mi=0;mi<4;++mi){
      const unsigned ro=(useF?aF[mi]:aH[mi])+kofs+acol;
      av[mi][0]=*(const bf16x8*)(base+ro);
      av[mi][1]=*(const bf16x8*)(base+ro+32u);
    }
  };

  auto STAGEB=[&](int buf, int t){
    const unsigned bk=(unsigned)t*64u+swz;
    char* Bd=Bbase+(size_t)buf*24576;
    #pragma unroll
    for(int i=0;i<6;++i)
      gll16(Wil+bofs[i]+bk, Bd+(w*48+i*8)*128);
  };

  auto COMPUTE=[&](int cur, bf16x8 (&av)[4][2]){
    const char* Bb=Bbase+(size_t)cur*24576;
    #pragma unroll
    for(int ks=0;ks<2;++ks){
      const unsigned cb=((unsigned)(ks*64+lg*16)) ^ ((unsigned)(lr&7)<<4);
      bf16x8 bv[6];
      #pragma unroll
      for(int ni=0;ni<6;++ni)
        bv[ni]=*(const bf16x8*)(Bb+(unsigned)((wcF+ni)*16+lr)*128u+cb);
      #pragma unroll
      for(int ni=0;ni<6;++ni)
        #pragma unroll
        for(int mi=0;mi<4;++mi)
          acc[mi][ni]=__builtin_amdgcn_mfma_f32_16x16x32_bf16(av[mi][ks],bv[ni],acc[mi][ni],0,0,0);
    }
  };

  // prologue
  LOADA(avA,0);
  STAGEB(0,0);
  STAGEB(1,1);
  asm volatile("s_waitcnt vmcnt(6)" ::: "memory");   // avA + B(0) done; B(1) in flight
  __builtin_amdgcn_s_barrier();
  __builtin_amdgcn_sched_barrier(0);

  for(int t=0;t<NT;t+=2){
    // ---- tile t (buf0, avA); prefetch avB for t+1 ----
    LOADA(avB, t+1);
    __builtin_amdgcn_sched_barrier(0);
    COMPUTE(0, avA);
    __builtin_amdgcn_sched_barrier(0);
    __builtin_amdgcn_s_barrier();                    // WAR buf0
    __builtin_amdgcn_sched_barrier(0);
    if(t+2<NT){
      STAGEB(0, t+2);
      asm volatile("s_waitcnt vmcnt(6)" ::: "memory"); // avB + B(t+1) done
    }else{
      asm volatile("s_waitcnt vmcnt(0)" ::: "memory");
    }
    __builtin_amdgcn_s_barrier();                    // RAW B(t+1)
    __builtin_amdgcn_sched_barrier(0);

    // ---- tile t+1 (buf1, avB); prefetch avA for t+2 ----
    if(t+2<NT) LOADA(avA, t+2);
    __builtin_amdgcn_sched_barrier(0);
    COMPUTE(1, avB);
    if(t+2<NT){
      __builtin_amdgcn_sched_barrier(0);
      __builtin_amdgcn_s_barrier();                  // WAR buf1
      __builtin_amdgcn_sched_barrier(0);
      if(t+3<NT){
        STAGEB(1, t+3);
        asm volatile("s_waitcnt vmcnt(6)" ::: "memory"); // avA + B(t+2) done
      }else{
        asm volatile("s_waitcnt vmcnt(0)" ::: "memory");
      }
      __builtin_amdgcn_s_barrier();                  // RAW B(t+2)
      __builtin_amdgcn_sched_barrier(0);
    }
  }

  // epilogue (identical geometry to R13)
  #pragma unroll
  for(int mi=0;mi<4;++mi){
    #pragma unroll
    for(int cg=0;cg<2;++cg){
      const int col = x*64 + ((w&1)*2+cg)*16 + lr;
      const float bi=bias[col], bo=bias[col+512], bu=bias[col+1024];
      #pragma unroll
      for(int r=0;r<4;++r){
        const int mm=m0+wr+mi*16+lg*4+r;
        float iv=acc[mi][3*cg+0][r]+bi;
        float ov=acc[mi][3*cg+1][r]+bo;
        float uv=acc[mi][3*cg+2][r]+bu;
        float cn=sigm(iv)*tanhf(uv);
        if(internal) cn+=csum[(size_t)mm*HD+col];
        float hn=sigm(ov)*tanhf(cn);
        const int tt=mm>>shift, jj=mm-(tt<<shift);
        const size_t nd=((size_t)tt*NPT+start_n+jj)*HD+col;
        cbuf[nd]=cn;
        bf16 hh=(bf16)hn;
        hbuf[nd]=hh;
        hlo[nd]=(bf16)(hn-(float)hh);
      }
    }
  }
}

// ---------------- old 64-tile iou (level 5 only, P=64; K=3840 layout) ----------------
__global__ __launch_bounds__(256)
void k_iou(const bf16* __restrict__ fH, const bf16* __restrict__ fL,
           const bf16* __restrict__ hsH, const bf16* __restrict__ hsL,
           const bf16* __restrict__ Wcat, const float* __restrict__ bias,
           const float* __restrict__ csum, bf16* __restrict__ hbuf,
           bf16* __restrict__ hlo, float* __restrict__ cbuf,
           int start_n, int shift, int K, int KB, int internal)
{
  __shared__ bf16 As[64][40];
  __shared__ bf16 Bs[3][64][40];
  const int tid=threadIdx.x;
  const int m0=blockIdx.x*64, n0=blockIdx.y*64;
  const int srow=tid>>2, skc=(tid&3)*8;
  const int m=m0+srow;
  const int t=m>>shift, j=m-(t<<shift);
  const size_t frow=((size_t)t*NPT+start_n+j)*768;
  const bf16* aFH=fH+frow;
  const bf16* aFL=fL+frow;
  const bf16* aHH=hsH+(size_t)m*HD;
  const bf16* aHL=hsL+(size_t)m*HD;
  const bf16* bp0=Wcat+(size_t)(n0+srow)*KB;
  const bf16* bp1=Wcat+(size_t)(512+n0+srow)*KB;
  const bf16* bp2=Wcat+(size_t)(1024+n0+srow)*KB;

  f32x4 acc[3][2][2];
  #pragma unroll
  for(int g=0;g<3;++g)
    #pragma unroll
    for(int mi=0;mi<2;++mi)
      #pragma unroll
      for(int ni=0;ni<2;++ni) acc[g][mi][ni]=(f32x4){0.f,0.f,0.f,0.f};

  const int w=tid>>6, lane=tid&63;
  const int wr=(w>>1)*32, wc=(w&1)*32;
  const int lr=lane&15, lg=lane>>4;

  for(int k0=0;k0<K;k0+=32){
    const bf16* ap;
    if(internal){
      if(k0<768)        ap=aFH+k0;
      else if(k0<1536)  ap=aFL+(k0-768);
      else if(k0<2048)  ap=aHH+(k0-1536);
      else if(k0<2560)  ap=aHL+(k0-2048);
      else if(k0<3328)  ap=aFH+(k0-2560);
      else              ap=aHH+(k0-3328);
    }else{
      ap=(k0<768)? (aFH+k0) : ((k0<1536)? (aFL+(k0-768)) : (aFH+(k0-1536)));
    }
    *(bf16x8*)&As[srow][skc]=*(const bf16x8*)(ap+skc);
    *(bf16x8*)&Bs[0][srow][skc]=*(const bf16x8*)(bp0+k0+skc);
    *(bf16x8*)&Bs[1][srow][skc]=*(const bf16x8*)(bp1+k0+skc);
    *(bf16x8*)&Bs[2][srow][skc]=*(const bf16x8*)(bp2+k0+skc);
    __syncthreads();
    bf16x8 a0=*(bf16x8*)&As[wr+lr][lg*8];
    bf16x8 a1=*(bf16x8*)&As[wr+16+lr][lg*8];
    #pragma unroll
    for(int g=0;g<3;++g){
      #pragma unroll
      for(int ni=0;ni<2;++ni){
        bf16x8 bv=*(bf16x8*)&Bs[g][wc+ni*16+lr][lg*8];
        acc[g][0][ni]=__builtin_amdgcn_mfma_f32_16x16x32_bf16(a0,bv,acc[g][0][ni],0,0,0);
        acc[g][1][ni]=__builtin_amdgcn_mfma_f32_16x16x32_bf16(a1,bv,acc[g][1][ni],0,0,0);
      }
    }
    __syncthreads();
  }

  #pragma unroll
  for(int mi=0;mi<2;++mi){
    #pragma unroll
    for(int ni=0;ni<2;++ni){
      const int col=n0+wc+ni*16+lr;
      const float bi=bias[col], bo=bias[col+512], bu=bias[col+1024];
      #pragma unroll
      for(int r=0;r<4;++r){
        const int mm=m0+wr+mi*16+lg*4+r;
        float iv=acc[0][mi][ni][r]+bi;
        float ov=acc[1][mi][ni][r]+bo;
        float uv=acc[2][mi][ni][r]+bu;
        float cn=sigm(iv)*tanhf(uv);
        if(internal) cn+=csum[(size_t)mm*HD+col];
        float hn=sigm(ov)*tanhf(cn);
        const int tt=mm>>shift, jj=mm-(tt<<shift);
        const size_t nd=((size_t)tt*NPT+start_n+jj)*HD+col;
        cbuf[nd]=cn;
        bf16 hh=(bf16)hn;
        hbuf[nd]=hh;
        hlo[nd]=(bf16)(hn-(float)hh);
      }
    }
  }
}

// ================= XWf: pipelined 128x128 (NT=36: fH·Whi, fH·Wlo, fL·Whi) =================
__global__ __launch_bounds__(256,2)
void k_xwf128p(const bf16* __restrict__ fH, const bf16* __restrict__ fL,
               const bf16* __restrict__ Wfc, float* __restrict__ XWf, int Mtot)
{
  extern __shared__ char sm[];     // A: 2x16384, B: 2x16384
  char* Abase=sm;
  char* Bbase=sm+32768;
  const int tid=threadIdx.x;
  const int w=tid>>6, lane=tid&63;
  const int m0=blockIdx.y*128, n0=blockIdx.x*128;
  const int NT=36;

  unsigned fofs[4];
  #pragma unroll
  for(int i=0;i<4;++i){
    int r=w*32+i*8+(lane>>3);
    int m=m0+r; if(m>=Mtot) m=Mtot-1;
    int t=m/NINT; int j=1024+(m-t*NINT);
    fofs[i]=(unsigned)(((size_t)t*NPT+j)*768);
  }
  unsigned bofs[4];
  #pragma unroll
  for(int i=0;i<4;++i){
    int r=n0+w*32+i*8+(lane>>3);
    bofs[i]=(unsigned)r*1536u;
  }
  const unsigned swz=8u*((unsigned)(lane&7)^(unsigned)(lane>>3));

  f32x4 acc[4][4];
  #pragma unroll
  for(int mi=0;mi<4;++mi)
    #pragma unroll
    for(int ni=0;ni<4;++ni) acc[mi][ni]=(f32x4){0.f,0.f,0.f,0.f};

  const int wr=(w>>1)*64, wc=(w&1)*64;
  const int lr=lane&15, lg=lane>>4;

  auto STAGE=[&](int buf, int t){
    const bf16* Abuf; unsigned ak, bk;
    if(t<12){ Abuf=fH; ak=(unsigned)t*64u; bk=(unsigned)t*64u; }
    else if(t<24){ Abuf=fH; ak=(unsigned)(t-12)*64u; bk=768u+(unsigned)(t-12)*64u; }
    else { Abuf=fL; ak=(unsigned)(t-24)*64u; bk=(unsigned)(t-24)*64u; }
    char* Ad=Abase+(size_t)buf*16384;
    #pragma unroll
    for(int i=0;i<4;++i)
      gll16(Abuf+fofs[i]+ak+swz, Ad+(w*32+i*8)*128);
    char* Bd=Bbase+(size_t)buf*16384;
    #pragma unroll
    for(int i=0;i<4;++i)
      gll16(Wfc+bofs[i]+bk+swz, Bd+(w*32+i*8)*128);
  };

  auto COMPUTE=[&](int cur){
    const char* Ab=Abase+(size_t)cur*16384;
    const char* Bb=Bbase+(size_t)cur*16384;
    #pragma unroll
    for(int ks=0;ks<2;++ks){
      const unsigned cb=((unsigned)(ks*64+lg*16)) ^ ((unsigned)(lr&7)<<4);
      bf16x8 av[4], bv[4];
      #pragma unroll
      for(int mi=0;mi<4;++mi)
        av[mi]=*(const bf16x8*)(Ab+(unsigned)(wr+mi*16+lr)*128u+cb);
      #pragma unroll
      for(int ni=0;ni<4;++ni)
        bv[ni]=*(const bf16x8*)(Bb+(unsigned)((wc+ni*16)+lr)*128u+cb);
      #pragma unroll
      for(int ni=0;ni<4;++ni)
        #pragma unroll
        for(int mi=0;mi<4;++mi)
          acc[mi][ni]=__builtin_amdgcn_mfma_f32_16x16x32_bf16(av[mi],bv[ni],acc[mi][ni],0,0,0);
    }
  };

  STAGE(0,0);
  STAGE(1,1);
  asm volatile("s_waitcnt vmcnt(8)" ::: "memory");
  __builtin_amdgcn_s_barrier();
  __builtin_amdgcn_sched_barrier(0);

  for(int t=0;t<NT;++t){
    COMPUTE(t&1);
    if(t+1<NT){
      __builtin_amdgcn_sched_barrier(0);
      __builtin_amdgcn_s_barrier();
      __builtin_amdgcn_sched_barrier(0);
      if(t+2<NT){
        STAGE(t&1, t+2);
        asm volatile("s_waitcnt vmcnt(8)" ::: "memory");
      }else{
        asm volatile("s_waitcnt vmcnt(0)" ::: "memory");
      }
      __builtin_amdgcn_s_barrier();
      __builtin_amdgcn_sched_barrier(0);
    }
  }

  #pragma unroll
  for(int mi=0;mi<4;++mi){
    #pragma unroll
    for(int ni=0;ni<4;++ni){
      const int col=n0+wc+ni*16+lr;
      #pragma unroll
      for(int r=0;r<4;++r){
        const int mm=m0+wr+mi*16+lg*4+r;
        if(mm<Mtot) XWf[(size_t)mm*512+col]=acc[mi][ni][r];
      }
    }
  }
}

// ================= Uh forget-gate: pipelined 128x128 (NT=24) + fused csum/hsum epilogue =================
__global__ __launch_bounds__(256,2)
void k_uh128p(const bf16* __restrict__ hhi, const bf16* __restrict__ hlo,
              const bf16* __restrict__ Ufc, const float* __restrict__ bias,
              const float* __restrict__ XWf, const float* __restrict__ cbuf,
              float* __restrict__ csum, bf16* __restrict__ hs_hi, bf16* __restrict__ hs_lo,
              int start_ch, int lc, int xwoff)
{
  extern __shared__ char sm[];     // A: 2x16384, B: 2x16384
  char* Abase=sm;
  char* Bbase=sm+32768;
  const int tid=threadIdx.x;
  const int w=tid>>6, lane=tid&63;
  const int e0=blockIdx.y*128, n0=blockIdx.x*128;
  const int NT=24;

  unsigned hofs[4];
  #pragma unroll
  for(int i=0;i<4;++i){
    int r=w*32+i*8+(lane>>3);
    int e=e0+r;
    int t=e>>lc, ei=e-(t<<lc);
    hofs[i]=(unsigned)(((size_t)t*NPT+start_ch+ei)*HD);
  }
  unsigned bofs[4];
  #pragma unroll
  for(int i=0;i<4;++i){
    int r=n0+w*32+i*8+(lane>>3);
    bofs[i]=(unsigned)r*1024u;
  }
  const unsigned swz=8u*((unsigned)(lane&7)^(unsigned)(lane>>3));

  f32x4 acc[4][4];
  #pragma unroll
  for(int mi=0;mi<4;++mi)
    #pragma unroll
    for(int ni=0;ni<4;++ni) acc[mi][ni]=(f32x4){0.f,0.f,0.f,0.f};

  const int wr=(w>>1)*64, wc=(w&1)*64;
  const int lr=lane&15, lg=lane>>4;

  auto STAGE=[&](int buf, int t){
    const bf16* Abuf; unsigned ak, bk;
    if(t<8){ Abuf=hhi; ak=(unsigned)t*64u; bk=(unsigned)t*64u; }
    else if(t<16){ Abuf=hhi; ak=(unsigned)(t-8)*64u; bk=512u+(unsigned)(t-8)*64u; }
    else { Abuf=hlo; ak=(unsigned)(t-16)*64u; bk=(unsigned)(t-16)*64u; }
    char* Ad=Abase+(size_t)buf*16384;
    #pragma unroll
    for(int i=0;i<4;++i)
      gll16(Abuf+hofs[i]+ak+swz, Ad+(w*32+i*8)*128);
    char* Bd=Bbase+(size_t)buf*16384;
    #pragma unroll
    for(int i=0;i<4;++i)
      gll16(Ufc+bofs[i]+bk+swz, Bd+(w*32+i*8)*128);
  };

  auto COMPUTE=[&](int cur){
    const char* Ab=Abase+(size_t)cur*16384;
    const char* Bb=Bbase+(size_t)cur*16384;
    #pragma unroll
    for(int ks=0;ks<2;++ks){
      const unsigned cb=((unsigned)(ks*64+lg*16)) ^ ((unsigned)(lr&7)<<4);
      bf16x8 av[4], bv[4];
      #pragma unroll
      for(int mi=0;mi<4;++mi)
        av[mi]=*(const bf16x8*)(Ab+(unsigned)(wr+mi*16+lr)*128u+cb);
      #pragma unroll
      for(int ni=0;ni<4;++ni)
        bv[ni]=*(const bf16x8*)(Bb+(unsigned)((wc+ni*16)+lr)*128u+cb);
      #pragma unroll
      for(int ni=0;ni<4;++ni)
        #pragma unroll
        for(int mi=0;mi<4;++mi)
          acc[mi][ni]=__builtin_amdgcn_mfma_f32_16x16x32_bf16(av[mi],bv[ni],acc[mi][ni],0,0,0);
    }
  };

  STAGE(0,0);
  STAGE(1,1);
  asm volatile("s_waitcnt vmcnt(8)" ::: "memory");
  __builtin_amdgcn_s_barrier();
  __builtin_amdgcn_sched_barrier(0);

  for(int t=0;t<NT;++t){
    COMPUTE(t&1);
    if(t+1<NT){
      __builtin_amdgcn_sched_barrier(0);
      __builtin_amdgcn_s_barrier();
      __builtin_amdgcn_sched_barrier(0);
      if(t+2<NT){
        STAGE(t&1, t+2);
        asm volatile("s_waitcnt vmcnt(8)" ::: "memory");
      }else{
        asm volatile("s_waitcnt vmcnt(0)" ::: "memory");
      }
      __builtin_amdgcn_s_barrier();
      __builtin_amdgcn_sched_barrier(0);
    }
  }

  #pragma unroll
  for(int mi=0;mi<4;++mi){
    const int ebase=e0+wr+mi*16+lg*4;
    const int tt=ebase>>lc, eib=ebase-(tt<<lc);
    const int inode=tt*NINT + xwoff + (eib>>2);
    const int par=ebase>>2;
    #pragma unroll
    for(int ni=0;ni<4;++ni){
      const int col=n0+wc+ni*16+lr;
      const float base=bias[col]+XWf[(size_t)inode*512+col];
      const size_t chbase=((size_t)tt*NPT+start_ch+eib)*HD+col;
      float s=0.f, hsv=0.f;
      #pragma unroll
      for(int r=0;r<4;++r){
        const size_t ci=chbase+(size_t)r*HD;
        float fv=sigm(acc[mi][ni][r]+base);
        s+=fv*cbuf[ci];
        hsv+=(float)hhi[ci]+(float)hlo[ci];
      }
      csum[(size_t)par*HD+col]=s;
      bf16 hh=(bf16)hsv;
      hs_hi[(size_t)par*HD+col]=hh;
      hs_lo[(size_t)par*HD+col]=(bf16)(hsv-(float)hh);
    }
  }
}

// ---------------- final head ----------------
__global__ __launch_bounds__(256)
void k_final2(const bf16* __restrict__ hhi, const bf16* __restrict__ hlo,
              const float* __restrict__ Wy, const float* __restrict__ gamma,
              const float* __restrict__ beta, float* __restrict__ out0, int Nn)
{
  const int gtid=blockIdx.x*256+threadIdx.x;
  const int node=gtid>>6, lane=gtid&63;
  if(node>=Nn) return;
  const size_t base=(size_t)node*HD+lane*8;
  bf16x8 hv=*(const bf16x8*)(hhi+base);
  bf16x8 lv=*(const bf16x8*)(hlo+base);
  float hf[8];
  #pragma unroll
  for(int e=0;e<8;++e) hf[e]=(float)hv[e]+(float)lv[e];
  float y[4];
  #pragma unroll
  for(int jj=0;jj<4;++jj){
    const float* wp=Wy+jj*HD+lane*8;
    float s=0.f;
    #pragma unroll
    for(int e=0;e<8;++e) s+=hf[e]*wp[e];
    #pragma unroll
    for(int off=32;off>=1;off>>=1) s+=__shfl_xor(s,off,64);
    y[jj]=s;
  }
  if(lane==0){
    float mu=0.25f*(y[0]+y[1]+y[2]+y[3]);
    float var=0.f;
    #pragma unroll
    for(int jj=0;jj<4;++jj){ float d=y[jj]-mu; var+=d*d; }
    var*=0.25f;
    float rs=rsqrtf(var+1e-6f);
    float z[4], zmax=-1e30f;
    #pragma unroll
    for(int jj=0;jj<4;++jj){ z[jj]=(y[jj]-mu)*rs*gamma[jj]+beta[jj]; zmax=fmaxf(zmax,z[jj]); }
    float es=0.f;
    #pragma unroll
    for(int jj=0;jj<4;++jj){ z[jj]=__expf(z[jj]-zmax); es+=z[jj]; }
    float inv=1.f/es;
    #pragma unroll
    for(int jj=0;jj<4;++jj) out0[(size_t)node*4+jj]=z[jj]*inv;
  }
}

// ---------------- root head ----------------
__global__ __launch_bounds__(256)
void k_root(const bf16* __restrict__ hhi, const bf16* __restrict__ hlo,
            const float* __restrict__ Wff, float* __restrict__ out1)
{
  const int gtid=blockIdx.x*256+threadIdx.x;
  const int tt=gtid>>6, lane=gtid&63;
  if(tt>=64) return;
  const size_t base=((size_t)tt*NPT+1364)*HD+lane*8;
  bf16x8 hv=*(const bf16x8*)(hhi+base);
  bf16x8 lv=*(const bf16x8*)(hlo+base);
  float hf[8];
  #pragma unroll
  for(int e=0;e<8;++e) hf[e]=(float)hv[e]+(float)lv[e];
  float y[4];
  #pragma unroll
  for(int jj=0;jj<4;++jj){
    const float* wp=Wff+jj*HD+lane*8;
    float s=0.f;
    #pragma unroll
    for(int e=0;e<8;++e) s+=hf[e]*wp[e];
    #pragma unroll
    for(int off=32;off>=1;off>>=1) s+=__shfl_xor(s,off,64);
    y[jj]=s;
  }
  if(lane==0){
    float zmax=fmaxf(fmaxf(y[0],y[1]),fmaxf(y[2],y[3]));
    float es=0.f, z[4];
    #pragma unroll
    for(int jj=0;jj<4;++jj){ z[jj]=__expf(y[jj]-zmax); es+=z[jj]; }
    float inv=1.f/es;
    #pragma unroll
    for(int jj=0;jj<4;++jj) out1[(size_t)tt*4+jj]=z[jj]*inv;
  }
}

extern "C" void kernel_launch(void* const* d_in, const int* in_sizes, int n_in,
                              void* d_out, int out_size, void* d_ws, size_t ws_size,
                              hipStream_t stream)
{
  const float* features=(const float*)d_in[0];
  const float* W_iou=(const float*)d_in[6];
  const float* b_iou=(const float*)d_in[7];
  const float* U_iou=(const float*)d_in[8];
  const float* W_f  =(const float*)d_in[9];
  const float* b_f  =(const float*)d_in[10];
  const float* U_f  =(const float*)d_in[11];
  const float* W_ff =(const float*)d_in[12];
  const float* W_sd =(const float*)d_in[13];
  const float* W_sd2=(const float*)d_in[14];
  const float* W_sf =(const float*)d_in[15];
  const float* ln_g =(const float*)d_in[16];
  const float* ln_b =(const float*)d_in[17];

  const int N=in_sizes[0]/768;   // 87360
  const int T=N/NPT;             // 64
  const int MINT=T*NINT;         // 21824

  float* out0=(float*)d_out;
  float* out1=out0+(size_t)N*4;
  float* cbuf=out1+(size_t)T*4;  // c output region (live c-state)

  char* p=(char*)d_ws;
  auto alloc=[&](size_t bytes){ char* r=p; p+=((bytes+255)&~(size_t)255); return r; };
  bf16*  f_hi =(bf16*) alloc((size_t)N*768*2);
  bf16*  f_lo =(bf16*) alloc((size_t)N*768*2);
  bf16*  hs_hi=(bf16*) alloc((size_t)16384*HD*2);
  bf16*  hs_lo=(bf16*) alloc((size_t)16384*HD*2);
  float* csum =(float*)alloc((size_t)16384*HD*4);
  bf16*  h_hi =(bf16*) alloc((size_t)N*HD*2);
  bf16*  h_lo =(bf16*) alloc((size_t)N*HD*2);
  bf16*  WilL =(bf16*) alloc((size_t)1536*2304*2);
  bf16*  WilI =(bf16*) alloc((size_t)1536*3840*2);
  bf16*  WcatI=(bf16*) alloc((size_t)1536*3840*2);   // level-5 64-tile layout
  bf16*  Wfc  =(bf16*) alloc((size_t)512*1536*2);
  bf16*  Ufc  =(bf16*) alloc((size_t)512*1024*2);
  float* Wcomb=(float*)alloc((size_t)512*512*4);
  float* Wy   =(float*)alloc((size_t)4*512*4);
  float* XWf  =(float*)alloc((size_t)MINT*512*4);

  // conversions / weight prep
  { size_t n8=(size_t)N*768/8;  k_split8<<<(int)((n8+255)/256),256,0,stream>>>(features,f_hi,f_lo,n8); }
  { size_t n=(size_t)1536*2304; k_wil<<<(int)((n+255)/256),256,0,stream>>>(W_iou,U_iou,WilL,0); }
  { size_t n=(size_t)1536*3840; k_wil<<<(int)((n+255)/256),256,0,stream>>>(W_iou,U_iou,WilI,1); }
  { size_t n=(size_t)1536*3840; k_concatHL3840<<<(int)((n+255)/256),256,0,stream>>>(W_iou,U_iou,WcatI,1536); }
  { size_t n=(size_t)512*1536;  k_catHL<<<(int)((n+255)/256),256,0,stream>>>(W_f,Wfc,512,768); }
  { size_t n=(size_t)512*1024;  k_catHL<<<(int)((n+255)/256),256,0,stream>>>(U_f,Ufc,512,512); }
  { dim3 g(8,8); k_wcomb<<<g,256,0,stream>>>(W_sd2,W_sd,Wcomb); }
  { k_wy<<<8,256,0,stream>>>(W_sf,Wcomb,Wy); }

  // upfront: XWf for all internal nodes (pipelined)
  { dim3 g(4,(MINT+127)/128);
    k_xwf128p<<<g,256,G128_LDS,stream>>>(f_hi,f_lo,Wfc,XWf,MINT); }

  static const int starts[6]={0,1024,1280,1344,1360,1364};
  static const int csh[6]  ={10,8,6,4,2,0};
  static const int counts[6]={1024,256,64,16,4,1};
  static const int xwoffs[6]={0,0,256,320,336,340};

  // level 0 (leaves): 128x192 pipelined kernel, A-in-registers
  { dim3 g(8,(T*1024)/128);
    k_iou128p<<<g,256,IOU_LDS,stream>>>(f_hi,f_lo,hs_hi,hs_lo,WilL,b_iou,csum,h_hi,h_lo,cbuf,0,10,0); }

  for(int n=1;n<6;++n){
    int P=T*counts[n], E=T*counts[n-1];
    { dim3 g(4,E/128);
      k_uh128p<<<g,256,G128_LDS,stream>>>(h_hi,h_lo,Ufc,b_f,XWf,cbuf,csum,hs_hi,hs_lo,
                                          starts[n-1],csh[n-1],xwoffs[n]); }
    if(P>=128){
      dim3 g(8,P/128);
      k_iou128p<<<g,256,IOU_LDS,stream>>>(f_hi,f_lo,hs_hi,hs_lo,WilI,b_iou,csum,h_hi,h_lo,cbuf,starts[n],csh[n],1);
    }else{
      dim3 g(P/64,8);
      k_iou<<<g,256,0,stream>>>(f_hi,f_lo,hs_hi,hs_lo,WcatI,b_iou,csum,h_hi,h_lo,cbuf,starts[n],csh[n],3840,3840,1);
    }
  }

  // heads (stance folded into Wy)
  { int th=N*64; k_final2<<<(th+255)/256,256,0,stream>>>(h_hi,h_lo,Wy,ln_g,ln_b,out0,N); }
  { k_root<<<16,256,0,stream>>>(h_hi,h_lo,W_ff,out1); }
}

// Round 15
// 1875.634 us; speedup vs baseline: 1.3114x; 1.3114x over previous
//
#include <hip/hip_runtime.h>
#include <hip/hip_bf16.h>
#include <math.h>

typedef __bf16 bf16;
typedef bf16 bf16x8 __attribute__((ext_vector_type(8)));
typedef float f32x4 __attribute__((ext_vector_type(4)));

#define NPT 1365
#define HD 512
#define NINT 341   // internal nodes per tree (256+64+16+4+1)
#define IOU_LDS (2*128*64*2 + 2*192*64*2)   // 81920 B -> 2 blocks/CU
#define G128_LDS (2*128*64*2 + 2*128*64*2)  // 65536 B -> 2 blocks/CU

__device__ __forceinline__ float sigm(float x){ return 1.0f/(1.0f+__expf(-x)); }

__device__ __forceinline__ void gll16(const void* g, void* l){
  __builtin_amdgcn_global_load_lds((const __attribute__((address_space(1))) void*)g,
                                   (__attribute__((address_space(3))) void*)l, 16, 0, 0);
}

// ---------------- split fp32 -> bf16 hi/lo, 8 elems/thread ----------------
__global__ void k_split8(const float* __restrict__ s, bf16* __restrict__ hi,
                         bf16* __restrict__ lo, size_t n8){
  size_t i=(size_t)blockIdx.x*blockDim.x+threadIdx.x;
  if(i>=n8) return;
  const float4* sp=(const float4*)(s+i*8);
  float4 a=sp[0], b=sp[1];
  float v[8]={a.x,a.y,a.z,a.w,b.x,b.y,b.z,b.w};
  bf16x8 h,l;
  #pragma unroll
  for(int e=0;e<8;++e){ bf16 hh=(bf16)v[e]; h[e]=hh; l[e]=(bf16)(v[e]-(float)hh); }
  *(bf16x8*)(hi+i*8)=h;
  *(bf16x8*)(lo+i*8)=l;
}

// ---------------- generic [hi|lo] row concat ----------------
__global__ void k_catHL(const float* __restrict__ S, bf16* __restrict__ d,
                        int rows, int Ksrc){
  size_t i=(size_t)blockIdx.x*blockDim.x+threadIdx.x;
  int K=2*Ksrc;
  size_t tot=(size_t)rows*K;
  if(i>=tot) return;
  int r=(int)(i/K); int k=(int)(i-(size_t)r*K);
  float v=S[(size_t)r*Ksrc + (k<Ksrc?k:k-Ksrc)];
  bf16 h=(bf16)v;
  d[i]=(k<Ksrc)? h : (bf16)(v-(float)h);
}

// ---------------- gate-interleaved iou weights ----------------
__global__ void k_wil(const float* __restrict__ W, const float* __restrict__ U,
                      bf16* __restrict__ d, int internal){
  const int K = internal? 3840 : 2304;
  size_t i=(size_t)blockIdx.x*blockDim.x+threadIdx.x;
  size_t tot=(size_t)1536*K;
  if(i>=tot) return;
  int rp=(int)(i/K); int k=(int)(i-(size_t)rp*K);
  int f=rp>>4, rr=rp&15;
  int g=f%3, cgrp=f/3;
  int orig=g*512+cgrp*16+rr;
  float v; int lo=0;
  if(internal){
    if(k<768)        v=W[(size_t)orig*768+k];
    else if(k<1536)  v=W[(size_t)orig*768+(k-768)];
    else if(k<2048)  v=U[(size_t)orig*512+(k-1536)];
    else if(k<2560)  v=U[(size_t)orig*512+(k-2048)];
    else if(k<3328){ v=W[(size_t)orig*768+(k-2560)]; lo=1; }
    else           { v=U[(size_t)orig*512+(k-3328)]; lo=1; }
  }else{
    int kk=(k<768)?k:((k<1536)?k-768:k-1536);
    v=W[(size_t)orig*768+kk];
    lo=(k>=1536);
  }
  bf16 h=(bf16)v;
  d[i]= lo ? (bf16)(v-(float)h) : h;
}

// ---------------- old-layout concat K=3840 (level-5 64-tile iou only) ----------------
__global__ void k_concatHL3840(const float* __restrict__ W, const float* __restrict__ U,
                               bf16* __restrict__ d, int rows){
  size_t i=(size_t)blockIdx.x*blockDim.x+threadIdx.x;
  const int K=3840;
  size_t tot=(size_t)rows*K;
  if(i>=tot) return;
  int r=(int)(i/K); int k=(int)(i-(size_t)r*K);
  float v; int lo=0;
  if(k<768)        v=W[(size_t)r*768+k];
  else if(k<1536)  v=W[(size_t)r*768+(k-768)];
  else if(k<2048)  v=U[(size_t)r*512+(k-1536)];
  else if(k<2560)  v=U[(size_t)r*512+(k-2048)];
  else if(k<3328){ v=W[(size_t)r*768+(k-2560)]; lo=1; }
  else           { v=U[(size_t)r*512+(k-3328)]; lo=1; }
  bf16 h=(bf16)v;
  d[i]= lo ? (bf16)(v-(float)h) : h;
}

// ---------------- Wcomb = W_sd2 @ W_sd  (512x512, fp32 exact) ----------------
__global__ __launch_bounds__(256)
void k_wcomb(const float* __restrict__ W2, const float* __restrict__ W1,
             float* __restrict__ out){
  __shared__ float As[64][33];
  __shared__ float Bs[32][65];
  const int tid=threadIdx.x;
  const int i0=blockIdx.x*64, j0=blockIdx.y*64;
  const int tr=(tid>>4)*4, tc=(tid&15)*4;
  float acc[4][4];
  #pragma unroll
  for(int x=0;x<4;++x)
    #pragma unroll
    for(int y=0;y<4;++y) acc[x][y]=0.f;
  for(int k0=0;k0<1024;k0+=32){
    for(int l=tid;l<64*32;l+=256){ int r=l>>5,c=l&31; As[r][c]=W2[(size_t)(i0+r)*1024+k0+c]; }
    for(int l=tid;l<32*64;l+=256){ int r=l>>6,c=l&63; Bs[r][c]=W1[(size_t)(k0+r)*512+j0+c]; }
    __syncthreads();
    #pragma unroll 8
    for(int k=0;k<32;++k){
      float a[4],b[4];
      #pragma unroll
      for(int x=0;x<4;++x){ a[x]=As[tr+x][k]; b[x]=Bs[k][tc+x]; }
      #pragma unroll
      for(int x=0;x<4;++x)
        #pragma unroll
        for(int y=0;y<4;++y) acc[x][y]+=a[x]*b[y];
    }
    __syncthreads();
  }
  #pragma unroll
  for(int x=0;x<4;++x)
    #pragma unroll
    for(int y=0;y<4;++y) out[(size_t)(i0+tr+x)*512+j0+tc+y]=acc[x][y];
}

// ---------------- Wy[j,c] = Wsf[j,c] + sum_d Wsf[j,d]*Wcomb[d,c] ----------------
__global__ void k_wy(const float* __restrict__ Wsf, const float* __restrict__ Wcomb,
                     float* __restrict__ Wy){
  int idx=blockIdx.x*256+threadIdx.x;
  if(idx>=2048) return;
  int j=idx>>9, c=idx&511;
  float s=Wsf[j*512+c];
  for(int d=0;d<512;++d) s+=Wsf[j*512+d]*Wcomb[(size_t)d*512+c];
  Wy[(size_t)j*512+c]=s;
}

// ================= iou GEMM: 128 x 192, dbuf + counted vmcnt + setprio, 2 blk/CU =================
__global__ __launch_bounds__(256,2)
void k_iou128p(const bf16* __restrict__ fH, const bf16* __restrict__ fL,
               const bf16* __restrict__ hsH, const bf16* __restrict__ hsL,
               const bf16* __restrict__ Wil, const float* __restrict__ bias,
               const float* __restrict__ csum, bf16* __restrict__ hbuf,
               bf16* __restrict__ hlo, float* __restrict__ cbuf,
               int start_n, int shift, int internal)
{
  extern __shared__ char sm[];                 // A: 2x16384, B: 2x24576
  char* Abase=sm;
  char* Bbase=sm+32768;
  const int tid=threadIdx.x;
  const int w=tid>>6, lane=tid&63;
  const int m0=blockIdx.y*128, x=blockIdx.x;
  const int K = internal? 3840 : 2304;
  const int NT = K>>6;

  unsigned fofs[4], hofs[4];
  #pragma unroll
  for(int i=0;i<4;++i){
    int r=w*32+i*8+(lane>>3);
    int m=m0+r;
    int t_=m>>shift, j=m-(t_<<shift);
    fofs[i]=(unsigned)(((size_t)t_*NPT+start_n+j)*768);
    hofs[i]=(unsigned)m*512u;
  }
  unsigned bofs[6];
  #pragma unroll
  for(int i=0;i<6;++i){
    int r=x*192+w*48+i*8+(lane>>3);
    bofs[i]=(unsigned)r*(unsigned)K;
  }
  const unsigned swz=8u*((unsigned)(lane&7)^(unsigned)(lane>>3));

  f32x4 acc[4][6];
  #pragma unroll
  for(int mi=0;mi<4;++mi)
    #pragma unroll
    for(int ni=0;ni<6;++ni) acc[mi][ni]=(f32x4){0.f,0.f,0.f,0.f};

  const int wr=(w>>1)*64;
  const int wcF=(w&1)*6;
  const int lr=lane&15, lg=lane>>4;

  auto STAGE=[&](int buf, int t){
    const bf16* base; int kt; bool useF;
    if(internal){
      if(t<12){ base=fH; kt=t;    useF=true; }
      else if(t<24){ base=fL; kt=t-12; useF=true; }
      else if(t<32){ base=hsH; kt=t-24; useF=false; }
      else if(t<40){ base=hsL; kt=t-32; useF=false; }
      else if(t<52){ base=fH; kt=t-40; useF=true; }
      else        { base=hsH; kt=t-52; useF=false; }
    }else{
      if(t<12){ base=fH; kt=t;    useF=true; }
      else if(t<24){ base=fL; kt=t-12; useF=true; }
      else        { base=fH; kt=t-24; useF=true; }
    }
    const unsigned kofs=(unsigned)kt*64u+swz;
    char* Ad=Abase+(size_t)buf*16384;
    #pragma unroll
    for(int i=0;i<4;++i){
      const bf16* g=base+(useF?fofs[i]:hofs[i])+kofs;
      gll16(g, Ad+(w*32+i*8)*128);
    }
    const unsigned bk=(unsigned)t*64u+swz;
    char* Bd=Bbase+(size_t)buf*24576;
    #pragma unroll
    for(int i=0;i<6;++i){
      gll16(Wil+bofs[i]+bk, Bd+(w*48+i*8)*128);
    }
  };

  auto COMPUTE=[&](int cur){
    const char* Ab=Abase+(size_t)cur*16384;
    const char* Bb=Bbase+(size_t)cur*24576;
    #pragma unroll
    for(int ks=0;ks<2;++ks){
      const unsigned cb=((unsigned)(ks*64+lg*16)) ^ ((unsigned)(lr&7)<<4);
      bf16x8 av[4], bv[6];
      #pragma unroll
      for(int mi=0;mi<4;++mi)
        av[mi]=*(const bf16x8*)(Ab+(unsigned)(wr+mi*16+lr)*128u+cb);
      #pragma unroll
      for(int ni=0;ni<6;++ni)
        bv[ni]=*(const bf16x8*)(Bb+(unsigned)((wcF+ni)*16+lr)*128u+cb);
      __builtin_amdgcn_s_setprio(1);
      #pragma unroll
      for(int ni=0;ni<6;++ni)
        #pragma unroll
        for(int mi=0;mi<4;++mi)
          acc[mi][ni]=__builtin_amdgcn_mfma_f32_16x16x32_bf16(av[mi],bv[ni],acc[mi][ni],0,0,0);
      __builtin_amdgcn_s_setprio(0);
    }
  };

  STAGE(0,0);
  STAGE(1,1);
  asm volatile("s_waitcnt vmcnt(10)" ::: "memory");
  __builtin_amdgcn_s_barrier();
  __builtin_amdgcn_sched_barrier(0);

  for(int t=0;t<NT;++t){
    COMPUTE(t&1);
    if(t+1<NT){
      __builtin_amdgcn_sched_barrier(0);
      __builtin_amdgcn_s_barrier();
      __builtin_amdgcn_sched_barrier(0);
      if(t+2<NT){
        STAGE(t&1, t+2);
        asm volatile("s_waitcnt vmcnt(10)" ::: "memory");
      }else{
        asm volatile("s_waitcnt vmcnt(0)" ::: "memory");
      }
      __builtin_amdgcn_s_barrier();
      __builtin_amdgcn_sched_barrier(0);
    }
  }

  #pragma unroll
  for(int mi=0;mi<4;++mi){
    #pragma unroll
    for(int cg=0;cg<2;++cg){
      const int col = x*64 + ((w&1)*2+cg)*16 + lr;
      const float bi=bias[col], bo=bias[col+512], bu=bias[col+1024];
      #pragma unroll
      for(int r=0;r<4;++r){
        const int mm=m0+wr+mi*16+lg*4+r;
        float iv=acc[mi][3*cg+0][r]+bi;
        float ov=acc[mi][3*cg+1][r]+bo;
        float uv=acc[mi][3*cg+2][r]+bu;
        float cn=sigm(iv)*tanhf(uv);
        if(internal) cn+=csum[(size_t)mm*HD+col];
        float hn=sigm(ov)*tanhf(cn);
        const int tt=mm>>shift, jj=mm-(tt<<shift);
        const size_t nd=((size_t)tt*NPT+start_n+jj)*HD+col;
        cbuf[nd]=cn;
        bf16 hh=(bf16)hn;
        hbuf[nd]=hh;
        hlo[nd]=(bf16)(hn-(float)hh);
      }
    }
  }
}

// ---------------- old 64-tile iou (level 5 only, P=64; K=3840 layout) ----------------
__global__ __launch_bounds__(256)
void k_iou(const bf16* __restrict__ fH, const bf16* __restrict__ fL,
           const bf16* __restrict__ hsH, const bf16* __restrict__ hsL,
           const bf16* __restrict__ Wcat, const float* __restrict__ bias,
           const float* __restrict__ csum, bf16* __restrict__ hbuf,
           bf16* __restrict__ hlo, float* __restrict__ cbuf,
           int start_n, int shift, int K, int KB, int internal)
{
  __shared__ bf16 As[64][40];
  __shared__ bf16 Bs[3][64][40];
  const int tid=threadIdx.x;
  const int m0=blockIdx.x*64, n0=blockIdx.y*64;
  const int srow=tid>>2, skc=(tid&3)*8;
  const int m=m0+srow;
  const int t=m>>shift, j=m-(t<<shift);
  const size_t frow=((size_t)t*NPT+start_n+j)*768;
  const bf16* aFH=fH+frow;
  const bf16* aFL=fL+frow;
  const bf16* aHH=hsH+(size_t)m*HD;
  const bf16* aHL=hsL+(size_t)m*HD;
  const bf16* bp0=Wcat+(size_t)(n0+srow)*KB;
  const bf16* bp1=Wcat+(size_t)(512+n0+srow)*KB;
  const bf16* bp2=Wcat+(size_t)(1024+n0+srow)*KB;

  f32x4 acc[3][2][2];
  #pragma unroll
  for(int g=0;g<3;++g)
    #pragma unroll
    for(int mi=0;mi<2;++mi)
      #pragma unroll
      for(int ni=0;ni<2;++ni) acc[g][mi][ni]=(f32x4){0.f,0.f,0.f,0.f};

  const int w=tid>>6, lane=tid&63;
  const int wr=(w>>1)*32, wc=(w&1)*32;
  const int lr=lane&15, lg=lane>>4;

  for(int k0=0;k0<K;k0+=32){
    const bf16* ap;
    if(internal){
      if(k0<768)        ap=aFH+k0;
      else if(k0<1536)  ap=aFL+(k0-768);
      else if(k0<2048)  ap=aHH+(k0-1536);
      else if(k0<2560)  ap=aHL+(k0-2048);
      else if(k0<3328)  ap=aFH+(k0-2560);
      else              ap=aHH+(k0-3328);
    }else{
      ap=(k0<768)? (aFH+k0) : ((k0<1536)? (aFL+(k0-768)) : (aFH+(k0-1536)));
    }
    *(bf16x8*)&As[srow][skc]=*(const bf16x8*)(ap+skc);
    *(bf16x8*)&Bs[0][srow][skc]=*(const bf16x8*)(bp0+k0+skc);
    *(bf16x8*)&Bs[1][srow][skc]=*(const bf16x8*)(bp1+k0+skc);
    *(bf16x8*)&Bs[2][srow][skc]=*(const bf16x8*)(bp2+k0+skc);
    __syncthreads();
    bf16x8 a0=*(bf16x8*)&As[wr+lr][lg*8];
    bf16x8 a1=*(bf16x8*)&As[wr+16+lr][lg*8];
    #pragma unroll
    for(int g=0;g<3;++g){
      #pragma unroll
      for(int ni=0;ni<2;++ni){
        bf16x8 bv=*(bf16x8*)&Bs[g][wc+ni*16+lr][lg*8];
        acc[g][0][ni]=__builtin_amdgcn_mfma_f32_16x16x32_bf16(a0,bv,acc[g][0][ni],0,0,0);
        acc[g][1][ni]=__builtin_amdgcn_mfma_f32_16x16x32_bf16(a1,bv,acc[g][1][ni],0,0,0);
      }
    }
    __syncthreads();
  }

  #pragma unroll
  for(int mi=0;mi<2;++mi){
    #pragma unroll
    for(int ni=0;ni<2;++ni){
      const int col=n0+wc+ni*16+lr;
      const float bi=bias[col], bo=bias[col+512], bu=bias[col+1024];
      #pragma unroll
      for(int r=0;r<4;++r){
        const int mm=m0+wr+mi*16+lg*4+r;
        float iv=acc[0][mi][ni][r]+bi;
        float ov=acc[1][mi][ni][r]+bo;
        float uv=acc[2][mi][ni][r]+bu;
        float cn=sigm(iv)*tanhf(uv);
        if(internal) cn+=csum[(size_t)mm*HD+col];
        float hn=sigm(ov)*tanhf(cn);
        const int tt=mm>>shift, jj=mm-(tt<<shift);
        const size_t nd=((size_t)tt*NPT+start_n+jj)*HD+col;
        cbuf[nd]=cn;
        bf16 hh=(bf16)hn;
        hbuf[nd]=hh;
        hlo[nd]=(bf16)(hn-(float)hh);
      }
    }
  }
}

// ================= XWf: pipelined 128x128 (NT=36) =================
__global__ __launch_bounds__(256,2)
void k_xwf128p(const bf16* __restrict__ fH, const bf16* __restrict__ fL,
               const bf16* __restrict__ Wfc, float* __restrict__ XWf, int Mtot)
{
  extern __shared__ char sm[];     // A: 2x16384, B: 2x16384
  char* Abase=sm;
  char* Bbase=sm+32768;
  const int tid=threadIdx.x;
  const int w=tid>>6, lane=tid&63;
  const int m0=blockIdx.y*128, n0=blockIdx.x*128;
  const int NT=36;

  unsigned fofs[4];
  #pragma unroll
  for(int i=0;i<4;++i){
    int r=w*32+i*8+(lane>>3);
    int m=m0+r; if(m>=Mtot) m=Mtot-1;
    int t=m/NINT; int j=1024+(m-t*NINT);
    fofs[i]=(unsigned)(((size_t)t*NPT+j)*768);
  }
  unsigned bofs[4];
  #pragma unroll
  for(int i=0;i<4;++i){
    int r=n0+w*32+i*8+(lane>>3);
    bofs[i]=(unsigned)r*1536u;
  }
  const unsigned swz=8u*((unsigned)(lane&7)^(unsigned)(lane>>3));

  f32x4 acc[4][4];
  #pragma unroll
  for(int mi=0;mi<4;++mi)
    #pragma unroll
    for(int ni=0;ni<4;++ni) acc[mi][ni]=(f32x4){0.f,0.f,0.f,0.f};

  const int wr=(w>>1)*64, wc=(w&1)*64;
  const int lr=lane&15, lg=lane>>4;

  auto STAGE=[&](int buf, int t){
    const bf16* Abuf; unsigned ak, bk;
    if(t<12){ Abuf=fH; ak=(unsigned)t*64u; bk=(unsigned)t*64u; }
    else if(t<24){ Abuf=fH; ak=(unsigned)(t-12)*64u; bk=768u+(unsigned)(t-12)*64u; }
    else { Abuf=fL; ak=(unsigned)(t-24)*64u; bk=(unsigned)(t-24)*64u; }
    char* Ad=Abase+(size_t)buf*16384;
    #pragma unroll
    for(int i=0;i<4;++i)
      gll16(Abuf+fofs[i]+ak+swz, Ad+(w*32+i*8)*128);
    char* Bd=Bbase+(size_t)buf*16384;
    #pragma unroll
    for(int i=0;i<4;++i)
      gll16(Wfc+bofs[i]+bk+swz, Bd+(w*32+i*8)*128);
  };

  auto COMPUTE=[&](int cur){
    const char* Ab=Abase+(size_t)cur*16384;
    const char* Bb=Bbase+(size_t)cur*16384;
    #pragma unroll
    for(int ks=0;ks<2;++ks){
      const unsigned cb=((unsigned)(ks*64+lg*16)) ^ ((unsigned)(lr&7)<<4);
      bf16x8 av[4], bv[4];
      #pragma unroll
      for(int mi=0;mi<4;++mi)
        av[mi]=*(const bf16x8*)(Ab+(unsigned)(wr+mi*16+lr)*128u+cb);
      #pragma unroll
      for(int ni=0;ni<4;++ni)
        bv[ni]=*(const bf16x8*)(Bb+(unsigned)((wc+ni*16)+lr)*128u+cb);
      __builtin_amdgcn_s_setprio(1);
      #pragma unroll
      for(int ni=0;ni<4;++ni)
        #pragma unroll
        for(int mi=0;mi<4;++mi)
          acc[mi][ni]=__builtin_amdgcn_mfma_f32_16x16x32_bf16(av[mi],bv[ni],acc[mi][ni],0,0,0);
      __builtin_amdgcn_s_setprio(0);
    }
  };

  STAGE(0,0);
  STAGE(1,1);
  asm volatile("s_waitcnt vmcnt(8)" ::: "memory");
  __builtin_amdgcn_s_barrier();
  __builtin_amdgcn_sched_barrier(0);

  for(int t=0;t<NT;++t){
    COMPUTE(t&1);
    if(t+1<NT){
      __builtin_amdgcn_sched_barrier(0);
      __builtin_amdgcn_s_barrier();
      __builtin_amdgcn_sched_barrier(0);
      if(t+2<NT){
        STAGE(t&1, t+2);
        asm volatile("s_waitcnt vmcnt(8)" ::: "memory");
      }else{
        asm volatile("s_waitcnt vmcnt(0)" ::: "memory");
      }
      __builtin_amdgcn_s_barrier();
      __builtin_amdgcn_sched_barrier(0);
    }
  }

  #pragma unroll
  for(int mi=0;mi<4;++mi){
    #pragma unroll
    for(int ni=0;ni<4;++ni){
      const int col=n0+wc+ni*16+lr;
      #pragma unroll
      for(int r=0;r<4;++r){
        const int mm=m0+wr+mi*16+lg*4+r;
        if(mm<Mtot) XWf[(size_t)mm*512+col]=acc[mi][ni][r];
      }
    }
  }
}

// ================= Uh forget-gate: pipelined 128x128 (NT=24) + fused csum/hsum epilogue =================
__global__ __launch_bounds__(256,2)
void k_uh128p(const bf16* __restrict__ hhi, const bf16* __restrict__ hlo,
              const bf16* __restrict__ Ufc, const float* __restrict__ bias,
              const float* __restrict__ XWf, const float* __restrict__ cbuf,
              float* __restrict__ csum, bf16* __restrict__ hs_hi, bf16* __restrict__ hs_lo,
              int start_ch, int lc, int xwoff)
{
  extern __shared__ char sm[];     // A: 2x16384, B: 2x16384
  char* Abase=sm;
  char* Bbase=sm+32768;
  const int tid=threadIdx.x;
  const int w=tid>>6, lane=tid&63;
  const int e0=blockIdx.y*128, n0=blockIdx.x*128;
  const int NT=24;

  unsigned hofs[4];
  #pragma unroll
  for(int i=0;i<4;++i){
    int r=w*32+i*8+(lane>>3);
    int e=e0+r;
    int t=e>>lc, ei=e-(t<<lc);
    hofs[i]=(unsigned)(((size_t)t*NPT+start_ch+ei)*HD);
  }
  unsigned bofs[4];
  #pragma unroll
  for(int i=0;i<4;++i){
    int r=n0+w*32+i*8+(lane>>3);
    bofs[i]=(unsigned)r*1024u;
  }
  const unsigned swz=8u*((unsigned)(lane&7)^(unsigned)(lane>>3));

  f32x4 acc[4][4];
  #pragma unroll
  for(int mi=0;mi<4;++mi)
    #pragma unroll
    for(int ni=0;ni<4;++ni) acc[mi][ni]=(f32x4){0.f,0.f,0.f,0.f};

  const int wr=(w>>1)*64, wc=(w&1)*64;
  const int lr=lane&15, lg=lane>>4;

  auto STAGE=[&](int buf, int t){
    const bf16* Abuf; unsigned ak, bk;
    if(t<8){ Abuf=hhi; ak=(unsigned)t*64u; bk=(unsigned)t*64u; }
    else if(t<16){ Abuf=hhi; ak=(unsigned)(t-8)*64u; bk=512u+(unsigned)(t-8)*64u; }
    else { Abuf=hlo; ak=(unsigned)(t-16)*64u; bk=(unsigned)(t-16)*64u; }
    char* Ad=Abase+(size_t)buf*16384;
    #pragma unroll
    for(int i=0;i<4;++i)
      gll16(Abuf+hofs[i]+ak+swz, Ad+(w*32+i*8)*128);
    char* Bd=Bbase+(size_t)buf*16384;
    #pragma unroll
    for(int i=0;i<4;++i)
      gll16(Ufc+bofs[i]+bk+swz, Bd+(w*32+i*8)*128);
  };

  auto COMPUTE=[&](int cur){
    const char* Ab=Abase+(size_t)cur*16384;
    const char* Bb=Bbase+(size_t)cur*16384;
    #pragma unroll
    for(int ks=0;ks<2;++ks){
      const unsigned cb=((unsigned)(ks*64+lg*16)) ^ ((unsigned)(lr&7)<<4);
      bf16x8 av[4], bv[4];
      #pragma unroll
      for(int mi=0;mi<4;++mi)
        av[mi]=*(const bf16x8*)(Ab+(unsigned)(wr+mi*16+lr)*128u+cb);
      #pragma unroll
      for(int ni=0;ni<4;++ni)
        bv[ni]=*(const bf16x8*)(Bb+(unsigned)((wc+ni*16)+lr)*128u+cb);
      __builtin_amdgcn_s_setprio(1);
      #pragma unroll
      for(int ni=0;ni<4;++ni)
        #pragma unroll
        for(int mi=0;mi<4;++mi)
          acc[mi][ni]=__builtin_amdgcn_mfma_f32_16x16x32_bf16(av[mi],bv[ni],acc[mi][ni],0,0,0);
      __builtin_amdgcn_s_setprio(0);
    }
  };

  STAGE(0,0);
  STAGE(1,1);
  asm volatile("s_waitcnt vmcnt(8)" ::: "memory");
  __builtin_amdgcn_s_barrier();
  __builtin_amdgcn_sched_barrier(0);

  for(int t=0;t<NT;++t){
    COMPUTE(t&1);
    if(t+1<NT){
      __builtin_amdgcn_sched_barrier(0);
      __builtin_amdgcn_s_barrier();
      __builtin_amdgcn_sched_barrier(0);
      if(t+2<NT){
        STAGE(t&1, t+2);
        asm volatile("s_waitcnt vmcnt(8)" ::: "memory");
      }else{
        asm volatile("s_waitcnt vmcnt(0)" ::: "memory");
      }
      __builtin_amdgcn_s_barrier();
      __builtin_amdgcn_sched_barrier(0);
    }
  }

  #pragma unroll
  for(int mi=0;mi<4;++mi){
    const int ebase=e0+wr+mi*16+lg*4;
    const int tt=ebase>>lc, eib=ebase-(tt<<lc);
    const int inode=tt*NINT + xwoff + (eib>>2);
    const int par=ebase>>2;
    #pragma unroll
    for(int ni=0;ni<4;++ni){
      const int col=n0+wc+ni*16+lr;
      const float base=bias[col]+XWf[(size_t)inode*512+col];
      const size_t chbase=((size_t)tt*NPT+start_ch+eib)*HD+col;
      float s=0.f, hsv=0.f;
      #pragma unroll
      for(int r=0;r<4;++r){
        const size_t ci=chbase+(size_t)r*HD;
        float fv=sigm(acc[mi][ni][r]+base);
        s+=fv*cbuf[ci];
        hsv+=(float)hhi[ci]+(float)hlo[ci];
      }
      csum[(size_t)par*HD+col]=s;
      bf16 hh=(bf16)hsv;
      hs_hi[(size_t)par*HD+col]=hh;
      hs_lo[(size_t)par*HD+col]=(bf16)(hsv-(float)hh);
    }
  }
}

// ---------------- final head ----------------
__global__ __launch_bounds__(256)
void k_final2(const bf16* __restrict__ hhi, const bf16* __restrict__ hlo,
              const float* __restrict__ Wy, const float* __restrict__ gamma,
              const float* __restrict__ beta, float* __restrict__ out0, int Nn)
{
  const int gtid=blockIdx.x*256+threadIdx.x;
  const int node=gtid>>6, lane=gtid&63;
  if(node>=Nn) return;
  const size_t base=(size_t)node*HD+lane*8;
  bf16x8 hv=*(const bf16x8*)(hhi+base);
  bf16x8 lv=*(const bf16x8*)(hlo+base);
  float hf[8];
  #pragma unroll
  for(int e=0;e<8;++e) hf[e]=(float)hv[e]+(float)lv[e];
  float y[4];
  #pragma unroll
  for(int jj=0;jj<4;++jj){
    const float* wp=Wy+jj*HD+lane*8;
    float s=0.f;
    #pragma unroll
    for(int e=0;e<8;++e) s+=hf[e]*wp[e];
    #pragma unroll
    for(int off=32;off>=1;off>>=1) s+=__shfl_xor(s,off,64);
    y[jj]=s;
  }
  if(lane==0){
    float mu=0.25f*(y[0]+y[1]+y[2]+y[3]);
    float var=0.f;
    #pragma unroll
    for(int jj=0;jj<4;++jj){ float d=y[jj]-mu; var+=d*d; }
    var*=0.25f;
    float rs=rsqrtf(var+1e-6f);
    float z[4], zmax=-1e30f;
    #pragma unroll
    for(int jj=0;jj<4;++jj){ z[jj]=(y[jj]-mu)*rs*gamma[jj]+beta[jj]; zmax=fmaxf(zmax,z[jj]); }
    float es=0.f;
    #pragma unroll
    for(int jj=0;jj<4;++jj){ z[jj]=__expf(z[jj]-zmax); es+=z[jj]; }
    float inv=1.f/es;
    #pragma unroll
    for(int jj=0;jj<4;++jj) out0[(size_t)node*4+jj]=z[jj]*inv;
  }
}

// ---------------- root head ----------------
__global__ __launch_bounds__(256)
void k_root(const bf16* __restrict__ hhi, const bf16* __restrict__ hlo,
            const float* __restrict__ Wff, float* __restrict__ out1)
{
  const int gtid=blockIdx.x*256+threadIdx.x;
  const int tt=gtid>>6, lane=gtid&63;
  if(tt>=64) return;
  const size_t base=((size_t)tt*NPT+1364)*HD+lane*8;
  bf16x8 hv=*(const bf16x8*)(hhi+base);
  bf16x8 lv=*(const bf16x8*)(hlo+base);
  float hf[8];
  #pragma unroll
  for(int e=0;e<8;++e) hf[e]=(float)hv[e]+(float)lv[e];
  float y[4];
  #pragma unroll
  for(int jj=0;jj<4;++jj){
    const float* wp=Wff+jj*HD+lane*8;
    float s=0.f;
    #pragma unroll
    for(int e=0;e<8;++e) s+=hf[e]*wp[e];
    #pragma unroll
    for(int off=32;off>=1;off>>=1) s+=__shfl_xor(s,off,64);
    y[jj]=s;
  }
  if(lane==0){
    float zmax=fmaxf(fmaxf(y[0],y[1]),fmaxf(y[2],y[3]));
    float es=0.f, z[4];
    #pragma unroll
    for(int jj=0;jj<4;++jj){ z[jj]=__expf(y[jj]-zmax); es+=z[jj]; }
    float inv=1.f/es;
    #pragma unroll
    for(int jj=0;jj<4;++jj) out1[(size_t)tt*4+jj]=z[jj]*inv;
  }
}

extern "C" void kernel_launch(void* const* d_in, const int* in_sizes, int n_in,
                              void* d_out, int out_size, void* d_ws, size_t ws_size,
                              hipStream_t stream)
{
  const float* features=(const float*)d_in[0];
  const float* W_iou=(const float*)d_in[6];
  const float* b_iou=(const float*)d_in[7];
  const float* U_iou=(const float*)d_in[8];
  const float* W_f  =(const float*)d_in[9];
  const float* b_f  =(const float*)d_in[10];
  const float* U_f  =(const float*)d_in[11];
  const float* W_ff =(const float*)d_in[12];
  const float* W_sd =(const float*)d_in[13];
  const float* W_sd2=(const float*)d_in[14];
  const float* W_sf =(const float*)d_in[15];
  const float* ln_g =(const float*)d_in[16];
  const float* ln_b =(const float*)d_in[17];

  const int N=in_sizes[0]/768;   // 87360
  const int T=N/NPT;             // 64
  const int MINT=T*NINT;         // 21824

  float* out0=(float*)d_out;
  float* out1=out0+(size_t)N*4;
  float* cbuf=out1+(size_t)T*4;  // c output region (live c-state)

  char* p=(char*)d_ws;
  auto alloc=[&](size_t bytes){ char* r=p; p+=((bytes+255)&~(size_t)255); return r; };
  bf16*  f_hi =(bf16*) alloc((size_t)N*768*2);
  bf16*  f_lo =(bf16*) alloc((size_t)N*768*2);
  bf16*  hs_hi=(bf16*) alloc((size_t)16384*HD*2);
  bf16*  hs_lo=(bf16*) alloc((size_t)16384*HD*2);
  float* csum =(float*)alloc((size_t)16384*HD*4);
  bf16*  h_hi =(bf16*) alloc((size_t)N*HD*2);
  bf16*  h_lo =(bf16*) alloc((size_t)N*HD*2);
  bf16*  WilL =(bf16*) alloc((size_t)1536*2304*2);
  bf16*  WilI =(bf16*) alloc((size_t)1536*3840*2);
  bf16*  WcatI=(bf16*) alloc((size_t)1536*3840*2);   // level-5 64-tile layout
  bf16*  Wfc  =(bf16*) alloc((size_t)512*1536*2);
  bf16*  Ufc  =(bf16*) alloc((size_t)512*1024*2);
  float* Wcomb=(float*)alloc((size_t)512*512*4);
  float* Wy   =(float*)alloc((size_t)4*512*4);
  float* XWf  =(float*)alloc((size_t)MINT*512*4);

  // conversions / weight prep
  { size_t n8=(size_t)N*768/8;  k_split8<<<(int)((n8+255)/256),256,0,stream>>>(features,f_hi,f_lo,n8); }
  { size_t n=(size_t)1536*2304; k_wil<<<(int)((n+255)/256),256,0,stream>>>(W_iou,U_iou,WilL,0); }
  { size_t n=(size_t)1536*3840; k_wil<<<(int)((n+255)/256),256,0,stream>>>(W_iou,U_iou,WilI,1); }
  { size_t n=(size_t)1536*3840; k_concatHL3840<<<(int)((n+255)/256),256,0,stream>>>(W_iou,U_iou,WcatI,1536); }
  { size_t n=(size_t)512*1536;  k_catHL<<<(int)((n+255)/256),256,0,stream>>>(W_f,Wfc,512,768); }
  { size_t n=(size_t)512*1024;  k_catHL<<<(int)((n+255)/256),256,0,stream>>>(U_f,Ufc,512,512); }
  { dim3 g(8,8); k_wcomb<<<g,256,0,stream>>>(W_sd2,W_sd,Wcomb); }
  { k_wy<<<8,256,0,stream>>>(W_sf,Wcomb,Wy); }

  // upfront: XWf for all internal nodes (pipelined)
  { dim3 g(4,(MINT+127)/128);
    k_xwf128p<<<g,256,G128_LDS,stream>>>(f_hi,f_lo,Wfc,XWf,MINT); }

  static const int starts[6]={0,1024,1280,1344,1360,1364};
  static const int csh[6]  ={10,8,6,4,2,0};
  static const int counts[6]={1024,256,64,16,4,1};
  static const int xwoffs[6]={0,0,256,320,336,340};

  // level 0 (leaves): 128x192 pipelined kernel, counted vmcnt
  { dim3 g(8,(T*1024)/128);
    k_iou128p<<<g,256,IOU_LDS,stream>>>(f_hi,f_lo,hs_hi,hs_lo,WilL,b_iou,csum,h_hi,h_lo,cbuf,0,10,0); }

  for(int n=1;n<6;++n){
    int P=T*counts[n], E=T*counts[n-1];
    { dim3 g(4,E/128);
      k_uh128p<<<g,256,G128_LDS,stream>>>(h_hi,h_lo,Ufc,b_f,XWf,cbuf,csum,hs_hi,hs_lo,
                                          starts[n-1],csh[n-1],xwoffs[n]); }
    if(P>=128){
      dim3 g(8,P/128);
      k_iou128p<<<g,256,IOU_LDS,stream>>>(f_hi,f_lo,hs_hi,hs_lo,WilI,b_iou,csum,h_hi,h_lo,cbuf,starts[n],csh[n],1);
    }else{
      dim3 g(P/64,8);
      k_iou<<<g,256,0,stream>>>(f_hi,f_lo,hs_hi,hs_lo,WcatI,b_iou,csum,h_hi,h_lo,cbuf,starts[n],csh[n],3840,3840,1);
    }
  }

  // heads (stance folded into Wy)
  { int th=N*64; k_final2<<<(th+255)/256,256,0,stream>>>(h_hi,h_lo,Wy,ln_g,ln_b,out0,N); }
  { k_root<<<16,256,0,stream>>>(h_hi,h_lo,W_ff,out1); }
}

// Round 16
// 1541.532 us; speedup vs baseline: 1.5956x; 1.2167x over previous
//
#include <hip/hip_runtime.h>
#include <hip/hip_bf16.h>
#include <math.h>

typedef __bf16 bf16;
typedef bf16 bf16x8 __attribute__((ext_vector_type(8)));
typedef float f32x4 __attribute__((ext_vector_type(4)));

#define NPT 1365
#define HD 512
#define NINT 341   // internal nodes per tree (256+64+16+4+1)
#define IOU_LDS (2*128*64*2 + 2*192*64*2)   // 81920 B -> 2 blocks/CU
#define G128_LDS (2*128*64*2 + 2*128*64*2)  // 65536 B -> 2 blocks/CU

__device__ __forceinline__ float sigm(float x){ return 1.0f/(1.0f+__expf(-x)); }

__device__ __forceinline__ void gll16(const void* g, void* l){
  __builtin_amdgcn_global_load_lds((const __attribute__((address_space(1))) void*)g,
                                   (__attribute__((address_space(3))) void*)l, 16, 0, 0);
}

// ---------------- split fp32 -> bf16 hi/lo, 8 elems/thread ----------------
__global__ void k_split8(const float* __restrict__ s, bf16* __restrict__ hi,
                         bf16* __restrict__ lo, size_t n8){
  size_t i=(size_t)blockIdx.x*blockDim.x+threadIdx.x;
  if(i>=n8) return;
  const float4* sp=(const float4*)(s+i*8);
  float4 a=sp[0], b=sp[1];
  float v[8]={a.x,a.y,a.z,a.w,b.x,b.y,b.z,b.w};
  bf16x8 h,l;
  #pragma unroll
  for(int e=0;e<8;++e){ bf16 hh=(bf16)v[e]; h[e]=hh; l[e]=(bf16)(v[e]-(float)hh); }
  *(bf16x8*)(hi+i*8)=h;
  *(bf16x8*)(lo+i*8)=l;
}

// ---------------- generic [hi|lo] row concat (Ufc/Wfc; only hi half used now) ----------------
__global__ void k_catHL(const float* __restrict__ S, bf16* __restrict__ d,
                        int rows, int Ksrc){
  size_t i=(size_t)blockIdx.x*blockDim.x+threadIdx.x;
  int K=2*Ksrc;
  size_t tot=(size_t)rows*K;
  if(i>=tot) return;
  int r=(int)(i/K); int k=(int)(i-(size_t)r*K);
  float v=S[(size_t)r*Ksrc + (k<Ksrc?k:k-Ksrc)];
  bf16 h=(bf16)v;
  d[i]=(k<Ksrc)? h : (bf16)(v-(float)h);
}

// ---------------- gate-interleaved iou weights, hi-only products ----------------
// leaf   (K=1536): [Whi | Whi]
// intern (K=2560): [Whi | Whi | Uhi | Uhi]
__global__ void k_wil(const float* __restrict__ W, const float* __restrict__ U,
                      bf16* __restrict__ d, int internal){
  const int K = internal? 2560 : 1536;
  size_t i=(size_t)blockIdx.x*blockDim.x+threadIdx.x;
  size_t tot=(size_t)1536*K;
  if(i>=tot) return;
  int rp=(int)(i/K); int k=(int)(i-(size_t)rp*K);
  int f=rp>>4, rr=rp&15;
  int g=f%3, cgrp=f/3;
  int orig=g*512+cgrp*16+rr;
  float v;
  if(internal){
    if(k<768)        v=W[(size_t)orig*768+k];
    else if(k<1536)  v=W[(size_t)orig*768+(k-768)];
    else if(k<2048)  v=U[(size_t)orig*512+(k-1536)];
    else             v=U[(size_t)orig*512+(k-2048)];
  }else{
    int kk=(k<768)?k:k-768;
    v=W[(size_t)orig*768+kk];
  }
  d[i]=(bf16)v;
}

// ---------------- old-layout concat K=3840 (level-5 64-tile iou; only first 2560 used) ----------------
__global__ void k_concatHL3840(const float* __restrict__ W, const float* __restrict__ U,
                               bf16* __restrict__ d, int rows){
  size_t i=(size_t)blockIdx.x*blockDim.x+threadIdx.x;
  const int K=3840;
  size_t tot=(size_t)rows*K;
  if(i>=tot) return;
  int r=(int)(i/K); int k=(int)(i-(size_t)r*K);
  float v; int lo=0;
  if(k<768)        v=W[(size_t)r*768+k];
  else if(k<1536)  v=W[(size_t)r*768+(k-768)];
  else if(k<2048)  v=U[(size_t)r*512+(k-1536)];
  else if(k<2560)  v=U[(size_t)r*512+(k-2048)];
  else if(k<3328){ v=W[(size_t)r*768+(k-2560)]; lo=1; }
  else           { v=U[(size_t)r*512+(k-3328)]; lo=1; }
  bf16 h=(bf16)v;
  d[i]= lo ? (bf16)(v-(float)h) : h;
}

// ---------------- Wcomb = W_sd2 @ W_sd  (512x512, fp32 exact) ----------------
__global__ __launch_bounds__(256)
void k_wcomb(const float* __restrict__ W2, const float* __restrict__ W1,
             float* __restrict__ out){
  __shared__ float As[64][33];
  __shared__ float Bs[32][65];
  const int tid=threadIdx.x;
  const int i0=blockIdx.x*64, j0=blockIdx.y*64;
  const int tr=(tid>>4)*4, tc=(tid&15)*4;
  float acc[4][4];
  #pragma unroll
  for(int x=0;x<4;++x)
    #pragma unroll
    for(int y=0;y<4;++y) acc[x][y]=0.f;
  for(int k0=0;k0<1024;k0+=32){
    for(int l=tid;l<64*32;l+=256){ int r=l>>5,c=l&31; As[r][c]=W2[(size_t)(i0+r)*1024+k0+c]; }
    for(int l=tid;l<32*64;l+=256){ int r=l>>6,c=l&63; Bs[r][c]=W1[(size_t)(k0+r)*512+j0+c]; }
    __syncthreads();
    #pragma unroll 8
    for(int k=0;k<32;++k){
      float a[4],b[4];
      #pragma unroll
      for(int x=0;x<4;++x){ a[x]=As[tr+x][k]; b[x]=Bs[k][tc+x]; }
      #pragma unroll
      for(int x=0;x<4;++x)
        #pragma unroll
        for(int y=0;y<4;++y) acc[x][y]+=a[x]*b[y];
    }
    __syncthreads();
  }
  #pragma unroll
  for(int x=0;x<4;++x)
    #pragma unroll
    for(int y=0;y<4;++y) out[(size_t)(i0+tr+x)*512+j0+tc+y]=acc[x][y];
}

// ---------------- Wy[j,c] = Wsf[j,c] + sum_d Wsf[j,d]*Wcomb[d,c] ----------------
__global__ void k_wy(const float* __restrict__ Wsf, const float* __restrict__ Wcomb,
                     float* __restrict__ Wy){
  int idx=blockIdx.x*256+threadIdx.x;
  if(idx>=2048) return;
  int j=idx>>9, c=idx&511;
  float s=Wsf[j*512+c];
  for(int d=0;d<512;++d) s+=Wsf[j*512+d]*Wcomb[(size_t)d*512+c];
  Wy[(size_t)j*512+c]=s;
}

// ================= iou GEMM: 128 x 192, dbuf + counted vmcnt + setprio, 2 blk/CU =================
__global__ __launch_bounds__(256,2)
void k_iou128p(const bf16* __restrict__ fH, const bf16* __restrict__ fL,
               const bf16* __restrict__ hsH, const bf16* __restrict__ hsL,
               const bf16* __restrict__ Wil, const float* __restrict__ bias,
               const float* __restrict__ csum, bf16* __restrict__ hbuf,
               bf16* __restrict__ hlo, float* __restrict__ cbuf,
               int start_n, int shift, int internal)
{
  extern __shared__ char sm[];                 // A: 2x16384, B: 2x24576
  char* Abase=sm;
  char* Bbase=sm+32768;
  const int tid=threadIdx.x;
  const int w=tid>>6, lane=tid&63;
  const int m0=blockIdx.y*128, x=blockIdx.x;
  const int K = internal? 2560 : 1536;
  const int NT = K>>6;

  unsigned fofs[4], hofs[4];
  #pragma unroll
  for(int i=0;i<4;++i){
    int r=w*32+i*8+(lane>>3);
    int m=m0+r;
    int t_=m>>shift, j=m-(t_<<shift);
    fofs[i]=(unsigned)(((size_t)t_*NPT+start_n+j)*768);
    hofs[i]=(unsigned)m*512u;
  }
  unsigned bofs[6];
  #pragma unroll
  for(int i=0;i<6;++i){
    int r=x*192+w*48+i*8+(lane>>3);
    bofs[i]=(unsigned)r*(unsigned)K;
  }
  const unsigned swz=8u*((unsigned)(lane&7)^(unsigned)(lane>>3));

  f32x4 acc[4][6];
  #pragma unroll
  for(int mi=0;mi<4;++mi)
    #pragma unroll
    for(int ni=0;ni<6;++ni) acc[mi][ni]=(f32x4){0.f,0.f,0.f,0.f};

  const int wr=(w>>1)*64;
  const int wcF=(w&1)*6;
  const int lr=lane&15, lg=lane>>4;

  auto STAGE=[&](int buf, int t){
    const bf16* base; int kt; bool useF;
    if(internal){
      if(t<12){ base=fH; kt=t;    useF=true; }
      else if(t<24){ base=fL; kt=t-12; useF=true; }
      else if(t<32){ base=hsH; kt=t-24; useF=false; }
      else        { base=hsL; kt=t-32; useF=false; }
    }else{
      if(t<12){ base=fH; kt=t;    useF=true; }
      else    { base=fL; kt=t-12; useF=true; }
    }
    const unsigned kofs=(unsigned)kt*64u+swz;
    char* Ad=Abase+(size_t)buf*16384;
    #pragma unroll
    for(int i=0;i<4;++i){
      const bf16* g=base+(useF?fofs[i]:hofs[i])+kofs;
      gll16(g, Ad+(w*32+i*8)*128);
    }
    const unsigned bk=(unsigned)t*64u+swz;
    char* Bd=Bbase+(size_t)buf*24576;
    #pragma unroll
    for(int i=0;i<6;++i){
      gll16(Wil+bofs[i]+bk, Bd+(w*48+i*8)*128);
    }
  };

  auto COMPUTE=[&](int cur){
    const char* Ab=Abase+(size_t)cur*16384;
    const char* Bb=Bbase+(size_t)cur*24576;
    #pragma unroll
    for(int ks=0;ks<2;++ks){
      const unsigned cb=((unsigned)(ks*64+lg*16)) ^ ((unsigned)(lr&7)<<4);
      bf16x8 av[4], bv[6];
      #pragma unroll
      for(int mi=0;mi<4;++mi)
        av[mi]=*(const bf16x8*)(Ab+(unsigned)(wr+mi*16+lr)*128u+cb);
      #pragma unroll
      for(int ni=0;ni<6;++ni)
        bv[ni]=*(const bf16x8*)(Bb+(unsigned)((wcF+ni)*16+lr)*128u+cb);
      __builtin_amdgcn_s_setprio(1);
      #pragma unroll
      for(int ni=0;ni<6;++ni)
        #pragma unroll
        for(int mi=0;mi<4;++mi)
          acc[mi][ni]=__builtin_amdgcn_mfma_f32_16x16x32_bf16(av[mi],bv[ni],acc[mi][ni],0,0,0);
      __builtin_amdgcn_s_setprio(0);
    }
  };

  STAGE(0,0);
  STAGE(1,1);
  asm volatile("s_waitcnt vmcnt(10)" ::: "memory");
  __builtin_amdgcn_s_barrier();
  __builtin_amdgcn_sched_barrier(0);

  for(int t=0;t<NT;++t){
    COMPUTE(t&1);
    if(t+1<NT){
      __builtin_amdgcn_sched_barrier(0);
      __builtin_amdgcn_s_barrier();
      __builtin_amdgcn_sched_barrier(0);
      if(t+2<NT){
        STAGE(t&1, t+2);
        asm volatile("s_waitcnt vmcnt(10)" ::: "memory");
      }else{
        asm volatile("s_waitcnt vmcnt(0)" ::: "memory");
      }
      __builtin_amdgcn_s_barrier();
      __builtin_amdgcn_sched_barrier(0);
    }
  }

  #pragma unroll
  for(int mi=0;mi<4;++mi){
    #pragma unroll
    for(int cg=0;cg<2;++cg){
      const int col = x*64 + ((w&1)*2+cg)*16 + lr;
      const float bi=bias[col], bo=bias[col+512], bu=bias[col+1024];
      #pragma unroll
      for(int r=0;r<4;++r){
        const int mm=m0+wr+mi*16+lg*4+r;
        float iv=acc[mi][3*cg+0][r]+bi;
        float ov=acc[mi][3*cg+1][r]+bo;
        float uv=acc[mi][3*cg+2][r]+bu;
        float cn=sigm(iv)*tanhf(uv);
        if(internal) cn+=csum[(size_t)mm*HD+col];
        float hn=sigm(ov)*tanhf(cn);
        const int tt=mm>>shift, jj=mm-(tt<<shift);
        const size_t nd=((size_t)tt*NPT+start_n+jj)*HD+col;
        cbuf[nd]=cn;
        bf16 hh=(bf16)hn;
        hbuf[nd]=hh;
        hlo[nd]=(bf16)(hn-(float)hh);
      }
    }
  }
}

// ---------------- old 64-tile iou (level 5 only, P=64; K=2560 prefix of 3840 layout) ----------------
__global__ __launch_bounds__(256)
void k_iou(const bf16* __restrict__ fH, const bf16* __restrict__ fL,
           const bf16* __restrict__ hsH, const bf16* __restrict__ hsL,
           const bf16* __restrict__ Wcat, const float* __restrict__ bias,
           const float* __restrict__ csum, bf16* __restrict__ hbuf,
           bf16* __restrict__ hlo, float* __restrict__ cbuf,
           int start_n, int shift, int K, int KB, int internal)
{
  __shared__ bf16 As[64][40];
  __shared__ bf16 Bs[3][64][40];
  const int tid=threadIdx.x;
  const int m0=blockIdx.x*64, n0=blockIdx.y*64;
  const int srow=tid>>2, skc=(tid&3)*8;
  const int m=m0+srow;
  const int t=m>>shift, j=m-(t<<shift);
  const size_t frow=((size_t)t*NPT+start_n+j)*768;
  const bf16* aFH=fH+frow;
  const bf16* aFL=fL+frow;
  const bf16* aHH=hsH+(size_t)m*HD;
  const bf16* aHL=hsL+(size_t)m*HD;
  const bf16* bp0=Wcat+(size_t)(n0+srow)*KB;
  const bf16* bp1=Wcat+(size_t)(512+n0+srow)*KB;
  const bf16* bp2=Wcat+(size_t)(1024+n0+srow)*KB;

  f32x4 acc[3][2][2];
  #pragma unroll
  for(int g=0;g<3;++g)
    #pragma unroll
    for(int mi=0;mi<2;++mi)
      #pragma unroll
      for(int ni=0;ni<2;++ni) acc[g][mi][ni]=(f32x4){0.f,0.f,0.f,0.f};

  const int w=tid>>6, lane=tid&63;
  const int wr=(w>>1)*32, wc=(w&1)*32;
  const int lr=lane&15, lg=lane>>4;

  for(int k0=0;k0<K;k0+=32){
    const bf16* ap;
    if(internal){
      if(k0<768)        ap=aFH+k0;
      else if(k0<1536)  ap=aFL+(k0-768);
      else if(k0<2048)  ap=aHH+(k0-1536);
      else              ap=aHL+(k0-2048);
    }else{
      ap=(k0<768)? (aFH+k0) : (aFL+(k0-768));
    }
    *(bf16x8*)&As[srow][skc]=*(const bf16x8*)(ap+skc);
    *(bf16x8*)&Bs[0][srow][skc]=*(const bf16x8*)(bp0+k0+skc);
    *(bf16x8*)&Bs[1][srow][skc]=*(const bf16x8*)(bp1+k0+skc);
    *(bf16x8*)&Bs[2][srow][skc]=*(const bf16x8*)(bp2+k0+skc);
    __syncthreads();
    bf16x8 a0=*(bf16x8*)&As[wr+lr][lg*8];
    bf16x8 a1=*(bf16x8*)&As[wr+16+lr][lg*8];
    #pragma unroll
    for(int g=0;g<3;++g){
      #pragma unroll
      for(int ni=0;ni<2;++ni){
        bf16x8 bv=*(bf16x8*)&Bs[g][wc+ni*16+lr][lg*8];
        acc[g][0][ni]=__builtin_amdgcn_mfma_f32_16x16x32_bf16(a0,bv,acc[g][0][ni],0,0,0);
        acc[g][1][ni]=__builtin_amdgcn_mfma_f32_16x16x32_bf16(a1,bv,acc[g][1][ni],0,0,0);
      }
    }
    __syncthreads();
  }

  #pragma unroll
  for(int mi=0;mi<2;++mi){
    #pragma unroll
    for(int ni=0;ni<2;++ni){
      const int col=n0+wc+ni*16+lr;
      const float bi=bias[col], bo=bias[col+512], bu=bias[col+1024];
      #pragma unroll
      for(int r=0;r<4;++r){
        const int mm=m0+wr+mi*16+lg*4+r;
        float iv=acc[0][mi][ni][r]+bi;
        float ov=acc[1][mi][ni][r]+bo;
        float uv=acc[2][mi][ni][r]+bu;
        float cn=sigm(iv)*tanhf(uv);
        if(internal) cn+=csum[(size_t)mm*HD+col];
        float hn=sigm(ov)*tanhf(cn);
        const int tt=mm>>shift, jj=mm-(tt<<shift);
        const size_t nd=((size_t)tt*NPT+start_n+jj)*HD+col;
        cbuf[nd]=cn;
        bf16 hh=(bf16)hn;
        hbuf[nd]=hh;
        hlo[nd]=(bf16)(hn-(float)hh);
      }
    }
  }
}

// ================= XWf: pipelined 128x128 (NT=24: fH·Whi, fL·Whi) =================
__global__ __launch_bounds__(256,2)
void k_xwf128p(const bf16* __restrict__ fH, const bf16* __restrict__ fL,
               const bf16* __restrict__ Wfc, float* __restrict__ XWf, int Mtot)
{
  extern __shared__ char sm[];     // A: 2x16384, B: 2x16384
  char* Abase=sm;
  char* Bbase=sm+32768;
  const int tid=threadIdx.x;
  const int w=tid>>6, lane=tid&63;
  const int m0=blockIdx.y*128, n0=blockIdx.x*128;
  const int NT=24;

  unsigned fofs[4];
  #pragma unroll
  for(int i=0;i<4;++i){
    int r=w*32+i*8+(lane>>3);
    int m=m0+r; if(m>=Mtot) m=Mtot-1;
    int t=m/NINT; int j=1024+(m-t*NINT);
    fofs[i]=(unsigned)(((size_t)t*NPT+j)*768);
  }
  unsigned bofs[4];
  #pragma unroll
  for(int i=0;i<4;++i){
    int r=n0+w*32+i*8+(lane>>3);
    bofs[i]=(unsigned)r*1536u;
  }
  const unsigned swz=8u*((unsigned)(lane&7)^(unsigned)(lane>>3));

  f32x4 acc[4][4];
  #pragma unroll
  for(int mi=0;mi<4;++mi)
    #pragma unroll
    for(int ni=0;ni<4;++ni) acc[mi][ni]=(f32x4){0.f,0.f,0.f,0.f};

  const int wr=(w>>1)*64, wc=(w&1)*64;
  const int lr=lane&15, lg=lane>>4;

  auto STAGE=[&](int buf, int t){
    const bf16* Abuf; unsigned ak, bk;
    if(t<12){ Abuf=fH; ak=(unsigned)t*64u; bk=(unsigned)t*64u; }
    else    { Abuf=fL; ak=(unsigned)(t-12)*64u; bk=(unsigned)(t-12)*64u; }
    char* Ad=Abase+(size_t)buf*16384;
    #pragma unroll
    for(int i=0;i<4;++i)
      gll16(Abuf+fofs[i]+ak+swz, Ad+(w*32+i*8)*128);
    char* Bd=Bbase+(size_t)buf*16384;
    #pragma unroll
    for(int i=0;i<4;++i)
      gll16(Wfc+bofs[i]+bk+swz, Bd+(w*32+i*8)*128);
  };

  auto COMPUTE=[&](int cur){
    const char* Ab=Abase+(size_t)cur*16384;
    const char* Bb=Bbase+(size_t)cur*16384;
    #pragma unroll
    for(int ks=0;ks<2;++ks){
      const unsigned cb=((unsigned)(ks*64+lg*16)) ^ ((unsigned)(lr&7)<<4);
      bf16x8 av[4], bv[4];
      #pragma unroll
      for(int mi=0;mi<4;++mi)
        av[mi]=*(const bf16x8*)(Ab+(unsigned)(wr+mi*16+lr)*128u+cb);
      #pragma unroll
      for(int ni=0;ni<4;++ni)
        bv[ni]=*(const bf16x8*)(Bb+(unsigned)((wc+ni*16)+lr)*128u+cb);
      __builtin_amdgcn_s_setprio(1);
      #pragma unroll
      for(int ni=0;ni<4;++ni)
        #pragma unroll
        for(int mi=0;mi<4;++mi)
          acc[mi][ni]=__builtin_amdgcn_mfma_f32_16x16x32_bf16(av[mi],bv[ni],acc[mi][ni],0,0,0);
      __builtin_amdgcn_s_setprio(0);
    }
  };

  STAGE(0,0);
  STAGE(1,1);
  asm volatile("s_waitcnt vmcnt(8)" ::: "memory");
  __builtin_amdgcn_s_barrier();
  __builtin_amdgcn_sched_barrier(0);

  for(int t=0;t<NT;++t){
    COMPUTE(t&1);
    if(t+1<NT){
      __builtin_amdgcn_sched_barrier(0);
      __builtin_amdgcn_s_barrier();
      __builtin_amdgcn_sched_barrier(0);
      if(t+2<NT){
        STAGE(t&1, t+2);
        asm volatile("s_waitcnt vmcnt(8)" ::: "memory");
      }else{
        asm volatile("s_waitcnt vmcnt(0)" ::: "memory");
      }
      __builtin_amdgcn_s_barrier();
      __builtin_amdgcn_sched_barrier(0);
    }
  }

  #pragma unroll
  for(int mi=0;mi<4;++mi){
    #pragma unroll
    for(int ni=0;ni<4;++ni){
      const int col=n0+wc+ni*16+lr;
      #pragma unroll
      for(int r=0;r<4;++r){
        const int mm=m0+wr+mi*16+lg*4+r;
        if(mm<Mtot) XWf[(size_t)mm*512+col]=acc[mi][ni][r];
      }
    }
  }
}

// ================= Uh forget-gate: pipelined 128x128 (NT=16) + fused csum/hsum epilogue =================
__global__ __launch_bounds__(256,2)
void k_uh128p(const bf16* __restrict__ hhi, const bf16* __restrict__ hlo,
              const bf16* __restrict__ Ufc, const float* __restrict__ bias,
              const float* __restrict__ XWf, const float* __restrict__ cbuf,
              float* __restrict__ csum, bf16* __restrict__ hs_hi, bf16* __restrict__ hs_lo,
              int start_ch, int lc, int xwoff)
{
  extern __shared__ char sm[];     // A: 2x16384, B: 2x16384
  char* Abase=sm;
  char* Bbase=sm+32768;
  const int tid=threadIdx.x;
  const int w=tid>>6, lane=tid&63;
  const int e0=blockIdx.y*128, n0=blockIdx.x*128;
  const int NT=16;

  unsigned hofs[4];
  #pragma unroll
  for(int i=0;i<4;++i){
    int r=w*32+i*8+(lane>>3);
    int e=e0+r;
    int t=e>>lc, ei=e-(t<<lc);
    hofs[i]=(unsigned)(((size_t)t*NPT+start_ch+ei)*HD);
  }
  unsigned bofs[4];
  #pragma unroll
  for(int i=0;i<4;++i){
    int r=n0+w*32+i*8+(lane>>3);
    bofs[i]=(unsigned)r*1024u;
  }
  const unsigned swz=8u*((unsigned)(lane&7)^(unsigned)(lane>>3));

  f32x4 acc[4][4];
  #pragma unroll
  for(int mi=0;mi<4;++mi)
    #pragma unroll
    for(int ni=0;ni<4;++ni) acc[mi][ni]=(f32x4){0.f,0.f,0.f,0.f};

  const int wr=(w>>1)*64, wc=(w&1)*64;
  const int lr=lane&15, lg=lane>>4;

  auto STAGE=[&](int buf, int t){
    const bf16* Abuf; unsigned ak, bk;
    if(t<8){ Abuf=hhi; ak=(unsigned)t*64u; bk=(unsigned)t*64u; }
    else   { Abuf=hlo; ak=(unsigned)(t-8)*64u; bk=(unsigned)(t-8)*64u; }
    char* Ad=Abase+(size_t)buf*16384;
    #pragma unroll
    for(int i=0;i<4;++i)
      gll16(Abuf+hofs[i]+ak+swz, Ad+(w*32+i*8)*128);
    char* Bd=Bbase+(size_t)buf*16384;
    #pragma unroll
    for(int i=0;i<4;++i)
      gll16(Ufc+bofs[i]+bk+swz, Bd+(w*32+i*8)*128);
  };

  auto COMPUTE=[&](int cur){
    const char* Ab=Abase+(size_t)cur*16384;
    const char* Bb=Bbase+(size_t)cur*16384;
    #pragma unroll
    for(int ks=0;ks<2;++ks){
      const unsigned cb=((unsigned)(ks*64+lg*16)) ^ ((unsigned)(lr&7)<<4);
      bf16x8 av[4], bv[4];
      #pragma unroll
      for(int mi=0;mi<4;++mi)
        av[mi]=*(const bf16x8*)(Ab+(unsigned)(wr+mi*16+lr)*128u+cb);
      #pragma unroll
      for(int ni=0;ni<4;++ni)
        bv[ni]=*(const bf16x8*)(Bb+(unsigned)((wc+ni*16)+lr)*128u+cb);
      __builtin_amdgcn_s_setprio(1);
      #pragma unroll
      for(int ni=0;ni<4;++ni)
        #pragma unroll
        for(int mi=0;mi<4;++mi)
          acc[mi][ni]=__builtin_amdgcn_mfma_f32_16x16x32_bf16(av[mi],bv[ni],acc[mi][ni],0,0,0);
      __builtin_amdgcn_s_setprio(0);
    }
  };

  STAGE(0,0);
  STAGE(1,1);
  asm volatile("s_waitcnt vmcnt(8)" ::: "memory");
  __builtin_amdgcn_s_barrier();
  __builtin_amdgcn_sched_barrier(0);

  for(int t=0;t<NT;++t){
    COMPUTE(t&1);
    if(t+1<NT){
      __builtin_amdgcn_sched_barrier(0);
      __builtin_amdgcn_s_barrier();
      __builtin_amdgcn_sched_barrier(0);
      if(t+2<NT){
        STAGE(t&1, t+2);
        asm volatile("s_waitcnt vmcnt(8)" ::: "memory");
      }else{
        asm volatile("s_waitcnt vmcnt(0)" ::: "memory");
      }
      __builtin_amdgcn_s_barrier();
      __builtin_amdgcn_sched_barrier(0);
    }
  }

  #pragma unroll
  for(int mi=0;mi<4;++mi){
    const int ebase=e0+wr+mi*16+lg*4;
    const int tt=ebase>>lc, eib=ebase-(tt<<lc);
    const int inode=tt*NINT + xwoff + (eib>>2);
    const int par=ebase>>2;
    #pragma unroll
    for(int ni=0;ni<4;++ni){
      const int col=n0+wc+ni*16+lr;
      const float base=bias[col]+XWf[(size_t)inode*512+col];
      const size_t chbase=((size_t)tt*NPT+start_ch+eib)*HD+col;
      float s=0.f, hsv=0.f;
      #pragma unroll
      for(int r=0;r<4;++r){
        const size_t ci=chbase+(size_t)r*HD;
        float fv=sigm(acc[mi][ni][r]+base);
        s+=fv*cbuf[ci];
        hsv+=(float)hhi[ci]+(float)hlo[ci];
      }
      csum[(size_t)par*HD+col]=s;
      bf16 hh=(bf16)hsv;
      hs_hi[(size_t)par*HD+col]=hh;
      hs_lo[(size_t)par*HD+col]=(bf16)(hsv-(float)hh);
    }
  }
}

// ---------------- final head ----------------
__global__ __launch_bounds__(256)
void k_final2(const bf16* __restrict__ hhi, const bf16* __restrict__ hlo,
              const float* __restrict__ Wy, const float* __restrict__ gamma,
              const float* __restrict__ beta, float* __restrict__ out0, int Nn)
{
  const int gtid=blockIdx.x*256+threadIdx.x;
  const int node=gtid>>6, lane=gtid&63;
  if(node>=Nn) return;
  const size_t base=(size_t)node*HD+lane*8;
  bf16x8 hv=*(const bf16x8*)(hhi+base);
  bf16x8 lv=*(const bf16x8*)(hlo+base);
  float hf[8];
  #pragma unroll
  for(int e=0;e<8;++e) hf[e]=(float)hv[e]+(float)lv[e];
  float y[4];
  #pragma unroll
  for(int jj=0;jj<4;++jj){
    const float* wp=Wy+jj*HD+lane*8;
    float s=0.f;
    #pragma unroll
    for(int e=0;e<8;++e) s+=hf[e]*wp[e];
    #pragma unroll
    for(int off=32;off>=1;off>>=1) s+=__shfl_xor(s,off,64);
    y[jj]=s;
  }
  if(lane==0){
    float mu=0.25f*(y[0]+y[1]+y[2]+y[3]);
    float var=0.f;
    #pragma unroll
    for(int jj=0;jj<4;++jj){ float d=y[jj]-mu; var+=d*d; }
    var*=0.25f;
    float rs=rsqrtf(var+1e-6f);
    float z[4], zmax=-1e30f;
    #pragma unroll
    for(int jj=0;jj<4;++jj){ z[jj]=(y[jj]-mu)*rs*gamma[jj]+beta[jj]; zmax=fmaxf(zmax,z[jj]); }
    float es=0.f;
    #pragma unroll
    for(int jj=0;jj<4;++jj){ z[jj]=__expf(z[jj]-zmax); es+=z[jj]; }
    float inv=1.f/es;
    #pragma unroll
    for(int jj=0;jj<4;++jj) out0[(size_t)node*4+jj]=z[jj]*inv;
  }
}

// ---------------- root head ----------------
__global__ __launch_bounds__(256)
void k_root(const bf16* __restrict__ hhi, const bf16* __restrict__ hlo,
            const float* __restrict__ Wff, float* __restrict__ out1)
{
  const int gtid=blockIdx.x*256+threadIdx.x;
  const int tt=gtid>>6, lane=gtid&63;
  if(tt>=64) return;
  const size_t base=((size_t)tt*NPT+1364)*HD+lane*8;
  bf16x8 hv=*(const bf16x8*)(hhi+base);
  bf16x8 lv=*(const bf16x8*)(hlo+base);
  float hf[8];
  #pragma unroll
  for(int e=0;e<8;++e) hf[e]=(float)hv[e]+(float)lv[e];
  float y[4];
  #pragma unroll
  for(int jj=0;jj<4;++jj){
    const float* wp=Wff+jj*HD+lane*8;
    float s=0.f;
    #pragma unroll
    for(int e=0;e<8;++e) s+=hf[e]*wp[e];
    #pragma unroll
    for(int off=32;off>=1;off>>=1) s+=__shfl_xor(s,off,64);
    y[jj]=s;
  }
  if(lane==0){
    float zmax=fmaxf(fmaxf(y[0],y[1]),fmaxf(y[2],y[3]));
    float es=0.f, z[4];
    #pragma unroll
    for(int jj=0;jj<4;++jj){ z[jj]=__expf(y[jj]-zmax); es+=z[jj]; }
    float inv=1.f/es;
    #pragma unroll
    for(int jj=0;jj<4;++jj) out1[(size_t)tt*4+jj]=z[jj]*inv;
  }
}

extern "C" void kernel_launch(void* const* d_in, const int* in_sizes, int n_in,
                              void* d_out, int out_size, void* d_ws, size_t ws_size,
                              hipStream_t stream)
{
  const float* features=(const float*)d_in[0];
  const float* W_iou=(const float*)d_in[6];
  const float* b_iou=(const float*)d_in[7];
  const float* U_iou=(const float*)d_in[8];
  const float* W_f  =(const float*)d_in[9];
  const float* b_f  =(const float*)d_in[10];
  const float* U_f  =(const float*)d_in[11];
  const float* W_ff =(const float*)d_in[12];
  const float* W_sd =(const float*)d_in[13];
  const float* W_sd2=(const float*)d_in[14];
  const float* W_sf =(const float*)d_in[15];
  const float* ln_g =(const float*)d_in[16];
  const float* ln_b =(const float*)d_in[17];

  const int N=in_sizes[0]/768;   // 87360
  const int T=N/NPT;             // 64
  const int MINT=T*NINT;         // 21824

  float* out0=(float*)d_out;
  float* out1=out0+(size_t)N*4;
  float* cbuf=out1+(size_t)T*4;  // c output region (live c-state)

  char* p=(char*)d_ws;
  auto alloc=[&](size_t bytes){ char* r=p; p+=((bytes+255)&~(size_t)255); return r; };
  bf16*  f_hi =(bf16*) alloc((size_t)N*768*2);
  bf16*  f_lo =(bf16*) alloc((size_t)N*768*2);
  bf16*  hs_hi=(bf16*) alloc((size_t)16384*HD*2);
  bf16*  hs_lo=(bf16*) alloc((size_t)16384*HD*2);
  float* csum =(float*)alloc((size_t)16384*HD*4);
  bf16*  h_hi =(bf16*) alloc((size_t)N*HD*2);
  bf16*  h_lo =(bf16*) alloc((size_t)N*HD*2);
  bf16*  WilL =(bf16*) alloc((size_t)1536*1536*2);
  bf16*  WilI =(bf16*) alloc((size_t)1536*2560*2);
  bf16*  WcatI=(bf16*) alloc((size_t)1536*3840*2);   // level-5 64-tile layout (first 2560 used)
  bf16*  Wfc  =(bf16*) alloc((size_t)512*1536*2);
  bf16*  Ufc  =(bf16*) alloc((size_t)512*1024*2);
  float* Wcomb=(float*)alloc((size_t)512*512*4);
  float* Wy   =(float*)alloc((size_t)4*512*4);
  float* XWf  =(float*)alloc((size_t)MINT*512*4);

  // conversions / weight prep
  { size_t n8=(size_t)N*768/8;  k_split8<<<(int)((n8+255)/256),256,0,stream>>>(features,f_hi,f_lo,n8); }
  { size_t n=(size_t)1536*1536; k_wil<<<(int)((n+255)/256),256,0,stream>>>(W_iou,U_iou,WilL,0); }
  { size_t n=(size_t)1536*2560; k_wil<<<(int)((n+255)/256),256,0,stream>>>(W_iou,U_iou,WilI,1); }
  { size_t n=(size_t)1536*3840; k_concatHL3840<<<(int)((n+255)/256),256,0,stream>>>(W_iou,U_iou,WcatI,1536); }
  { size_t n=(size_t)512*1536;  k_catHL<<<(int)((n+255)/256),256,0,stream>>>(W_f,Wfc,512,768); }
  { size_t n=(size_t)512*1024;  k_catHL<<<(int)((n+255)/256),256,0,stream>>>(U_f,Ufc,512,512); }
  { dim3 g(8,8); k_wcomb<<<g,256,0,stream>>>(W_sd2,W_sd,Wcomb); }
  { k_wy<<<8,256,0,stream>>>(W_sf,Wcomb,Wy); }

  // upfront: XWf for all internal nodes (pipelined)
  { dim3 g(4,(MINT+127)/128);
    k_xwf128p<<<g,256,G128_LDS,stream>>>(f_hi,f_lo,Wfc,XWf,MINT); }

  static const int starts[6]={0,1024,1280,1344,1360,1364};
  static const int csh[6]  ={10,8,6,4,2,0};
  static const int counts[6]={1024,256,64,16,4,1};
  static const int xwoffs[6]={0,0,256,320,336,340};

  // level 0 (leaves): 128x192 pipelined kernel, counted vmcnt
  { dim3 g(8,(T*1024)/128);
    k_iou128p<<<g,256,IOU_LDS,stream>>>(f_hi,f_lo,hs_hi,hs_lo,WilL,b_iou,csum,h_hi,h_lo,cbuf,0,10,0); }

  for(int n=1;n<6;++n){
    int P=T*counts[n], E=T*counts[n-1];
    { dim3 g(4,E/128);
      k_uh128p<<<g,256,G128_LDS,stream>>>(h_hi,h_lo,Ufc,b_f,XWf,cbuf,csum,hs_hi,hs_lo,
                                          starts[n-1],csh[n-1],xwoffs[n]); }
    if(P>=128){
      dim3 g(8,P/128);
      k_iou128p<<<g,256,IOU_LDS,stream>>>(f_hi,f_lo,hs_hi,hs_lo,WilI,b_iou,csum,h_hi,h_lo,cbuf,starts[n],csh[n],1);
    }else{
      dim3 g(P/64,8);
      k_iou<<<g,256,0,stream>>>(f_hi,f_lo,hs_hi,hs_lo,WcatI,b_iou,csum,h_hi,h_lo,cbuf,starts[n],csh[n],2560,3840,1);
    }
  }

  // heads (stance folded into Wy)
  { int th=N*64; k_final2<<<(th+255)/256,256,0,stream>>>(h_hi,h_lo,Wy,ln_g,ln_b,out0,N); }
  { k_root<<<16,256,0,stream>>>(h_hi,h_lo,W_ff,out1); }
}

// Round 17
// 1517.850 us; speedup vs baseline: 1.6205x; 1.0156x over previous
//
#include <hip/hip_runtime.h>
#include <hip/hip_bf16.h>
#include <math.h>

typedef __bf16 bf16;
typedef bf16 bf16x8 __attribute__((ext_vector_type(8)));
typedef float f32x4 __attribute__((ext_vector_type(4)));

#define NPT 1365
#define HD 512
#define NINT 341   // internal nodes per tree (256+64+16+4+1)
#define IOU_LDS (2*128*64*2 + 2*192*64*2)   // 81920 B -> 2 blocks/CU
#define G128_LDS (2*128*64*2 + 2*128*64*2)  // 65536 B -> 2 blocks/CU

__device__ __forceinline__ float sigm(float x){ return 1.0f/(1.0f+__expf(-x)); }

__device__ __forceinline__ void gll16(const void* g, void* l){
  __builtin_amdgcn_global_load_lds((const __attribute__((address_space(1))) void*)g,
                                   (__attribute__((address_space(3))) void*)l, 16, 0, 0);
}

// XCD-chunked bijection: phys%8 = XCD; give each XCD a contiguous y-range with all x.
// requires (nb%8==0 && ytiles%8==0); else identity.
__device__ __forceinline__ void xcd_map(int phys, int nb, int xdim, int& x, int& my){
  int ytiles = nb / xdim;
  if((ytiles & 7)==0){
    int k = phys & 7, i = phys >> 3;
    my = k * (ytiles >> 3) + i / xdim;
    x  = i % xdim;
  }else{
    x  = phys % xdim;
    my = phys / xdim;
  }
}

// ---------------- split fp32 -> bf16 hi/lo, 8 elems/thread ----------------
__global__ void k_split8(const float* __restrict__ s, bf16* __restrict__ hi,
                         bf16* __restrict__ lo, size_t n8){
  size_t i=(size_t)blockIdx.x*blockDim.x+threadIdx.x;
  if(i>=n8) return;
  const float4* sp=(const float4*)(s+i*8);
  float4 a=sp[0], b=sp[1];
  float v[8]={a.x,a.y,a.z,a.w,b.x,b.y,b.z,b.w};
  bf16x8 h,l;
  #pragma unroll
  for(int e=0;e<8;++e){ bf16 hh=(bf16)v[e]; h[e]=hh; l[e]=(bf16)(v[e]-(float)hh); }
  *(bf16x8*)(hi+i*8)=h;
  *(bf16x8*)(lo+i*8)=l;
}

// ---------------- generic [hi|lo] row concat ----------------
__global__ void k_catHL(const float* __restrict__ S, bf16* __restrict__ d,
                        int rows, int Ksrc){
  size_t i=(size_t)blockIdx.x*blockDim.x+threadIdx.x;
  int K=2*Ksrc;
  size_t tot=(size_t)rows*K;
  if(i>=tot) return;
  int r=(int)(i/K); int k=(int)(i-(size_t)r*K);
  float v=S[(size_t)r*Ksrc + (k<Ksrc?k:k-Ksrc)];
  bf16 h=(bf16)v;
  d[i]=(k<Ksrc)? h : (bf16)(v-(float)h);
}

// ---------------- gate-interleaved iou weights, hi-only products ----------------
__global__ void k_wil(const float* __restrict__ W, const float* __restrict__ U,
                      bf16* __restrict__ d, int internal){
  const int K = internal? 2560 : 1536;
  size_t i=(size_t)blockIdx.x*blockDim.x+threadIdx.x;
  size_t tot=(size_t)1536*K;
  if(i>=tot) return;
  int rp=(int)(i/K); int k=(int)(i-(size_t)rp*K);
  int f=rp>>4, rr=rp&15;
  int g=f%3, cgrp=f/3;
  int orig=g*512+cgrp*16+rr;
  float v;
  if(internal){
    if(k<768)        v=W[(size_t)orig*768+k];
    else if(k<1536)  v=W[(size_t)orig*768+(k-768)];
    else if(k<2048)  v=U[(size_t)orig*512+(k-1536)];
    else             v=U[(size_t)orig*512+(k-2048)];
  }else{
    int kk=(k<768)?k:k-768;
    v=W[(size_t)orig*768+kk];
  }
  d[i]=(bf16)v;
}

// ---------------- old-layout concat K=3840 (level-5 64-tile iou; first 2560 used) ----------------
__global__ void k_concatHL3840(const float* __restrict__ W, const float* __restrict__ U,
                               bf16* __restrict__ d, int rows){
  size_t i=(size_t)blockIdx.x*blockDim.x+threadIdx.x;
  const int K=3840;
  size_t tot=(size_t)rows*K;
  if(i>=tot) return;
  int r=(int)(i/K); int k=(int)(i-(size_t)r*K);
  float v; int lo=0;
  if(k<768)        v=W[(size_t)r*768+k];
  else if(k<1536)  v=W[(size_t)r*768+(k-768)];
  else if(k<2048)  v=U[(size_t)r*512+(k-1536)];
  else if(k<2560)  v=U[(size_t)r*512+(k-2048)];
  else if(k<3328){ v=W[(size_t)r*768+(k-2560)]; lo=1; }
  else           { v=U[(size_t)r*512+(k-3328)]; lo=1; }
  bf16 h=(bf16)v;
  d[i]= lo ? (bf16)(v-(float)h) : h;
}

// ---------------- Wcomb = W_sd2 @ W_sd  (512x512, fp32 exact) ----------------
__global__ __launch_bounds__(256)
void k_wcomb(const float* __restrict__ W2, const float* __restrict__ W1,
             float* __restrict__ out){
  __shared__ float As[64][33];
  __shared__ float Bs[32][65];
  const int tid=threadIdx.x;
  const int i0=blockIdx.x*64, j0=blockIdx.y*64;
  const int tr=(tid>>4)*4, tc=(tid&15)*4;
  float acc[4][4];
  #pragma unroll
  for(int x=0;x<4;++x)
    #pragma unroll
    for(int y=0;y<4;++y) acc[x][y]=0.f;
  for(int k0=0;k0<1024;k0+=32){
    for(int l=tid;l<64*32;l+=256){ int r=l>>5,c=l&31; As[r][c]=W2[(size_t)(i0+r)*1024+k0+c]; }
    for(int l=tid;l<32*64;l+=256){ int r=l>>6,c=l&63; Bs[r][c]=W1[(size_t)(k0+r)*512+j0+c]; }
    __syncthreads();
    #pragma unroll 8
    for(int k=0;k<32;++k){
      float a[4],b[4];
      #pragma unroll
      for(int x=0;x<4;++x){ a[x]=As[tr+x][k]; b[x]=Bs[k][tc+x]; }
      #pragma unroll
      for(int x=0;x<4;++x)
        #pragma unroll
        for(int y=0;y<4;++y) acc[x][y]+=a[x]*b[y];
    }
    __syncthreads();
  }
  #pragma unroll
  for(int x=0;x<4;++x)
    #pragma unroll
    for(int y=0;y<4;++y) out[(size_t)(i0+tr+x)*512+j0+tc+y]=acc[x][y];
}

// ---------------- Wy[j,c] = Wsf[j,c] + sum_d Wsf[j,d]*Wcomb[d,c] ----------------
__global__ void k_wy(const float* __restrict__ Wsf, const float* __restrict__ Wcomb,
                     float* __restrict__ Wy){
  int idx=blockIdx.x*256+threadIdx.x;
  if(idx>=2048) return;
  int j=idx>>9, c=idx&511;
  float s=Wsf[j*512+c];
  for(int d=0;d<512;++d) s+=Wsf[j*512+d]*Wcomb[(size_t)d*512+c];
  Wy[(size_t)j*512+c]=s;
}

// ================= iou GEMM: 128 x 192, dbuf + counted vmcnt + setprio, XCD-chunked =================
__global__ __launch_bounds__(256,2)
void k_iou128p(const bf16* __restrict__ fH, const bf16* __restrict__ fL,
               const bf16* __restrict__ hsH, const bf16* __restrict__ hsL,
               const bf16* __restrict__ Wil, const float* __restrict__ bias,
               const float* __restrict__ csum, bf16* __restrict__ hbuf,
               bf16* __restrict__ hlo, float* __restrict__ cbuf,
               int start_n, int shift, int internal)
{
  extern __shared__ char sm[];                 // A: 2x16384, B: 2x24576
  char* Abase=sm;
  char* Bbase=sm+32768;
  const int tid=threadIdx.x;
  const int w=tid>>6, lane=tid&63;
  int x, my;
  xcd_map(blockIdx.x, gridDim.x, 8, x, my);
  const int m0=my*128;
  const int K = internal? 2560 : 1536;
  const int NT = K>>6;

  unsigned fofs[4], hofs[4];
  #pragma unroll
  for(int i=0;i<4;++i){
    int r=w*32+i*8+(lane>>3);
    int m=m0+r;
    int t_=m>>shift, j=m-(t_<<shift);
    fofs[i]=(unsigned)(((size_t)t_*NPT+start_n+j)*768);
    hofs[i]=(unsigned)m*512u;
  }
  unsigned bofs[6];
  #pragma unroll
  for(int i=0;i<6;++i){
    int r=x*192+w*48+i*8+(lane>>3);
    bofs[i]=(unsigned)r*(unsigned)K;
  }
  const unsigned swz=8u*((unsigned)(lane&7)^(unsigned)(lane>>3));

  f32x4 acc[4][6];
  #pragma unroll
  for(int mi=0;mi<4;++mi)
    #pragma unroll
    for(int ni=0;ni<6;++ni) acc[mi][ni]=(f32x4){0.f,0.f,0.f,0.f};

  const int wr=(w>>1)*64;
  const int wcF=(w&1)*6;
  const int lr=lane&15, lg=lane>>4;

  auto STAGE=[&](int buf, int t){
    const bf16* base; int kt; bool useF;
    if(internal){
      if(t<12){ base=fH; kt=t;    useF=true; }
      else if(t<24){ base=fL; kt=t-12; useF=true; }
      else if(t<32){ base=hsH; kt=t-24; useF=false; }
      else        { base=hsL; kt=t-32; useF=false; }
    }else{
      if(t<12){ base=fH; kt=t;    useF=true; }
      else    { base=fL; kt=t-12; useF=true; }
    }
    const unsigned kofs=(unsigned)kt*64u+swz;
    char* Ad=Abase+(size_t)buf*16384;
    #pragma unroll
    for(int i=0;i<4;++i){
      const bf16* g=base+(useF?fofs[i]:hofs[i])+kofs;
      gll16(g, Ad+(w*32+i*8)*128);
    }
    const unsigned bk=(unsigned)t*64u+swz;
    char* Bd=Bbase+(size_t)buf*24576;
    #pragma unroll
    for(int i=0;i<6;++i){
      gll16(Wil+bofs[i]+bk, Bd+(w*48+i*8)*128);
    }
  };

  auto COMPUTE=[&](int cur){
    const char* Ab=Abase+(size_t)cur*16384;
    const char* Bb=Bbase+(size_t)cur*24576;
    #pragma unroll
    for(int ks=0;ks<2;++ks){
      const unsigned cb=((unsigned)(ks*64+lg*16)) ^ ((unsigned)(lr&7)<<4);
      bf16x8 av[4], bv[6];
      #pragma unroll
      for(int mi=0;mi<4;++mi)
        av[mi]=*(const bf16x8*)(Ab+(unsigned)(wr+mi*16+lr)*128u+cb);
      #pragma unroll
      for(int ni=0;ni<6;++ni)
        bv[ni]=*(const bf16x8*)(Bb+(unsigned)((wcF+ni)*16+lr)*128u+cb);
      __builtin_amdgcn_s_setprio(1);
      #pragma unroll
      for(int ni=0;ni<6;++ni)
        #pragma unroll
        for(int mi=0;mi<4;++mi)
          acc[mi][ni]=__builtin_amdgcn_mfma_f32_16x16x32_bf16(av[mi],bv[ni],acc[mi][ni],0,0,0);
      __builtin_amdgcn_s_setprio(0);
    }
  };

  STAGE(0,0);
  STAGE(1,1);
  asm volatile("s_waitcnt vmcnt(10)" ::: "memory");
  __builtin_amdgcn_s_barrier();
  __builtin_amdgcn_sched_barrier(0);

  for(int t=0;t<NT;++t){
    COMPUTE(t&1);
    if(t+1<NT){
      __builtin_amdgcn_sched_barrier(0);
      __builtin_amdgcn_s_barrier();
      __builtin_amdgcn_sched_barrier(0);
      if(t+2<NT){
        STAGE(t&1, t+2);
        asm volatile("s_waitcnt vmcnt(10)" ::: "memory");
      }else{
        asm volatile("s_waitcnt vmcnt(0)" ::: "memory");
      }
      __builtin_amdgcn_s_barrier();
      __builtin_amdgcn_sched_barrier(0);
    }
  }

  #pragma unroll
  for(int mi=0;mi<4;++mi){
    #pragma unroll
    for(int cg=0;cg<2;++cg){
      const int col = x*64 + ((w&1)*2+cg)*16 + lr;
      const float bi=bias[col], bo=bias[col+512], bu=bias[col+1024];
      #pragma unroll
      for(int r=0;r<4;++r){
        const int mm=m0+wr+mi*16+lg*4+r;
        float iv=acc[mi][3*cg+0][r]+bi;
        float ov=acc[mi][3*cg+1][r]+bo;
        float uv=acc[mi][3*cg+2][r]+bu;
        float cn=sigm(iv)*tanhf(uv);
        if(internal) cn+=csum[(size_t)mm*HD+col];
        float hn=sigm(ov)*tanhf(cn);
        const int tt=mm>>shift, jj=mm-(tt<<shift);
        const size_t nd=((size_t)tt*NPT+start_n+jj)*HD+col;
        cbuf[nd]=cn;
        bf16 hh=(bf16)hn;
        hbuf[nd]=hh;
        hlo[nd]=(bf16)(hn-(float)hh);
      }
    }
  }
}

// ---------------- old 64-tile iou (level 5 only, P=64; K=2560 prefix of 3840 layout) ----------------
__global__ __launch_bounds__(256)
void k_iou(const bf16* __restrict__ fH, const bf16* __restrict__ fL,
           const bf16* __restrict__ hsH, const bf16* __restrict__ hsL,
           const bf16* __restrict__ Wcat, const float* __restrict__ bias,
           const float* __restrict__ csum, bf16* __restrict__ hbuf,
           bf16* __restrict__ hlo, float* __restrict__ cbuf,
           int start_n, int shift, int K, int KB, int internal)
{
  __shared__ bf16 As[64][40];
  __shared__ bf16 Bs[3][64][40];
  const int tid=threadIdx.x;
  const int m0=blockIdx.x*64, n0=blockIdx.y*64;
  const int srow=tid>>2, skc=(tid&3)*8;
  const int m=m0+srow;
  const int t=m>>shift, j=m-(t<<shift);
  const size_t frow=((size_t)t*NPT+start_n+j)*768;
  const bf16* aFH=fH+frow;
  const bf16* aFL=fL+frow;
  const bf16* aHH=hsH+(size_t)m*HD;
  const bf16* aHL=hsL+(size_t)m*HD;
  const bf16* bp0=Wcat+(size_t)(n0+srow)*KB;
  const bf16* bp1=Wcat+(size_t)(512+n0+srow)*KB;
  const bf16* bp2=Wcat+(size_t)(1024+n0+srow)*KB;

  f32x4 acc[3][2][2];
  #pragma unroll
  for(int g=0;g<3;++g)
    #pragma unroll
    for(int mi=0;mi<2;++mi)
      #pragma unroll
      for(int ni=0;ni<2;++ni) acc[g][mi][ni]=(f32x4){0.f,0.f,0.f,0.f};

  const int w=tid>>6, lane=tid&63;
  const int wr=(w>>1)*32, wc=(w&1)*32;
  const int lr=lane&15, lg=lane>>4;

  for(int k0=0;k0<K;k0+=32){
    const bf16* ap;
    if(internal){
      if(k0<768)        ap=aFH+k0;
      else if(k0<1536)  ap=aFL+(k0-768);
      else if(k0<2048)  ap=aHH+(k0-1536);
      else              ap=aHL+(k0-2048);
    }else{
      ap=(k0<768)? (aFH+k0) : (aFL+(k0-768));
    }
    *(bf16x8*)&As[srow][skc]=*(const bf16x8*)(ap+skc);
    *(bf16x8*)&Bs[0][srow][skc]=*(const bf16x8*)(bp0+k0+skc);
    *(bf16x8*)&Bs[1][srow][skc]=*(const bf16x8*)(bp1+k0+skc);
    *(bf16x8*)&Bs[2][srow][skc]=*(const bf16x8*)(bp2+k0+skc);
    __syncthreads();
    bf16x8 a0=*(bf16x8*)&As[wr+lr][lg*8];
    bf16x8 a1=*(bf16x8*)&As[wr+16+lr][lg*8];
    #pragma unroll
    for(int g=0;g<3;++g){
      #pragma unroll
      for(int ni=0;ni<2;++ni){
        bf16x8 bv=*(bf16x8*)&Bs[g][wc+ni*16+lr][lg*8];
        acc[g][0][ni]=__builtin_amdgcn_mfma_f32_16x16x32_bf16(a0,bv,acc[g][0][ni],0,0,0);
        acc[g][1][ni]=__builtin_amdgcn_mfma_f32_16x16x32_bf16(a1,bv,acc[g][1][ni],0,0,0);
      }
    }
    __syncthreads();
  }

  #pragma unroll
  for(int mi=0;mi<2;++mi){
    #pragma unroll
    for(int ni=0;ni<2;++ni){
      const int col=n0+wc+ni*16+lr;
      const float bi=bias[col], bo=bias[col+512], bu=bias[col+1024];
      #pragma unroll
      for(int r=0;r<4;++r){
        const int mm=m0+wr+mi*16+lg*4+r;
        float iv=acc[0][mi][ni][r]+bi;
        float ov=acc[1][mi][ni][r]+bo;
        float uv=acc[2][mi][ni][r]+bu;
        float cn=sigm(iv)*tanhf(uv);
        if(internal) cn+=csum[(size_t)mm*HD+col];
        float hn=sigm(ov)*tanhf(cn);
        const int tt=mm>>shift, jj=mm-(tt<<shift);
        const size_t nd=((size_t)tt*NPT+start_n+jj)*HD+col;
        cbuf[nd]=cn;
        bf16 hh=(bf16)hn;
        hbuf[nd]=hh;
        hlo[nd]=(bf16)(hn-(float)hh);
      }
    }
  }
}

// ================= XWf: pipelined 128x128 (NT=24), 1D grid =================
__global__ __launch_bounds__(256,2)
void k_xwf128p(const bf16* __restrict__ fH, const bf16* __restrict__ fL,
               const bf16* __restrict__ Wfc, float* __restrict__ XWf, int Mtot)
{
  extern __shared__ char sm[];     // A: 2x16384, B: 2x16384
  char* Abase=sm;
  char* Bbase=sm+32768;
  const int tid=threadIdx.x;
  const int w=tid>>6, lane=tid&63;
  int xb, my;
  xcd_map(blockIdx.x, gridDim.x, 4, xb, my);
  const int m0=my*128, n0=xb*128;
  const int NT=24;

  unsigned fofs[4];
  #pragma unroll
  for(int i=0;i<4;++i){
    int r=w*32+i*8+(lane>>3);
    int m=m0+r; if(m>=Mtot) m=Mtot-1;
    int t=m/NINT; int j=1024+(m-t*NINT);
    fofs[i]=(unsigned)(((size_t)t*NPT+j)*768);
  }
  unsigned bofs[4];
  #pragma unroll
  for(int i=0;i<4;++i){
    int r=n0+w*32+i*8+(lane>>3);
    bofs[i]=(unsigned)r*1536u;
  }
  const unsigned swz=8u*((unsigned)(lane&7)^(unsigned)(lane>>3));

  f32x4 acc[4][4];
  #pragma unroll
  for(int mi=0;mi<4;++mi)
    #pragma unroll
    for(int ni=0;ni<4;++ni) acc[mi][ni]=(f32x4){0.f,0.f,0.f,0.f};

  const int wr=(w>>1)*64, wc=(w&1)*64;
  const int lr=lane&15, lg=lane>>4;

  auto STAGE=[&](int buf, int t){
    const bf16* Abuf; unsigned ak, bk;
    if(t<12){ Abuf=fH; ak=(unsigned)t*64u; bk=(unsigned)t*64u; }
    else    { Abuf=fL; ak=(unsigned)(t-12)*64u; bk=(unsigned)(t-12)*64u; }
    char* Ad=Abase+(size_t)buf*16384;
    #pragma unroll
    for(int i=0;i<4;++i)
      gll16(Abuf+fofs[i]+ak+swz, Ad+(w*32+i*8)*128);
    char* Bd=Bbase+(size_t)buf*16384;
    #pragma unroll
    for(int i=0;i<4;++i)
      gll16(Wfc+bofs[i]+bk+swz, Bd+(w*32+i*8)*128);
  };

  auto COMPUTE=[&](int cur){
    const char* Ab=Abase+(size_t)cur*16384;
    const char* Bb=Bbase+(size_t)cur*16384;
    #pragma unroll
    for(int ks=0;ks<2;++ks){
      const unsigned cb=((unsigned)(ks*64+lg*16)) ^ ((unsigned)(lr&7)<<4);
      bf16x8 av[4], bv[4];
      #pragma unroll
      for(int mi=0;mi<4;++mi)
        av[mi]=*(const bf16x8*)(Ab+(unsigned)(wr+mi*16+lr)*128u+cb);
      #pragma unroll
      for(int ni=0;ni<4;++ni)
        bv[ni]=*(const bf16x8*)(Bb+(unsigned)((wc+ni*16)+lr)*128u+cb);
      __builtin_amdgcn_s_setprio(1);
      #pragma unroll
      for(int ni=0;ni<4;++ni)
        #pragma unroll
        for(int mi=0;mi<4;++mi)
          acc[mi][ni]=__builtin_amdgcn_mfma_f32_16x16x32_bf16(av[mi],bv[ni],acc[mi][ni],0,0,0);
      __builtin_amdgcn_s_setprio(0);
    }
  };

  STAGE(0,0);
  STAGE(1,1);
  asm volatile("s_waitcnt vmcnt(8)" ::: "memory");
  __builtin_amdgcn_s_barrier();
  __builtin_amdgcn_sched_barrier(0);

  for(int t=0;t<NT;++t){
    COMPUTE(t&1);
    if(t+1<NT){
      __builtin_amdgcn_sched_barrier(0);
      __builtin_amdgcn_s_barrier();
      __builtin_amdgcn_sched_barrier(0);
      if(t+2<NT){
        STAGE(t&1, t+2);
        asm volatile("s_waitcnt vmcnt(8)" ::: "memory");
      }else{
        asm volatile("s_waitcnt vmcnt(0)" ::: "memory");
      }
      __builtin_amdgcn_s_barrier();
      __builtin_amdgcn_sched_barrier(0);
    }
  }

  #pragma unroll
  for(int mi=0;mi<4;++mi){
    #pragma unroll
    for(int ni=0;ni<4;++ni){
      const int col=n0+wc+ni*16+lr;
      #pragma unroll
      for(int r=0;r<4;++r){
        const int mm=m0+wr+mi*16+lg*4+r;
        if(mm<Mtot) XWf[(size_t)mm*512+col]=acc[mi][ni][r];
      }
    }
  }
}

// ================= Uh forget-gate: pipelined 128x128 (NT=16) + fused csum/hsum, XCD-chunked =================
__global__ __launch_bounds__(256,2)
void k_uh128p(const bf16* __restrict__ hhi, const bf16* __restrict__ hlo,
              const bf16* __restrict__ Ufc, const float* __restrict__ bias,
              const float* __restrict__ XWf, const float* __restrict__ cbuf,
              float* __restrict__ csum, bf16* __restrict__ hs_hi, bf16* __restrict__ hs_lo,
              int start_ch, int lc, int xwoff)
{
  extern __shared__ char sm[];     // A: 2x16384, B: 2x16384
  char* Abase=sm;
  char* Bbase=sm+32768;
  const int tid=threadIdx.x;
  const int w=tid>>6, lane=tid&63;
  int xb, my;
  xcd_map(blockIdx.x, gridDim.x, 4, xb, my);
  const int e0=my*128, n0=xb*128;
  const int NT=16;

  unsigned hofs[4];
  #pragma unroll
  for(int i=0;i<4;++i){
    int r=w*32+i*8+(lane>>3);
    int e=e0+r;
    int t=e>>lc, ei=e-(t<<lc);
    hofs[i]=(unsigned)(((size_t)t*NPT+start_ch+ei)*HD);
  }
  unsigned bofs[4];
  #pragma unroll
  for(int i=0;i<4;++i){
    int r=n0+w*32+i*8+(lane>>3);
    bofs[i]=(unsigned)r*1024u;
  }
  const unsigned swz=8u*((unsigned)(lane&7)^(unsigned)(lane>>3));

  f32x4 acc[4][4];
  #pragma unroll
  for(int mi=0;mi<4;++mi)
    #pragma unroll
    for(int ni=0;ni<4;++ni) acc[mi][ni]=(f32x4){0.f,0.f,0.f,0.f};

  const int wr=(w>>1)*64, wc=(w&1)*64;
  const int lr=lane&15, lg=lane>>4;

  auto STAGE=[&](int buf, int t){
    const bf16* Abuf; unsigned ak, bk;
    if(t<8){ Abuf=hhi; ak=(unsigned)t*64u; bk=(unsigned)t*64u; }
    else   { Abuf=hlo; ak=(unsigned)(t-8)*64u; bk=(unsigned)(t-8)*64u; }
    char* Ad=Abase+(size_t)buf*16384;
    #pragma unroll
    for(int i=0;i<4;++i)
      gll16(Abuf+hofs[i]+ak+swz, Ad+(w*32+i*8)*128);
    char* Bd=Bbase+(size_t)buf*16384;
    #pragma unroll
    for(int i=0;i<4;++i)
      gll16(Ufc+bofs[i]+bk+swz, Bd+(w*32+i*8)*128);
  };

  auto COMPUTE=[&](int cur){
    const char* Ab=Abase+(size_t)cur*16384;
    const char* Bb=Bbase+(size_t)cur*16384;
    #pragma unroll
    for(int ks=0;ks<2;++ks){
      const unsigned cb=((unsigned)(ks*64+lg*16)) ^ ((unsigned)(lr&7)<<4);
      bf16x8 av[4], bv[4];
      #pragma unroll
      for(int mi=0;mi<4;++mi)
        av[mi]=*(const bf16x8*)(Ab+(unsigned)(wr+mi*16+lr)*128u+cb);
      #pragma unroll
      for(int ni=0;ni<4;++ni)
        bv[ni]=*(const bf16x8*)(Bb+(unsigned)((wc+ni*16)+lr)*128u+cb);
      __builtin_amdgcn_s_setprio(1);
      #pragma unroll
      for(int ni=0;ni<4;++ni)
        #pragma unroll
        for(int mi=0;mi<4;++mi)
          acc[mi][ni]=__builtin_amdgcn_mfma_f32_16x16x32_bf16(av[mi],bv[ni],acc[mi][ni],0,0,0);
      __builtin_amdgcn_s_setprio(0);
    }
  };

  STAGE(0,0);
  STAGE(1,1);
  asm volatile("s_waitcnt vmcnt(8)" ::: "memory");
  __builtin_amdgcn_s_barrier();
  __builtin_amdgcn_sched_barrier(0);

  for(int t=0;t<NT;++t){
    COMPUTE(t&1);
    if(t+1<NT){
      __builtin_amdgcn_sched_barrier(0);
      __builtin_amdgcn_s_barrier();
      __builtin_amdgcn_sched_barrier(0);
      if(t+2<NT){
        STAGE(t&1, t+2);
        asm volatile("s_waitcnt vmcnt(8)" ::: "memory");
      }else{
        asm volatile("s_waitcnt vmcnt(0)" ::: "memory");
      }
      __builtin_amdgcn_s_barrier();
      __builtin_amdgcn_sched_barrier(0);
    }
  }

  #pragma unroll
  for(int mi=0;mi<4;++mi){
    const int ebase=e0+wr+mi*16+lg*4;
    const int tt=ebase>>lc, eib=ebase-(tt<<lc);
    const int inode=tt*NINT + xwoff + (eib>>2);
    const int par=ebase>>2;
    #pragma unroll
    for(int ni=0;ni<4;++ni){
      const int col=n0+wc+ni*16+lr;
      const float base=bias[col]+XWf[(size_t)inode*512+col];
      const size_t chbase=((size_t)tt*NPT+start_ch+eib)*HD+col;
      float s=0.f, hsv=0.f;
      #pragma unroll
      for(int r=0;r<4;++r){
        const size_t ci=chbase+(size_t)r*HD;
        float fv=sigm(acc[mi][ni][r]+base);
        s+=fv*cbuf[ci];
        hsv+=(float)hhi[ci]+(float)hlo[ci];
      }
      csum[(size_t)par*HD+col]=s;
      bf16 hh=(bf16)hsv;
      hs_hi[(size_t)par*HD+col]=hh;
      hs_lo[(size_t)par*HD+col]=(bf16)(hsv-(float)hh);
    }
  }
}

// ---------------- final head ----------------
__global__ __launch_bounds__(256)
void k_final2(const bf16* __restrict__ hhi, const bf16* __restrict__ hlo,
              const float* __restrict__ Wy, const float* __restrict__ gamma,
              const float* __restrict__ beta, float* __restrict__ out0, int Nn)
{
  const int gtid=blockIdx.x*256+threadIdx.x;
  const int node=gtid>>6, lane=gtid&63;
  if(node>=Nn) return;
  const size_t base=(size_t)node*HD+lane*8;
  bf16x8 hv=*(const bf16x8*)(hhi+base);
  bf16x8 lv=*(const bf16x8*)(hlo+base);
  float hf[8];
  #pragma unroll
  for(int e=0;e<8;++e) hf[e]=(float)hv[e]+(float)lv[e];
  float y[4];
  #pragma unroll
  for(int jj=0;jj<4;++jj){
    const float* wp=Wy+jj*HD+lane*8;
    float s=0.f;
    #pragma unroll
    for(int e=0;e<8;++e) s+=hf[e]*wp[e];
    #pragma unroll
    for(int off=32;off>=1;off>>=1) s+=__shfl_xor(s,off,64);
    y[jj]=s;
  }
  if(lane==0){
    float mu=0.25f*(y[0]+y[1]+y[2]+y[3]);
    float var=0.f;
    #pragma unroll
    for(int jj=0;jj<4;++jj){ float d=y[jj]-mu; var+=d*d; }
    var*=0.25f;
    float rs=rsqrtf(var+1e-6f);
    float z[4], zmax=-1e30f;
    #pragma unroll
    for(int jj=0;jj<4;++jj){ z[jj]=(y[jj]-mu)*rs*gamma[jj]+beta[jj]; zmax=fmaxf(zmax,z[jj]); }
    float es=0.f;
    #pragma unroll
    for(int jj=0;jj<4;++jj){ z[jj]=__expf(z[jj]-zmax); es+=z[jj]; }
    float inv=1.f/es;
    #pragma unroll
    for(int jj=0;jj<4;++jj) out0[(size_t)node*4+jj]=z[jj]*inv;
  }
}

// ---------------- root head ----------------
__global__ __launch_bounds__(256)
void k_root(const bf16* __restrict__ hhi, const bf16* __restrict__ hlo,
            const float* __restrict__ Wff, float* __restrict__ out1)
{
  const int gtid=blockIdx.x*256+threadIdx.x;
  const int tt=gtid>>6, lane=gtid&63;
  if(tt>=64) return;
  const size_t base=((size_t)tt*NPT+1364)*HD+lane*8;
  bf16x8 hv=*(const bf16x8*)(hhi+base);
  bf16x8 lv=*(const bf16x8*)(hlo+base);
  float hf[8];
  #pragma unroll
  for(int e=0;e<8;++e) hf[e]=(float)hv[e]+(float)lv[e];
  float y[4];
  #pragma unroll
  for(int jj=0;jj<4;++jj){
    const float* wp=Wff+jj*HD+lane*8;
    float s=0.f;
    #pragma unroll
    for(int e=0;e<8;++e) s+=hf[e]*wp[e];
    #pragma unroll
    for(int off=32;off>=1;off>>=1) s+=__shfl_xor(s,off,64);
    y[jj]=s;
  }
  if(lane==0){
    float zmax=fmaxf(fmaxf(y[0],y[1]),fmaxf(y[2],y[3]));
    float es=0.f, z[4];
    #pragma unroll
    for(int jj=0;jj<4;++jj){ z[jj]=__expf(y[jj]-zmax); es+=z[jj]; }
    float inv=1.f/es;
    #pragma unroll
    for(int jj=0;jj<4;++jj) out1[(size_t)tt*4+jj]=z[jj]*inv;
  }
}

extern "C" void kernel_launch(void* const* d_in, const int* in_sizes, int n_in,
                              void* d_out, int out_size, void* d_ws, size_t ws_size,
                              hipStream_t stream)
{
  const float* features=(const float*)d_in[0];
  const float* W_iou=(const float*)d_in[6];
  const float* b_iou=(const float*)d_in[7];
  const float* U_iou=(const float*)d_in[8];
  const float* W_f  =(const float*)d_in[9];
  const float* b_f  =(const float*)d_in[10];
  const float* U_f  =(const float*)d_in[11];
  const float* W_ff =(const float*)d_in[12];
  const float* W_sd =(const float*)d_in[13];
  const float* W_sd2=(const float*)d_in[14];
  const float* W_sf =(const float*)d_in[15];
  const float* ln_g =(const float*)d_in[16];
  const float* ln_b =(const float*)d_in[17];

  const int N=in_sizes[0]/768;   // 87360
  const int T=N/NPT;             // 64
  const int MINT=T*NINT;         // 21824

  float* out0=(float*)d_out;
  float* out1=out0+(size_t)N*4;
  float* cbuf=out1+(size_t)T*4;  // c output region (live c-state)

  char* p=(char*)d_ws;
  auto alloc=[&](size_t bytes){ char* r=p; p+=((bytes+255)&~(size_t)255); return r; };
  bf16*  f_hi =(bf16*) alloc((size_t)N*768*2);
  bf16*  f_lo =(bf16*) alloc((size_t)N*768*2);
  bf16*  hs_hi=(bf16*) alloc((size_t)16384*HD*2);
  bf16*  hs_lo=(bf16*) alloc((size_t)16384*HD*2);
  float* csum =(float*)alloc((size_t)16384*HD*4);
  bf16*  h_hi =(bf16*) alloc((size_t)N*HD*2);
  bf16*  h_lo =(bf16*) alloc((size_t)N*HD*2);
  bf16*  WilL =(bf16*) alloc((size_t)1536*1536*2);
  bf16*  WilI =(bf16*) alloc((size_t)1536*2560*2);
  bf16*  WcatI=(bf16*) alloc((size_t)1536*3840*2);
  bf16*  Wfc  =(bf16*) alloc((size_t)512*1536*2);
  bf16*  Ufc  =(bf16*) alloc((size_t)512*1024*2);
  float* Wcomb=(float*)alloc((size_t)512*512*4);
  float* Wy   =(float*)alloc((size_t)4*512*4);
  float* XWf  =(float*)alloc((size_t)MINT*512*4);

  // conversions / weight prep
  { size_t n8=(size_t)N*768/8;  k_split8<<<(int)((n8+255)/256),256,0,stream>>>(features,f_hi,f_lo,n8); }
  { size_t n=(size_t)1536*1536; k_wil<<<(int)((n+255)/256),256,0,stream>>>(W_iou,U_iou,WilL,0); }
  { size_t n=(size_t)1536*2560; k_wil<<<(int)((n+255)/256),256,0,stream>>>(W_iou,U_iou,WilI,1); }
  { size_t n=(size_t)1536*3840; k_concatHL3840<<<(int)((n+255)/256),256,0,stream>>>(W_iou,U_iou,WcatI,1536); }
  { size_t n=(size_t)512*1536;  k_catHL<<<(int)((n+255)/256),256,0,stream>>>(W_f,Wfc,512,768); }
  { size_t n=(size_t)512*1024;  k_catHL<<<(int)((n+255)/256),256,0,stream>>>(U_f,Ufc,512,512); }
  { dim3 g(8,8); k_wcomb<<<g,256,0,stream>>>(W_sd2,W_sd,Wcomb); }
  { k_wy<<<8,256,0,stream>>>(W_sf,Wcomb,Wy); }

  // upfront: XWf for all internal nodes (pipelined, 1D grid)
  { int nb=4*((MINT+127)/128);
    k_xwf128p<<<nb,256,G128_LDS,stream>>>(f_hi,f_lo,Wfc,XWf,MINT); }

  static const int starts[6]={0,1024,1280,1344,1360,1364};
  static const int csh[6]  ={10,8,6,4,2,0};
  static const int counts[6]={1024,256,64,16,4,1};
  static const int xwoffs[6]={0,0,256,320,336,340};

  // level 0 (leaves): XCD-chunked 1D grid
  { int nb=8*((T*1024)/128);
    k_iou128p<<<nb,256,IOU_LDS,stream>>>(f_hi,f_lo,hs_hi,hs_lo,WilL,b_iou,csum,h_hi,h_lo,cbuf,0,10,0); }

  for(int n=1;n<6;++n){
    int P=T*counts[n], E=T*counts[n-1];
    { int nb=4*(E/128);
      k_uh128p<<<nb,256,G128_LDS,stream>>>(h_hi,h_lo,Ufc,b_f,XWf,cbuf,csum,hs_hi,hs_lo,
                                           starts[n-1],csh[n-1],xwoffs[n]); }
    if(P>=128){
      int nb=8*(P/128);
      k_iou128p<<<nb,256,IOU_LDS,stream>>>(f_hi,f_lo,hs_hi,hs_lo,WilI,b_iou,csum,h_hi,h_lo,cbuf,starts[n],csh[n],1);
    }else{
      dim3 g(P/64,8);
      k_iou<<<g,256,0,stream>>>(f_hi,f_lo,hs_hi,hs_lo,WcatI,b_iou,csum,h_hi,h_lo,cbuf,starts[n],csh[n],2560,3840,1);
    }
  }

  // heads (stance folded into Wy)
  { int th=N*64; k_final2<<<(th+255)/256,256,0,stream>>>(h_hi,h_lo,Wy,ln_g,ln_b,out0,N); }
  { k_root<<<16,256,0,stream>>>(h_hi,h_lo,W_ff,out1); }
}

// Round 18
// 1405.737 us; speedup vs baseline: 1.7498x; 1.0798x over previous
//
#include <hip/hip_runtime.h>
#include <hip/hip_bf16.h>
#include <math.h>

typedef __bf16 bf16;
typedef bf16 bf16x8 __attribute__((ext_vector_type(8)));
typedef float f32x4 __attribute__((ext_vector_type(4)));

#define NPT 1365
#define HD 512
#define NINT 341   // internal nodes per tree (256+64+16+4+1)
#define IOU_LDS (2*128*64*2 + 2*192*64*2)   // 81920 B -> 2 blocks/CU
#define G128_LDS (2*128*64*2 + 2*128*64*2)  // 65536 B -> 2 blocks/CU

__device__ __forceinline__ float sigm(float x){ return 1.0f/(1.0f+__expf(-x)); }

__device__ __forceinline__ void gll16(const void* g, void* l){
  __builtin_amdgcn_global_load_lds((const __attribute__((address_space(1))) void*)g,
                                   (__attribute__((address_space(3))) void*)l, 16, 0, 0);
}

// XCD-chunked bijection: phys%8 = XCD; each XCD gets a contiguous y-range with all x.
__device__ __forceinline__ void xcd_map(int phys, int nb, int xdim, int& x, int& my){
  int ytiles = nb / xdim;
  if((ytiles & 7)==0){
    int k = phys & 7, i = phys >> 3;
    my = k * (ytiles >> 3) + i / xdim;
    x  = i % xdim;
  }else{
    x  = phys % xdim;
    my = phys / xdim;
  }
}

// ---------------- split fp32 -> bf16 hi/lo, 8 elems/thread ----------------
__global__ void k_split8(const float* __restrict__ s, bf16* __restrict__ hi,
                         bf16* __restrict__ lo, size_t n8){
  size_t i=(size_t)blockIdx.x*blockDim.x+threadIdx.x;
  if(i>=n8) return;
  const float4* sp=(const float4*)(s+i*8);
  float4 a=sp[0], b=sp[1];
  float v[8]={a.x,a.y,a.z,a.w,b.x,b.y,b.z,b.w};
  bf16x8 h,l;
  #pragma unroll
  for(int e=0;e<8;++e){ bf16 hh=(bf16)v[e]; h[e]=hh; l[e]=(bf16)(v[e]-(float)hh); }
  *(bf16x8*)(hi+i*8)=h;
  *(bf16x8*)(lo+i*8)=l;
}

// ---------------- generic [hi|lo] row concat (Wfc/Ufc; hi halves used) ----------------
__global__ void k_catHL(const float* __restrict__ S, bf16* __restrict__ d,
                        int rows, int Ksrc){
  size_t i=(size_t)blockIdx.x*blockDim.x+threadIdx.x;
  int K=2*Ksrc;
  size_t tot=(size_t)rows*K;
  if(i>=tot) return;
  int r=(int)(i/K); int k=(int)(i-(size_t)r*K);
  float v=S[(size_t)r*Ksrc + (k<Ksrc?k:k-Ksrc)];
  bf16 h=(bf16)v;
  d[i]=(k<Ksrc)? h : (bf16)(v-(float)h);
}

// ---------------- gate-interleaved iou weights ----------------
// leaf   (K=1536): [Whi | Whi]       -- fH*Whi + fL*Whi
// intern (K=2048): [Whi | Whi | Uhi] -- fH*Whi + fL*Whi + hsH*Uhi
__global__ void k_wil(const float* __restrict__ W, const float* __restrict__ U,
                      bf16* __restrict__ d, int internal){
  const int K = internal? 2048 : 1536;
  size_t i=(size_t)blockIdx.x*blockDim.x+threadIdx.x;
  size_t tot=(size_t)1536*K;
  if(i>=tot) return;
  int rp=(int)(i/K); int k=(int)(i-(size_t)rp*K);
  int f=rp>>4, rr=rp&15;
  int g=f%3, cgrp=f/3;
  int orig=g*512+cgrp*16+rr;
  float v;
  if(internal){
    if(k<768)        v=W[(size_t)orig*768+k];
    else if(k<1536)  v=W[(size_t)orig*768+(k-768)];
    else             v=U[(size_t)orig*512+(k-1536)];
  }else{
    int kk=(k<768)?k:k-768;
    v=W[(size_t)orig*768+kk];
  }
  d[i]=(bf16)v;
}

// ---------------- old-layout concat K=3840 (level-5 64-tile iou; first 2048 used) ----------------
__global__ void k_concatHL3840(const float* __restrict__ W, const float* __restrict__ U,
                               bf16* __restrict__ d, int rows){
  size_t i=(size_t)blockIdx.x*blockDim.x+threadIdx.x;
  const int K=3840;
  size_t tot=(size_t)rows*K;
  if(i>=tot) return;
  int r=(int)(i/K); int k=(int)(i-(size_t)r*K);
  float v; int lo=0;
  if(k<768)        v=W[(size_t)r*768+k];
  else if(k<1536)  v=W[(size_t)r*768+(k-768)];
  else if(k<2048)  v=U[(size_t)r*512+(k-1536)];
  else if(k<2560)  v=U[(size_t)r*512+(k-2048)];
  else if(k<3328){ v=W[(size_t)r*768+(k-2560)]; lo=1; }
  else           { v=U[(size_t)r*512+(k-3328)]; lo=1; }
  bf16 h=(bf16)v;
  d[i]= lo ? (bf16)(v-(float)h) : h;
}

// ---------------- Wcomb = W_sd2 @ W_sd  (512x512, fp32 exact) ----------------
__global__ __launch_bounds__(256)
void k_wcomb(const float* __restrict__ W2, const float* __restrict__ W1,
             float* __restrict__ out){
  __shared__ float As[64][33];
  __shared__ float Bs[32][65];
  const int tid=threadIdx.x;
  const int i0=blockIdx.x*64, j0=blockIdx.y*64;
  const int tr=(tid>>4)*4, tc=(tid&15)*4;
  float acc[4][4];
  #pragma unroll
  for(int x=0;x<4;++x)
    #pragma unroll
    for(int y=0;y<4;++y) acc[x][y]=0.f;
  for(int k0=0;k0<1024;k0+=32){
    for(int l=tid;l<64*32;l+=256){ int r=l>>5,c=l&31; As[r][c]=W2[(size_t)(i0+r)*1024+k0+c]; }
    for(int l=tid;l<32*64;l+=256){ int r=l>>6,c=l&63; Bs[r][c]=W1[(size_t)(k0+r)*512+j0+c]; }
    __syncthreads();
    #pragma unroll 8
    for(int k=0;k<32;++k){
      float a[4],b[4];
      #pragma unroll
      for(int x=0;x<4;++x){ a[x]=As[tr+x][k]; b[x]=Bs[k][tc+x]; }
      #pragma unroll
      for(int x=0;x<4;++x)
        #pragma unroll
        for(int y=0;y<4;++y) acc[x][y]+=a[x]*b[y];
    }
    __syncthreads();
  }
  #pragma unroll
  for(int x=0;x<4;++x)
    #pragma unroll
    for(int y=0;y<4;++y) out[(size_t)(i0+tr+x)*512+j0+tc+y]=acc[x][y];
}

// ---------------- Wy[j,c] = Wsf[j,c] + sum_d Wsf[j,d]*Wcomb[d,c] ----------------
__global__ void k_wy(const float* __restrict__ Wsf, const float* __restrict__ Wcomb,
                     float* __restrict__ Wy){
  int idx=blockIdx.x*256+threadIdx.x;
  if(idx>=2048) return;
  int j=idx>>9, c=idx&511;
  float s=Wsf[j*512+c];
  for(int d=0;d<512;++d) s+=Wsf[j*512+d]*Wcomb[(size_t)d*512+c];
  Wy[(size_t)j*512+c]=s;
}

// ================= iou GEMM: 128 x 192, dbuf + counted vmcnt + setprio, XCD-chunked =================
__global__ __launch_bounds__(256,2)
void k_iou128p(const bf16* __restrict__ fH, const bf16* __restrict__ fL,
               const bf16* __restrict__ hsH,
               const bf16* __restrict__ Wil, const float* __restrict__ bias,
               const float* __restrict__ csum, bf16* __restrict__ hbuf,
               bf16* __restrict__ hlo, float* __restrict__ cbuf,
               int start_n, int shift, int internal)
{
  extern __shared__ char sm[];                 // A: 2x16384, B: 2x24576
  char* Abase=sm;
  char* Bbase=sm+32768;
  const int tid=threadIdx.x;
  const int w=tid>>6, lane=tid&63;
  int x, my;
  xcd_map(blockIdx.x, gridDim.x, 8, x, my);
  const int m0=my*128;
  const int K = internal? 2048 : 1536;
  const int NT = K>>6;

  unsigned fofs[4], hofs[4];
  #pragma unroll
  for(int i=0;i<4;++i){
    int r=w*32+i*8+(lane>>3);
    int m=m0+r;
    int t_=m>>shift, j=m-(t_<<shift);
    fofs[i]=(unsigned)(((size_t)t_*NPT+start_n+j)*768);
    hofs[i]=(unsigned)m*512u;
  }
  unsigned bofs[6];
  #pragma unroll
  for(int i=0;i<6;++i){
    int r=x*192+w*48+i*8+(lane>>3);
    bofs[i]=(unsigned)r*(unsigned)K;
  }
  const unsigned swz=8u*((unsigned)(lane&7)^(unsigned)(lane>>3));

  f32x4 acc[4][6];
  #pragma unroll
  for(int mi=0;mi<4;++mi)
    #pragma unroll
    for(int ni=0;ni<6;++ni) acc[mi][ni]=(f32x4){0.f,0.f,0.f,0.f};

  const int wr=(w>>1)*64;
  const int wcF=(w&1)*6;
  const int lr=lane&15, lg=lane>>4;

  auto STAGE=[&](int buf, int t){
    const bf16* base; int kt; bool useF;
    if(internal){
      if(t<12){ base=fH; kt=t;    useF=true; }
      else if(t<24){ base=fL; kt=t-12; useF=true; }
      else        { base=hsH; kt=t-24; useF=false; }
    }else{
      if(t<12){ base=fH; kt=t;    useF=true; }
      else    { base=fL; kt=t-12; useF=true; }
    }
    const unsigned kofs=(unsigned)kt*64u+swz;
    char* Ad=Abase+(size_t)buf*16384;
    #pragma unroll
    for(int i=0;i<4;++i){
      const bf16* g=base+(useF?fofs[i]:hofs[i])+kofs;
      gll16(g, Ad+(w*32+i*8)*128);
    }
    const unsigned bk=(unsigned)t*64u+swz;
    char* Bd=Bbase+(size_t)buf*24576;
    #pragma unroll
    for(int i=0;i<6;++i){
      gll16(Wil+bofs[i]+bk, Bd+(w*48+i*8)*128);
    }
  };

  auto COMPUTE=[&](int cur){
    const char* Ab=Abase+(size_t)cur*16384;
    const char* Bb=Bbase+(size_t)cur*24576;
    #pragma unroll
    for(int ks=0;ks<2;++ks){
      const unsigned cb=((unsigned)(ks*64+lg*16)) ^ ((unsigned)(lr&7)<<4);
      bf16x8 av[4], bv[6];
      #pragma unroll
      for(int mi=0;mi<4;++mi)
        av[mi]=*(const bf16x8*)(Ab+(unsigned)(wr+mi*16+lr)*128u+cb);
      #pragma unroll
      for(int ni=0;ni<6;++ni)
        bv[ni]=*(const bf16x8*)(Bb+(unsigned)((wcF+ni)*16+lr)*128u+cb);
      __builtin_amdgcn_s_setprio(1);
      #pragma unroll
      for(int ni=0;ni<6;++ni)
        #pragma unroll
        for(int mi=0;mi<4;++mi)
          acc[mi][ni]=__builtin_amdgcn_mfma_f32_16x16x32_bf16(av[mi],bv[ni],acc[mi][ni],0,0,0);
      __builtin_amdgcn_s_setprio(0);
    }
  };

  STAGE(0,0);
  STAGE(1,1);
  asm volatile("s_waitcnt vmcnt(10)" ::: "memory");
  __builtin_amdgcn_s_barrier();
  __builtin_amdgcn_sched_barrier(0);

  for(int t=0;t<NT;++t){
    COMPUTE(t&1);
    if(t+1<NT){
      __builtin_amdgcn_sched_barrier(0);
      __builtin_amdgcn_s_barrier();
      __builtin_amdgcn_sched_barrier(0);
      if(t+2<NT){
        STAGE(t&1, t+2);
        asm volatile("s_waitcnt vmcnt(10)" ::: "memory");
      }else{
        asm volatile("s_waitcnt vmcnt(0)" ::: "memory");
      }
      __builtin_amdgcn_s_barrier();
      __builtin_amdgcn_sched_barrier(0);
    }
  }

  #pragma unroll
  for(int mi=0;mi<4;++mi){
    #pragma unroll
    for(int cg=0;cg<2;++cg){
      const int col = x*64 + ((w&1)*2+cg)*16 + lr;
      const float bi=bias[col], bo=bias[col+512], bu=bias[col+1024];
      #pragma unroll
      for(int r=0;r<4;++r){
        const int mm=m0+wr+mi*16+lg*4+r;
        float iv=acc[mi][3*cg+0][r]+bi;
        float ov=acc[mi][3*cg+1][r]+bo;
        float uv=acc[mi][3*cg+2][r]+bu;
        float cn=sigm(iv)*tanhf(uv);
        if(internal) cn+=csum[(size_t)mm*HD+col];
        float hn=sigm(ov)*tanhf(cn);
        const int tt=mm>>shift, jj=mm-(tt<<shift);
        const size_t nd=((size_t)tt*NPT+start_n+jj)*HD+col;
        cbuf[nd]=cn;
        bf16 hh=(bf16)hn;
        hbuf[nd]=hh;
        hlo[nd]=(bf16)(hn-(float)hh);
      }
    }
  }
}

// ---------------- old 64-tile iou (level 5 only, P=64; K=2048 prefix of 3840 layout) ----------------
__global__ __launch_bounds__(256)
void k_iou(const bf16* __restrict__ fH, const bf16* __restrict__ fL,
           const bf16* __restrict__ hsH,
           const bf16* __restrict__ Wcat, const float* __restrict__ bias,
           const float* __restrict__ csum, bf16* __restrict__ hbuf,
           bf16* __restrict__ hlo, float* __restrict__ cbuf,
           int start_n, int shift, int K, int KB, int internal)
{
  __shared__ bf16 As[64][40];
  __shared__ bf16 Bs[3][64][40];
  const int tid=threadIdx.x;
  const int m0=blockIdx.x*64, n0=blockIdx.y*64;
  const int srow=tid>>2, skc=(tid&3)*8;
  const int m=m0+srow;
  const int t=m>>shift, j=m-(t<<shift);
  const size_t frow=((size_t)t*NPT+start_n+j)*768;
  const bf16* aFH=fH+frow;
  const bf16* aFL=fL+frow;
  const bf16* aHH=hsH+(size_t)m*HD;
  const bf16* bp0=Wcat+(size_t)(n0+srow)*KB;
  const bf16* bp1=Wcat+(size_t)(512+n0+srow)*KB;
  const bf16* bp2=Wcat+(size_t)(1024+n0+srow)*KB;

  f32x4 acc[3][2][2];
  #pragma unroll
  for(int g=0;g<3;++g)
    #pragma unroll
    for(int mi=0;mi<2;++mi)
      #pragma unroll
      for(int ni=0;ni<2;++ni) acc[g][mi][ni]=(f32x4){0.f,0.f,0.f,0.f};

  const int w=tid>>6, lane=tid&63;
  const int wr=(w>>1)*32, wc=(w&1)*32;
  const int lr=lane&15, lg=lane>>4;

  for(int k0=0;k0<K;k0+=32){
    const bf16* ap;
    if(internal){
      if(k0<768)        ap=aFH+k0;
      else if(k0<1536)  ap=aFL+(k0-768);
      else              ap=aHH+(k0-1536);
    }else{
      ap=(k0<768)? (aFH+k0) : (aFL+(k0-768));
    }
    *(bf16x8*)&As[srow][skc]=*(const bf16x8*)(ap+skc);
    *(bf16x8*)&Bs[0][srow][skc]=*(const bf16x8*)(bp0+k0+skc);
    *(bf16x8*)&Bs[1][srow][skc]=*(const bf16x8*)(bp1+k0+skc);
    *(bf16x8*)&Bs[2][srow][skc]=*(const bf16x8*)(bp2+k0+skc);
    __syncthreads();
    bf16x8 a0=*(bf16x8*)&As[wr+lr][lg*8];
    bf16x8 a1=*(bf16x8*)&As[wr+16+lr][lg*8];
    #pragma unroll
    for(int g=0;g<3;++g){
      #pragma unroll
      for(int ni=0;ni<2;++ni){
        bf16x8 bv=*(bf16x8*)&Bs[g][wc+ni*16+lr][lg*8];
        acc[g][0][ni]=__builtin_amdgcn_mfma_f32_16x16x32_bf16(a0,bv,acc[g][0][ni],0,0,0);
        acc[g][1][ni]=__builtin_amdgcn_mfma_f32_16x16x32_bf16(a1,bv,acc[g][1][ni],0,0,0);
      }
    }
    __syncthreads();
  }

  #pragma unroll
  for(int mi=0;mi<2;++mi){
    #pragma unroll
    for(int ni=0;ni<2;++ni){
      const int col=n0+wc+ni*16+lr;
      const float bi=bias[col], bo=bias[col+512], bu=bias[col+1024];
      #pragma unroll
      for(int r=0;r<4;++r){
        const int mm=m0+wr+mi*16+lg*4+r;
        float iv=acc[0][mi][ni][r]+bi;
        float ov=acc[1][mi][ni][r]+bo;
        float uv=acc[2][mi][ni][r]+bu;
        float cn=sigm(iv)*tanhf(uv);
        if(internal) cn+=csum[(size_t)mm*HD+col];
        float hn=sigm(ov)*tanhf(cn);
        const int tt=mm>>shift, jj=mm-(tt<<shift);
        const size_t nd=((size_t)tt*NPT+start_n+jj)*HD+col;
        cbuf[nd]=cn;
        bf16 hh=(bf16)hn;
        hbuf[nd]=hh;
        hlo[nd]=(bf16)(hn-(float)hh);
      }
    }
  }
}

// ================= XWf: pipelined 128x128 (NT=24), 1D grid =================
__global__ __launch_bounds__(256,2)
void k_xwf128p(const bf16* __restrict__ fH, const bf16* __restrict__ fL,
               const bf16* __restrict__ Wfc, float* __restrict__ XWf, int Mtot)
{
  extern __shared__ char sm[];     // A: 2x16384, B: 2x16384
  char* Abase=sm;
  char* Bbase=sm+32768;
  const int tid=threadIdx.x;
  const int w=tid>>6, lane=tid&63;
  int xb, my;
  xcd_map(blockIdx.x, gridDim.x, 4, xb, my);
  const int m0=my*128, n0=xb*128;
  const int NT=24;

  unsigned fofs[4];
  #pragma unroll
  for(int i=0;i<4;++i){
    int r=w*32+i*8+(lane>>3);
    int m=m0+r; if(m>=Mtot) m=Mtot-1;
    int t=m/NINT; int j=1024+(m-t*NINT);
    fofs[i]=(unsigned)(((size_t)t*NPT+j)*768);
  }
  unsigned bofs[4];
  #pragma unroll
  for(int i=0;i<4;++i){
    int r=n0+w*32+i*8+(lane>>3);
    bofs[i]=(unsigned)r*1536u;
  }
  const unsigned swz=8u*((unsigned)(lane&7)^(unsigned)(lane>>3));

  f32x4 acc[4][4];
  #pragma unroll
  for(int mi=0;mi<4;++mi)
    #pragma unroll
    for(int ni=0;ni<4;++ni) acc[mi][ni]=(f32x4){0.f,0.f,0.f,0.f};

  const int wr=(w>>1)*64, wc=(w&1)*64;
  const int lr=lane&15, lg=lane>>4;

  auto STAGE=[&](int buf, int t){
    const bf16* Abuf; unsigned ak, bk;
    if(t<12){ Abuf=fH; ak=(unsigned)t*64u; bk=(unsigned)t*64u; }
    else    { Abuf=fL; ak=(unsigned)(t-12)*64u; bk=(unsigned)(t-12)*64u; }
    char* Ad=Abase+(size_t)buf*16384;
    #pragma unroll
    for(int i=0;i<4;++i)
      gll16(Abuf+fofs[i]+ak+swz, Ad+(w*32+i*8)*128);
    char* Bd=Bbase+(size_t)buf*16384;
    #pragma unroll
    for(int i=0;i<4;++i)
      gll16(Wfc+bofs[i]+bk+swz, Bd+(w*32+i*8)*128);
  };

  auto COMPUTE=[&](int cur){
    const char* Ab=Abase+(size_t)cur*16384;
    const char* Bb=Bbase+(size_t)cur*16384;
    #pragma unroll
    for(int ks=0;ks<2;++ks){
      const unsigned cb=((unsigned)(ks*64+lg*16)) ^ ((unsigned)(lr&7)<<4);
      bf16x8 av[4], bv[4];
      #pragma unroll
      for(int mi=0;mi<4;++mi)
        av[mi]=*(const bf16x8*)(Ab+(unsigned)(wr+mi*16+lr)*128u+cb);
      #pragma unroll
      for(int ni=0;ni<4;++ni)
        bv[ni]=*(const bf16x8*)(Bb+(unsigned)((wc+ni*16)+lr)*128u+cb);
      __builtin_amdgcn_s_setprio(1);
      #pragma unroll
      for(int ni=0;ni<4;++ni)
        #pragma unroll
        for(int mi=0;mi<4;++mi)
          acc[mi][ni]=__builtin_amdgcn_mfma_f32_16x16x32_bf16(av[mi],bv[ni],acc[mi][ni],0,0,0);
      __builtin_amdgcn_s_setprio(0);
    }
  };

  STAGE(0,0);
  STAGE(1,1);
  asm volatile("s_waitcnt vmcnt(8)" ::: "memory");
  __builtin_amdgcn_s_barrier();
  __builtin_amdgcn_sched_barrier(0);

  for(int t=0;t<NT;++t){
    COMPUTE(t&1);
    if(t+1<NT){
      __builtin_amdgcn_sched_barrier(0);
      __builtin_amdgcn_s_barrier();
      __builtin_amdgcn_sched_barrier(0);
      if(t+2<NT){
        STAGE(t&1, t+2);
        asm volatile("s_waitcnt vmcnt(8)" ::: "memory");
      }else{
        asm volatile("s_waitcnt vmcnt(0)" ::: "memory");
      }
      __builtin_amdgcn_s_barrier();
      __builtin_amdgcn_sched_barrier(0);
    }
  }

  #pragma unroll
  for(int mi=0;mi<4;++mi){
    #pragma unroll
    for(int ni=0;ni<4;++ni){
      const int col=n0+wc+ni*16+lr;
      #pragma unroll
      for(int r=0;r<4;++r){
        const int mm=m0+wr+mi*16+lg*4+r;
        if(mm<Mtot) XWf[(size_t)mm*512+col]=acc[mi][ni][r];
      }
    }
  }
}

// ================= Uh forget-gate: pipelined 128x128 (NT=8, hi-only) + fused csum/hsum =================
__global__ __launch_bounds__(256,2)
void k_uh128p(const bf16* __restrict__ hhi, const bf16* __restrict__ hlo,
              const bf16* __restrict__ Ufc, const float* __restrict__ bias,
              const float* __restrict__ XWf, const float* __restrict__ cbuf,
              float* __restrict__ csum, bf16* __restrict__ hs_hi,
              int start_ch, int lc, int xwoff)
{
  extern __shared__ char sm[];     // A: 2x16384, B: 2x16384
  char* Abase=sm;
  char* Bbase=sm+32768;
  const int tid=threadIdx.x;
  const int w=tid>>6, lane=tid&63;
  int xb, my;
  xcd_map(blockIdx.x, gridDim.x, 4, xb, my);
  const int e0=my*128, n0=xb*128;
  const int NT=8;

  unsigned hofs[4];
  #pragma unroll
  for(int i=0;i<4;++i){
    int r=w*32+i*8+(lane>>3);
    int e=e0+r;
    int t=e>>lc, ei=e-(t<<lc);
    hofs[i]=(unsigned)(((size_t)t*NPT+start_ch+ei)*HD);
  }
  unsigned bofs[4];
  #pragma unroll
  for(int i=0;i<4;++i){
    int r=n0+w*32+i*8+(lane>>3);
    bofs[i]=(unsigned)r*1024u;
  }
  const unsigned swz=8u*((unsigned)(lane&7)^(unsigned)(lane>>3));

  f32x4 acc[4][4];
  #pragma unroll
  for(int mi=0;mi<4;++mi)
    #pragma unroll
    for(int ni=0;ni<4;++ni) acc[mi][ni]=(f32x4){0.f,0.f,0.f,0.f};

  const int wr=(w>>1)*64, wc=(w&1)*64;
  const int lr=lane&15, lg=lane>>4;

  auto STAGE=[&](int buf, int t){
    const unsigned ak=(unsigned)t*64u, bk=(unsigned)t*64u;
    char* Ad=Abase+(size_t)buf*16384;
    #pragma unroll
    for(int i=0;i<4;++i)
      gll16(hhi+hofs[i]+ak+swz, Ad+(w*32+i*8)*128);
    char* Bd=Bbase+(size_t)buf*16384;
    #pragma unroll
    for(int i=0;i<4;++i)
      gll16(Ufc+bofs[i]+bk+swz, Bd+(w*32+i*8)*128);
  };

  auto COMPUTE=[&](int cur){
    const char* Ab=Abase+(size_t)cur*16384;
    const char* Bb=Bbase+(size_t)cur*16384;
    #pragma unroll
    for(int ks=0;ks<2;++ks){
      const unsigned cb=((unsigned)(ks*64+lg*16)) ^ ((unsigned)(lr&7)<<4);
      bf16x8 av[4], bv[4];
      #pragma unroll
      for(int mi=0;mi<4;++mi)
        av[mi]=*(const bf16x8*)(Ab+(unsigned)(wr+mi*16+lr)*128u+cb);
      #pragma unroll
      for(int ni=0;ni<4;++ni)
        bv[ni]=*(const bf16x8*)(Bb+(unsigned)((wc+ni*16)+lr)*128u+cb);
      __builtin_amdgcn_s_setprio(1);
      #pragma unroll
      for(int ni=0;ni<4;++ni)
        #pragma unroll
        for(int mi=0;mi<4;++mi)
          acc[mi][ni]=__builtin_amdgcn_mfma_f32_16x16x32_bf16(av[mi],bv[ni],acc[mi][ni],0,0,0);
      __builtin_amdgcn_s_setprio(0);
    }
  };

  STAGE(0,0);
  STAGE(1,1);
  asm volatile("s_waitcnt vmcnt(8)" ::: "memory");
  __builtin_amdgcn_s_barrier();
  __builtin_amdgcn_sched_barrier(0);

  for(int t=0;t<NT;++t){
    COMPUTE(t&1);
    if(t+1<NT){
      __builtin_amdgcn_sched_barrier(0);
      __builtin_amdgcn_s_barrier();
      __builtin_amdgcn_sched_barrier(0);
      if(t+2<NT){
        STAGE(t&1, t+2);
        asm volatile("s_waitcnt vmcnt(8)" ::: "memory");
      }else{
        asm volatile("s_waitcnt vmcnt(0)" ::: "memory");
      }
      __builtin_amdgcn_s_barrier();
      __builtin_amdgcn_sched_barrier(0);
    }
  }

  #pragma unroll
  for(int mi=0;mi<4;++mi){
    const int ebase=e0+wr+mi*16+lg*4;
    const int tt=ebase>>lc, eib=ebase-(tt<<lc);
    const int inode=tt*NINT + xwoff + (eib>>2);
    const int par=ebase>>2;
    #pragma unroll
    for(int ni=0;ni<4;++ni){
      const int col=n0+wc+ni*16+lr;
      const float base=bias[col]+XWf[(size_t)inode*512+col];
      const size_t chbase=((size_t)tt*NPT+start_ch+eib)*HD+col;
      float s=0.f, hsv=0.f;
      #pragma unroll
      for(int r=0;r<4;++r){
        const size_t ci=chbase+(size_t)r*HD;
        float fv=sigm(acc[mi][ni][r]+base);
        s+=fv*cbuf[ci];
        hsv+=(float)hhi[ci]+(float)hlo[ci];
      }
      csum[(size_t)par*HD+col]=s;
      hs_hi[(size_t)par*HD+col]=(bf16)hsv;
    }
  }
}

// ---------------- final head ----------------
__global__ __launch_bounds__(256)
void k_final2(const bf16* __restrict__ hhi, const bf16* __restrict__ hlo,
              const float* __restrict__ Wy, const float* __restrict__ gamma,
              const float* __restrict__ beta, float* __restrict__ out0, int Nn)
{
  const int gtid=blockIdx.x*256+threadIdx.x;
  const int node=gtid>>6, lane=gtid&63;
  if(node>=Nn) return;
  const size_t base=(size_t)node*HD+lane*8;
  bf16x8 hv=*(const bf16x8*)(hhi+base);
  bf16x8 lv=*(const bf16x8*)(hlo+base);
  float hf[8];
  #pragma unroll
  for(int e=0;e<8;++e) hf[e]=(float)hv[e]+(float)lv[e];
  float y[4];
  #pragma unroll
  for(int jj=0;jj<4;++jj){
    const float* wp=Wy+jj*HD+lane*8;
    float s=0.f;
    #pragma unroll
    for(int e=0;e<8;++e) s+=hf[e]*wp[e];
    #pragma unroll
    for(int off=32;off>=1;off>>=1) s+=__shfl_xor(s,off,64);
    y[jj]=s;
  }
  if(lane==0){
    float mu=0.25f*(y[0]+y[1]+y[2]+y[3]);
    float var=0.f;
    #pragma unroll
    for(int jj=0;jj<4;++jj){ float d=y[jj]-mu; var+=d*d; }
    var*=0.25f;
    float rs=rsqrtf(var+1e-6f);
    float z[4], zmax=-1e30f;
    #pragma unroll
    for(int jj=0;jj<4;++jj){ z[jj]=(y[jj]-mu)*rs*gamma[jj]+beta[jj]; zmax=fmaxf(zmax,z[jj]); }
    float es=0.f;
    #pragma unroll
    for(int jj=0;jj<4;++jj){ z[jj]=__expf(z[jj]-zmax); es+=z[jj]; }
    float inv=1.f/es;
    #pragma unroll
    for(int jj=0;jj<4;++jj) out0[(size_t)node*4+jj]=z[jj]*inv;
  }
}

// ---------------- root head ----------------
__global__ __launch_bounds__(256)
void k_root(const bf16* __restrict__ hhi, const bf16* __restrict__ hlo,
            const float* __restrict__ Wff, float* __restrict__ out1)
{
  const int gtid=blockIdx.x*256+threadIdx.x;
  const int tt=gtid>>6, lane=gtid&63;
  if(tt>=64) return;
  const size_t base=((size_t)tt*NPT+1364)*HD+lane*8;
  bf16x8 hv=*(const bf16x8*)(hhi+base);
  bf16x8 lv=*(const bf16x8*)(hlo+base);
  float hf[8];
  #pragma unroll
  for(int e=0;e<8;++e) hf[e]=(float)hv[e]+(float)lv[e];
  float y[4];
  #pragma unroll
  for(int jj=0;jj<4;++jj){
    const float* wp=Wff+jj*HD+lane*8;
    float s=0.f;
    #pragma unroll
    for(int e=0;e<8;++e) s+=hf[e]*wp[e];
    #pragma unroll
    for(int off=32;off>=1;off>>=1) s+=__shfl_xor(s,off,64);
    y[jj]=s;
  }
  if(lane==0){
    float zmax=fmaxf(fmaxf(y[0],y[1]),fmaxf(y[2],y[3]));
    float es=0.f, z[4];
    #pragma unroll
    for(int jj=0;jj<4;++jj){ z[jj]=__expf(y[jj]-zmax); es+=z[jj]; }
    float inv=1.f/es;
    #pragma unroll
    for(int jj=0;jj<4;++jj) out1[(size_t)tt*4+jj]=z[jj]*inv;
  }
}

extern "C" void kernel_launch(void* const* d_in, const int* in_sizes, int n_in,
                              void* d_out, int out_size, void* d_ws, size_t ws_size,
                              hipStream_t stream)
{
  const float* features=(const float*)d_in[0];
  const float* W_iou=(const float*)d_in[6];
  const float* b_iou=(const float*)d_in[7];
  const float* U_iou=(const float*)d_in[8];
  const float* W_f  =(const float*)d_in[9];
  const float* b_f  =(const float*)d_in[10];
  const float* U_f  =(const float*)d_in[11];
  const float* W_ff =(const float*)d_in[12];
  const float* W_sd =(const float*)d_in[13];
  const float* W_sd2=(const float*)d_in[14];
  const float* W_sf =(const float*)d_in[15];
  const float* ln_g =(const float*)d_in[16];
  const float* ln_b =(const float*)d_in[17];

  const int N=in_sizes[0]/768;   // 87360
  const int T=N/NPT;             // 64
  const int MINT=T*NINT;         // 21824

  float* out0=(float*)d_out;
  float* out1=out0+(size_t)N*4;
  float* cbuf=out1+(size_t)T*4;  // c output region (live c-state)

  char* p=(char*)d_ws;
  auto alloc=[&](size_t bytes){ char* r=p; p+=((bytes+255)&~(size_t)255); return r; };
  bf16*  f_hi =(bf16*) alloc((size_t)N*768*2);
  bf16*  f_lo =(bf16*) alloc((size_t)N*768*2);
  bf16*  hs_hi=(bf16*) alloc((size_t)16384*HD*2);
  float* csum =(float*)alloc((size_t)16384*HD*4);
  bf16*  h_hi =(bf16*) alloc((size_t)N*HD*2);
  bf16*  h_lo =(bf16*) alloc((size_t)N*HD*2);
  bf16*  WilL =(bf16*) alloc((size_t)1536*1536*2);
  bf16*  WilI =(bf16*) alloc((size_t)1536*2048*2);
  bf16*  WcatI=(bf16*) alloc((size_t)1536*3840*2);
  bf16*  Wfc  =(bf16*) alloc((size_t)512*1536*2);
  bf16*  Ufc  =(bf16*) alloc((size_t)512*1024*2);
  float* Wcomb=(float*)alloc((size_t)512*512*4);
  float* Wy   =(float*)alloc((size_t)4*512*4);
  float* XWf  =(float*)alloc((size_t)MINT*512*4);

  // conversions / weight prep
  { size_t n8=(size_t)N*768/8;  k_split8<<<(int)((n8+255)/256),256,0,stream>>>(features,f_hi,f_lo,n8); }
  { size_t n=(size_t)1536*1536; k_wil<<<(int)((n+255)/256),256,0,stream>>>(W_iou,U_iou,WilL,0); }
  { size_t n=(size_t)1536*2048; k_wil<<<(int)((n+255)/256),256,0,stream>>>(W_iou,U_iou,WilI,1); }
  { size_t n=(size_t)1536*3840; k_concatHL3840<<<(int)((n+255)/256),256,0,stream>>>(W_iou,U_iou,WcatI,1536); }
  { size_t n=(size_t)512*1536;  k_catHL<<<(int)((n+255)/256),256,0,stream>>>(W_f,Wfc,512,768); }
  { size_t n=(size_t)512*1024;  k_catHL<<<(int)((n+255)/256),256,0,stream>>>(U_f,Ufc,512,512); }
  { dim3 g(8,8); k_wcomb<<<g,256,0,stream>>>(W_sd2,W_sd,Wcomb); }
  { k_wy<<<8,256,0,stream>>>(W_sf,Wcomb,Wy); }

  // upfront: XWf for all internal nodes (pipelined, 1D grid)
  { int nb=4*((MINT+127)/128);
    k_xwf128p<<<nb,256,G128_LDS,stream>>>(f_hi,f_lo,Wfc,XWf,MINT); }

  static const int starts[6]={0,1024,1280,1344,1360,1364};
  static const int csh[6]  ={10,8,6,4,2,0};
  static const int counts[6]={1024,256,64,16,4,1};
  static const int xwoffs[6]={0,0,256,320,336,340};

  // level 0 (leaves): XCD-chunked 1D grid
  { int nb=8*((T*1024)/128);
    k_iou128p<<<nb,256,IOU_LDS,stream>>>(f_hi,f_lo,hs_hi,WilL,b_iou,csum,h_hi,h_lo,cbuf,0,10,0); }

  for(int n=1;n<6;++n){
    int P=T*counts[n], E=T*counts[n-1];
    { int nb=4*(E/128);
      k_uh128p<<<nb,256,G128_LDS,stream>>>(h_hi,h_lo,Ufc,b_f,XWf,cbuf,csum,hs_hi,
                                           starts[n-1],csh[n-1],xwoffs[n]); }
    if(P>=128){
      int nb=8*(P/128);
      k_iou128p<<<nb,256,IOU_LDS,stream>>>(f_hi,f_lo,hs_hi,WilI,b_iou,csum,h_hi,h_lo,cbuf,starts[n],csh[n],1);
    }else{
      dim3 g(P/64,8);
      k_iou<<<g,256,0,stream>>>(f_hi,f_lo,hs_hi,WcatI,b_iou,csum,h_hi,h_lo,cbuf,starts[n],csh[n],2048,3840,1);
    }
  }

  // heads (stance folded into Wy)
  { int th=N*64; k_final2<<<(th+255)/256,256,0,stream>>>(h_hi,h_lo,Wy,ln_g,ln_b,out0,N); }
  { k_root<<<16,256,0,stream>>>(h_hi,h_lo,W_ff,out1); }
}

// Round 19
// 1309.722 us; speedup vs baseline: 1.8780x; 1.0733x over previous
//
#include <hip/hip_runtime.h>
#include <hip/hip_bf16.h>
#include <math.h>

typedef __bf16 bf16;
typedef bf16 bf16x8 __attribute__((ext_vector_type(8)));
typedef float f32x4 __attribute__((ext_vector_type(4)));

#define NPT 1365
#define HD 512
#define NINT 341   // internal nodes per tree (256+64+16+4+1)
#define IOU_LDS (2*128*64*2 + 2*192*64*2)   // 81920 B -> 2 blocks/CU
#define G128_LDS (2*128*64*2 + 2*128*64*2)  // 65536 B -> 2 blocks/CU

__device__ __forceinline__ float sigm(float x){ return 1.0f/(1.0f+__expf(-x)); }
// fast tanh: overflow-safe, ~1e-6 rel err (vs 0.035 accuracy budget)
__device__ __forceinline__ float ftanh(float x){
  float ax=fabsf(x);
  float e=__expf(2.f*ax);
  float t=1.f-2.f/(e+1.f);
  return copysignf(t,x);
}

__device__ __forceinline__ void gll16(const void* g, void* l){
  __builtin_amdgcn_global_load_lds((const __attribute__((address_space(1))) void*)g,
                                   (__attribute__((address_space(3))) void*)l, 16, 0, 0);
}

// XCD-chunked bijection: phys%8 = XCD; each XCD gets a contiguous y-range with all x.
__device__ __forceinline__ void xcd_map(int phys, int nb, int xdim, int& x, int& my){
  int ytiles = nb / xdim;
  if((ytiles & 7)==0){
    int k = phys & 7, i = phys >> 3;
    my = k * (ytiles >> 3) + i / xdim;
    x  = i % xdim;
  }else{
    x  = phys % xdim;
    my = phys / xdim;
  }
}

// ---------------- split fp32 -> bf16 hi/lo, 8 elems/thread ----------------
__global__ void k_split8(const float* __restrict__ s, bf16* __restrict__ hi,
                         bf16* __restrict__ lo, size_t n8){
  size_t i=(size_t)blockIdx.x*blockDim.x+threadIdx.x;
  if(i>=n8) return;
  const float4* sp=(const float4*)(s+i*8);
  float4 a=sp[0], b=sp[1];
  float v[8]={a.x,a.y,a.z,a.w,b.x,b.y,b.z,b.w};
  bf16x8 h,l;
  #pragma unroll
  for(int e=0;e<8;++e){ bf16 hh=(bf16)v[e]; h[e]=hh; l[e]=(bf16)(v[e]-(float)hh); }
  *(bf16x8*)(hi+i*8)=h;
  *(bf16x8*)(lo+i*8)=l;
}

// ---------------- generic [hi|lo] row concat ----------------
__global__ void k_catHL(const float* __restrict__ S, bf16* __restrict__ d,
                        int rows, int Ksrc){
  size_t i=(size_t)blockIdx.x*blockDim.x+threadIdx.x;
  int K=2*Ksrc;
  size_t tot=(size_t)rows*K;
  if(i>=tot) return;
  int r=(int)(i/K); int k=(int)(i-(size_t)r*K);
  float v=S[(size_t)r*Ksrc + (k<Ksrc?k:k-Ksrc)];
  bf16 h=(bf16)v;
  d[i]=(k<Ksrc)? h : (bf16)(v-(float)h);
}

// ---------------- gate-interleaved iou weights ----------------
// leaf   (K=1536): [Whi | Whi]       -- fH*Whi + fL*Whi
// intern (K=2048): [Whi | Whi | Uhi] -- fH*Whi + fL*Whi + hsH*Uhi
__global__ void k_wil(const float* __restrict__ W, const float* __restrict__ U,
                      bf16* __restrict__ d, int internal){
  const int K = internal? 2048 : 1536;
  size_t i=(size_t)blockIdx.x*blockDim.x+threadIdx.x;
  size_t tot=(size_t)1536*K;
  if(i>=tot) return;
  int rp=(int)(i/K); int k=(int)(i-(size_t)rp*K);
  int f=rp>>4, rr=rp&15;
  int g=f%3, cgrp=f/3;
  int orig=g*512+cgrp*16+rr;
  float v;
  if(internal){
    if(k<768)        v=W[(size_t)orig*768+k];
    else if(k<1536)  v=W[(size_t)orig*768+(k-768)];
    else             v=U[(size_t)orig*512+(k-1536)];
  }else{
    int kk=(k<768)?k:k-768;
    v=W[(size_t)orig*768+kk];
  }
  d[i]=(bf16)v;
}

// ---------------- old-layout concat K=3840 (level-5 64-tile iou; first 2048 used) ----------------
__global__ void k_concatHL3840(const float* __restrict__ W, const float* __restrict__ U,
                               bf16* __restrict__ d, int rows){
  size_t i=(size_t)blockIdx.x*blockDim.x+threadIdx.x;
  const int K=3840;
  size_t tot=(size_t)rows*K;
  if(i>=tot) return;
  int r=(int)(i/K); int k=(int)(i-(size_t)r*K);
  float v; int lo=0;
  if(k<768)        v=W[(size_t)r*768+k];
  else if(k<1536)  v=W[(size_t)r*768+(k-768)];
  else if(k<2048)  v=U[(size_t)r*512+(k-1536)];
  else if(k<2560)  v=U[(size_t)r*512+(k-2048)];
  else if(k<3328){ v=W[(size_t)r*768+(k-2560)]; lo=1; }
  else           { v=U[(size_t)r*512+(k-3328)]; lo=1; }
  bf16 h=(bf16)v;
  d[i]= lo ? (bf16)(v-(float)h) : h;
}

// ---------------- Wcomb = W_sd2 @ W_sd  (512x512, fp32 exact) ----------------
__global__ __launch_bounds__(256)
void k_wcomb(const float* __restrict__ W2, const float* __restrict__ W1,
             float* __restrict__ out){
  __shared__ float As[64][33];
  __shared__ float Bs[32][65];
  const int tid=threadIdx.x;
  const int i0=blockIdx.x*64, j0=blockIdx.y*64;
  const int tr=(tid>>4)*4, tc=(tid&15)*4;
  float acc[4][4];
  #pragma unroll
  for(int x=0;x<4;++x)
    #pragma unroll
    for(int y=0;y<4;++y) acc[x][y]=0.f;
  for(int k0=0;k0<1024;k0+=32){
    for(int l=tid;l<64*32;l+=256){ int r=l>>5,c=l&31; As[r][c]=W2[(size_t)(i0+r)*1024+k0+c]; }
    for(int l=tid;l<32*64;l+=256){ int r=l>>6,c=l&63; Bs[r][c]=W1[(size_t)(k0+r)*512+j0+c]; }
    __syncthreads();
    #pragma unroll 8
    for(int k=0;k<32;++k){
      float a[4],b[4];
      #pragma unroll
      for(int x=0;x<4;++x){ a[x]=As[tr+x][k]; b[x]=Bs[k][tc+x]; }
      #pragma unroll
      for(int x=0;x<4;++x)
        #pragma unroll
        for(int y=0;y<4;++y) acc[x][y]+=a[x]*b[y];
    }
    __syncthreads();
  }
  #pragma unroll
  for(int x=0;x<4;++x)
    #pragma unroll
    for(int y=0;y<4;++y) out[(size_t)(i0+tr+x)*512+j0+tc+y]=acc[x][y];
}

// ---------------- Wy[j,c] = Wsf[j,c] + sum_d Wsf[j,d]*Wcomb[d,c] ----------------
__global__ void k_wy(const float* __restrict__ Wsf, const float* __restrict__ Wcomb,
                     float* __restrict__ Wy){
  int idx=blockIdx.x*256+threadIdx.x;
  if(idx>=2048) return;
  int j=idx>>9, c=idx&511;
  float s=Wsf[j*512+c];
  for(int d=0;d<512;++d) s+=Wsf[j*512+d]*Wcomb[(size_t)d*512+c];
  Wy[(size_t)j*512+c]=s;
}

// ================= iou GEMM: 128 x 192, dbuf + counted vmcnt + setprio, XCD-chunked =================
__global__ __launch_bounds__(256,2)
void k_iou128p(const bf16* __restrict__ fH, const bf16* __restrict__ fL,
               const bf16* __restrict__ hsH,
               const bf16* __restrict__ Wil, const float* __restrict__ bias,
               const float* __restrict__ csum, bf16* __restrict__ hbuf,
               bf16* __restrict__ hlo, float* __restrict__ cbuf,
               int start_n, int shift, int internal)
{
  extern __shared__ char sm[];                 // A: 2x16384, B: 2x24576
  char* Abase=sm;
  char* Bbase=sm+32768;
  const int tid=threadIdx.x;
  const int w=tid>>6, lane=tid&63;
  int x, my;
  xcd_map(blockIdx.x, gridDim.x, 8, x, my);
  const int m0=my*128;
  const int K = internal? 2048 : 1536;
  const int NT = K>>6;

  unsigned fofs[4], hofs[4];
  #pragma unroll
  for(int i=0;i<4;++i){
    int r=w*32+i*8+(lane>>3);
    int m=m0+r;
    int t_=m>>shift, j=m-(t_<<shift);
    fofs[i]=(unsigned)(((size_t)t_*NPT+start_n+j)*768);
    hofs[i]=(unsigned)m*512u;
  }
  unsigned bofs[6];
  #pragma unroll
  for(int i=0;i<6;++i){
    int r=x*192+w*48+i*8+(lane>>3);
    bofs[i]=(unsigned)r*(unsigned)K;
  }
  const unsigned swz=8u*((unsigned)(lane&7)^(unsigned)(lane>>3));

  f32x4 acc[4][6];
  #pragma unroll
  for(int mi=0;mi<4;++mi)
    #pragma unroll
    for(int ni=0;ni<6;++ni) acc[mi][ni]=(f32x4){0.f,0.f,0.f,0.f};

  const int wr=(w>>1)*64;
  const int wcF=(w&1)*6;
  const int lr=lane&15, lg=lane>>4;

  auto STAGE=[&](int buf, int t){
    const bf16* base; int kt; bool useF;
    if(internal){
      if(t<12){ base=fH; kt=t;    useF=true; }
      else if(t<24){ base=fL; kt=t-12; useF=true; }
      else        { base=hsH; kt=t-24; useF=false; }
    }else{
      if(t<12){ base=fH; kt=t;    useF=true; }
      else    { base=fL; kt=t-12; useF=true; }
    }
    const unsigned kofs=(unsigned)kt*64u+swz;
    char* Ad=Abase+(size_t)buf*16384;
    #pragma unroll
    for(int i=0;i<4;++i){
      const bf16* g=base+(useF?fofs[i]:hofs[i])+kofs;
      gll16(g, Ad+(w*32+i*8)*128);
    }
    const unsigned bk=(unsigned)t*64u+swz;
    char* Bd=Bbase+(size_t)buf*24576;
    #pragma unroll
    for(int i=0;i<6;++i){
      gll16(Wil+bofs[i]+bk, Bd+(w*48+i*8)*128);
    }
  };

  auto COMPUTE=[&](int cur){
    const char* Ab=Abase+(size_t)cur*16384;
    const char* Bb=Bbase+(size_t)cur*24576;
    #pragma unroll
    for(int ks=0;ks<2;++ks){
      const unsigned cb=((unsigned)(ks*64+lg*16)) ^ ((unsigned)(lr&7)<<4);
      bf16x8 av[4], bv[6];
      #pragma unroll
      for(int mi=0;mi<4;++mi)
        av[mi]=*(const bf16x8*)(Ab+(unsigned)(wr+mi*16+lr)*128u+cb);
      #pragma unroll
      for(int ni=0;ni<6;++ni)
        bv[ni]=*(const bf16x8*)(Bb+(unsigned)((wcF+ni)*16+lr)*128u+cb);
      __builtin_amdgcn_s_setprio(1);
      #pragma unroll
      for(int ni=0;ni<6;++ni)
        #pragma unroll
        for(int mi=0;mi<4;++mi)
          acc[mi][ni]=__builtin_amdgcn_mfma_f32_16x16x32_bf16(av[mi],bv[ni],acc[mi][ni],0,0,0);
      __builtin_amdgcn_s_setprio(0);
    }
  };

  STAGE(0,0);
  STAGE(1,1);
  asm volatile("s_waitcnt vmcnt(10)" ::: "memory");
  __builtin_amdgcn_s_barrier();
  __builtin_amdgcn_sched_barrier(0);

  for(int t=0;t<NT;++t){
    COMPUTE(t&1);
    if(t+1<NT){
      __builtin_amdgcn_sched_barrier(0);
      __builtin_amdgcn_s_barrier();
      __builtin_amdgcn_sched_barrier(0);
      if(t+2<NT){
        STAGE(t&1, t+2);
        asm volatile("s_waitcnt vmcnt(10)" ::: "memory");
      }else{
        asm volatile("s_waitcnt vmcnt(0)" ::: "memory");
      }
      __builtin_amdgcn_s_barrier();
      __builtin_amdgcn_sched_barrier(0);
    }
  }

  #pragma unroll
  for(int mi=0;mi<4;++mi){
    #pragma unroll
    for(int cg=0;cg<2;++cg){
      const int col = x*64 + ((w&1)*2+cg)*16 + lr;
      const float bi=bias[col], bo=bias[col+512], bu=bias[col+1024];
      #pragma unroll
      for(int r=0;r<4;++r){
        const int mm=m0+wr+mi*16+lg*4+r;
        float iv=acc[mi][3*cg+0][r]+bi;
        float ov=acc[mi][3*cg+1][r]+bo;
        float uv=acc[mi][3*cg+2][r]+bu;
        float cn=sigm(iv)*ftanh(uv);
        if(internal) cn+=csum[(size_t)mm*HD+col];
        float hn=sigm(ov)*ftanh(cn);
        const int tt=mm>>shift, jj=mm-(tt<<shift);
        const size_t nd=((size_t)tt*NPT+start_n+jj)*HD+col;
        cbuf[nd]=cn;
        bf16 hh=(bf16)hn;
        hbuf[nd]=hh;
        hlo[nd]=(bf16)(hn-(float)hh);
      }
    }
  }
}

// ---------------- old 64-tile iou (level 5 only, P=64; K=2048 prefix of 3840 layout) ----------------
__global__ __launch_bounds__(256)
void k_iou(const bf16* __restrict__ fH, const bf16* __restrict__ fL,
           const bf16* __restrict__ hsH,
           const bf16* __restrict__ Wcat, const float* __restrict__ bias,
           const float* __restrict__ csum, bf16* __restrict__ hbuf,
           bf16* __restrict__ hlo, float* __restrict__ cbuf,
           int start_n, int shift, int K, int KB, int internal)
{
  __shared__ bf16 As[64][40];
  __shared__ bf16 Bs[3][64][40];
  const int tid=threadIdx.x;
  const int m0=blockIdx.x*64, n0=blockIdx.y*64;
  const int srow=tid>>2, skc=(tid&3)*8;
  const int m=m0+srow;
  const int t=m>>shift, j=m-(t<<shift);
  const size_t frow=((size_t)t*NPT+start_n+j)*768;
  const bf16* aFH=fH+frow;
  const bf16* aFL=fL+frow;
  const bf16* aHH=hsH+(size_t)m*HD;
  const bf16* bp0=Wcat+(size_t)(n0+srow)*KB;
  const bf16* bp1=Wcat+(size_t)(512+n0+srow)*KB;
  const bf16* bp2=Wcat+(size_t)(1024+n0+srow)*KB;

  f32x4 acc[3][2][2];
  #pragma unroll
  for(int g=0;g<3;++g)
    #pragma unroll
    for(int mi=0;mi<2;++mi)
      #pragma unroll
      for(int ni=0;ni<2;++ni) acc[g][mi][ni]=(f32x4){0.f,0.f,0.f,0.f};

  const int w=tid>>6, lane=tid&63;
  const int wr=(w>>1)*32, wc=(w&1)*32;
  const int lr=lane&15, lg=lane>>4;

  for(int k0=0;k0<K;k0+=32){
    const bf16* ap;
    if(internal){
      if(k0<768)        ap=aFH+k0;
      else if(k0<1536)  ap=aFL+(k0-768);
      else              ap=aHH+(k0-1536);
    }else{
      ap=(k0<768)? (aFH+k0) : (aFL+(k0-768));
    }
    *(bf16x8*)&As[srow][skc]=*(const bf16x8*)(ap+skc);
    *(bf16x8*)&Bs[0][srow][skc]=*(const bf16x8*)(bp0+k0+skc);
    *(bf16x8*)&Bs[1][srow][skc]=*(const bf16x8*)(bp1+k0+skc);
    *(bf16x8*)&Bs[2][srow][skc]=*(const bf16x8*)(bp2+k0+skc);
    __syncthreads();
    bf16x8 a0=*(bf16x8*)&As[wr+lr][lg*8];
    bf16x8 a1=*(bf16x8*)&As[wr+16+lr][lg*8];
    #pragma unroll
    for(int g=0;g<3;++g){
      #pragma unroll
      for(int ni=0;ni<2;++ni){
        bf16x8 bv=*(bf16x8*)&Bs[g][wc+ni*16+lr][lg*8];
        acc[g][0][ni]=__builtin_amdgcn_mfma_f32_16x16x32_bf16(a0,bv,acc[g][0][ni],0,0,0);
        acc[g][1][ni]=__builtin_amdgcn_mfma_f32_16x16x32_bf16(a1,bv,acc[g][1][ni],0,0,0);
      }
    }
    __syncthreads();
  }

  #pragma unroll
  for(int mi=0;mi<2;++mi){
    #pragma unroll
    for(int ni=0;ni<2;++ni){
      const int col=n0+wc+ni*16+lr;
      const float bi=bias[col], bo=bias[col+512], bu=bias[col+1024];
      #pragma unroll
      for(int r=0;r<4;++r){
        const int mm=m0+wr+mi*16+lg*4+r;
        float iv=acc[0][mi][ni][r]+bi;
        float ov=acc[1][mi][ni][r]+bo;
        float uv=acc[2][mi][ni][r]+bu;
        float cn=sigm(iv)*ftanh(uv);
        if(internal) cn+=csum[(size_t)mm*HD+col];
        float hn=sigm(ov)*ftanh(cn);
        const int tt=mm>>shift, jj=mm-(tt<<shift);
        const size_t nd=((size_t)tt*NPT+start_n+jj)*HD+col;
        cbuf[nd]=cn;
        bf16 hh=(bf16)hn;
        hbuf[nd]=hh;
        hlo[nd]=(bf16)(hn-(float)hh);
      }
    }
  }
}

// ================= XWf: pipelined 128x128 (NT=24), 1D grid =================
__global__ __launch_bounds__(256,2)
void k_xwf128p(const bf16* __restrict__ fH, const bf16* __restrict__ fL,
               const bf16* __restrict__ Wfc, float* __restrict__ XWf, int Mtot)
{
  extern __shared__ char sm[];     // A: 2x16384, B: 2x16384
  char* Abase=sm;
  char* Bbase=sm+32768;
  const int tid=threadIdx.x;
  const int w=tid>>6, lane=tid&63;
  int xb, my;
  xcd_map(blockIdx.x, gridDim.x, 4, xb, my);
  const int m0=my*128, n0=xb*128;
  const int NT=24;

  unsigned fofs[4];
  #pragma unroll
  for(int i=0;i<4;++i){
    int r=w*32+i*8+(lane>>3);
    int m=m0+r; if(m>=Mtot) m=Mtot-1;
    int t=m/NINT; int j=1024+(m-t*NINT);
    fofs[i]=(unsigned)(((size_t)t*NPT+j)*768);
  }
  unsigned bofs[4];
  #pragma unroll
  for(int i=0;i<4;++i){
    int r=n0+w*32+i*8+(lane>>3);
    bofs[i]=(unsigned)r*1536u;
  }
  const unsigned swz=8u*((unsigned)(lane&7)^(unsigned)(lane>>3));

  f32x4 acc[4][4];
  #pragma unroll
  for(int mi=0;mi<4;++mi)
    #pragma unroll
    for(int ni=0;ni<4;++ni) acc[mi][ni]=(f32x4){0.f,0.f,0.f,0.f};

  const int wr=(w>>1)*64, wc=(w&1)*64;
  const int lr=lane&15, lg=lane>>4;

  auto STAGE=[&](int buf, int t){
    const bf16* Abuf; unsigned ak, bk;
    if(t<12){ Abuf=fH; ak=(unsigned)t*64u; bk=(unsigned)t*64u; }
    else    { Abuf=fL; ak=(unsigned)(t-12)*64u; bk=(unsigned)(t-12)*64u; }
    char* Ad=Abase+(size_t)buf*16384;
    #pragma unroll
    for(int i=0;i<4;++i)
      gll16(Abuf+fofs[i]+ak+swz, Ad+(w*32+i*8)*128);
    char* Bd=Bbase+(size_t)buf*16384;
    #pragma unroll
    for(int i=0;i<4;++i)
      gll16(Wfc+bofs[i]+bk+swz, Bd+(w*32+i*8)*128);
  };

  auto COMPUTE=[&](int cur){
    const char* Ab=Abase+(size_t)cur*16384;
    const char* Bb=Bbase+(size_t)cur*16384;
    #pragma unroll
    for(int ks=0;ks<2;++ks){
      const unsigned cb=((unsigned)(ks*64+lg*16)) ^ ((unsigned)(lr&7)<<4);
      bf16x8 av[4], bv[4];
      #pragma unroll
      for(int mi=0;mi<4;++mi)
        av[mi]=*(const bf16x8*)(Ab+(unsigned)(wr+mi*16+lr)*128u+cb);
      #pragma unroll
      for(int ni=0;ni<4;++ni)
        bv[ni]=*(const bf16x8*)(Bb+(unsigned)((wc+ni*16)+lr)*128u+cb);
      __builtin_amdgcn_s_setprio(1);
      #pragma unroll
      for(int ni=0;ni<4;++ni)
        #pragma unroll
        for(int mi=0;mi<4;++mi)
          acc[mi][ni]=__builtin_amdgcn_mfma_f32_16x16x32_bf16(av[mi],bv[ni],acc[mi][ni],0,0,0);
      __builtin_amdgcn_s_setprio(0);
    }
  };

  STAGE(0,0);
  STAGE(1,1);
  asm volatile("s_waitcnt vmcnt(8)" ::: "memory");
  __builtin_amdgcn_s_barrier();
  __builtin_amdgcn_sched_barrier(0);

  for(int t=0;t<NT;++t){
    COMPUTE(t&1);
    if(t+1<NT){
      __builtin_amdgcn_sched_barrier(0);
      __builtin_amdgcn_s_barrier();
      __builtin_amdgcn_sched_barrier(0);
      if(t+2<NT){
        STAGE(t&1, t+2);
        asm volatile("s_waitcnt vmcnt(8)" ::: "memory");
      }else{
        asm volatile("s_waitcnt vmcnt(0)" ::: "memory");
      }
      __builtin_amdgcn_s_barrier();
      __builtin_amdgcn_sched_barrier(0);
    }
  }

  #pragma unroll
  for(int mi=0;mi<4;++mi){
    #pragma unroll
    for(int ni=0;ni<4;++ni){
      const int col=n0+wc+ni*16+lr;
      #pragma unroll
      for(int r=0;r<4;++r){
        const int mm=m0+wr+mi*16+lg*4+r;
        if(mm<Mtot) XWf[(size_t)mm*512+col]=acc[mi][ni][r];
      }
    }
  }
}

// ================= Uh forget-gate: pipelined 128x128 (NT=8, hi-only) + fused csum/hsum =================
__global__ __launch_bounds__(256,2)
void k_uh128p(const bf16* __restrict__ hhi, const bf16* __restrict__ hlo,
              const bf16* __restrict__ Ufc, const float* __restrict__ bias,
              const float* __restrict__ XWf, const float* __restrict__ cbuf,
              float* __restrict__ csum, bf16* __restrict__ hs_hi,
              int start_ch, int lc, int xwoff)
{
  extern __shared__ char sm[];     // A: 2x16384, B: 2x16384
  char* Abase=sm;
  char* Bbase=sm+32768;
  const int tid=threadIdx.x;
  const int w=tid>>6, lane=tid&63;
  int xb, my;
  xcd_map(blockIdx.x, gridDim.x, 4, xb, my);
  const int e0=my*128, n0=xb*128;
  const int NT=8;

  unsigned hofs[4];
  #pragma unroll
  for(int i=0;i<4;++i){
    int r=w*32+i*8+(lane>>3);
    int e=e0+r;
    int t=e>>lc, ei=e-(t<<lc);
    hofs[i]=(unsigned)(((size_t)t*NPT+start_ch+ei)*HD);
  }
  unsigned bofs[4];
  #pragma unroll
  for(int i=0;i<4;++i){
    int r=n0+w*32+i*8+(lane>>3);
    bofs[i]=(unsigned)r*1024u;
  }
  const unsigned swz=8u*((unsigned)(lane&7)^(unsigned)(lane>>3));

  f32x4 acc[4][4];
  #pragma unroll
  for(int mi=0;mi<4;++mi)
    #pragma unroll
    for(int ni=0;ni<4;++ni) acc[mi][ni]=(f32x4){0.f,0.f,0.f,0.f};

  const int wr=(w>>1)*64, wc=(w&1)*64;
  const int lr=lane&15, lg=lane>>4;

  auto STAGE=[&](int buf, int t){
    const unsigned ak=(unsigned)t*64u, bk=(unsigned)t*64u;
    char* Ad=Abase+(size_t)buf*16384;
    #pragma unroll
    for(int i=0;i<4;++i)
      gll16(hhi+hofs[i]+ak+swz, Ad+(w*32+i*8)*128);
    char* Bd=Bbase+(size_t)buf*16384;
    #pragma unroll
    for(int i=0;i<4;++i)
      gll16(Ufc+bofs[i]+bk+swz, Bd+(w*32+i*8)*128);
  };

  auto COMPUTE=[&](int cur){
    const char* Ab=Abase+(size_t)cur*16384;
    const char* Bb=Bbase+(size_t)cur*16384;
    #pragma unroll
    for(int ks=0;ks<2;++ks){
      const unsigned cb=((unsigned)(ks*64+lg*16)) ^ ((unsigned)(lr&7)<<4);
      bf16x8 av[4], bv[4];
      #pragma unroll
      for(int mi=0;mi<4;++mi)
        av[mi]=*(const bf16x8*)(Ab+(unsigned)(wr+mi*16+lr)*128u+cb);
      #pragma unroll
      for(int ni=0;ni<4;++ni)
        bv[ni]=*(const bf16x8*)(Bb+(unsigned)((wc+ni*16)+lr)*128u+cb);
      __builtin_amdgcn_s_setprio(1);
      #pragma unroll
      for(int ni=0;ni<4;++ni)
        #pragma unroll
        for(int mi=0;mi<4;++mi)
          acc[mi][ni]=__builtin_amdgcn_mfma_f32_16x16x32_bf16(av[mi],bv[ni],acc[mi][ni],0,0,0);
      __builtin_amdgcn_s_setprio(0);
    }
  };

  STAGE(0,0);
  STAGE(1,1);
  asm volatile("s_waitcnt vmcnt(8)" ::: "memory");
  __builtin_amdgcn_s_barrier();
  __builtin_amdgcn_sched_barrier(0);

  for(int t=0;t<NT;++t){
    COMPUTE(t&1);
    if(t+1<NT){
      __builtin_amdgcn_sched_barrier(0);
      __builtin_amdgcn_s_barrier();
      __builtin_amdgcn_sched_barrier(0);
      if(t+2<NT){
        STAGE(t&1, t+2);
        asm volatile("s_waitcnt vmcnt(8)" ::: "memory");
      }else{
        asm volatile("s_waitcnt vmcnt(0)" ::: "memory");
      }
      __builtin_amdgcn_s_barrier();
      __builtin_amdgcn_sched_barrier(0);
    }
  }

  #pragma unroll
  for(int mi=0;mi<4;++mi){
    const int ebase=e0+wr+mi*16+lg*4;
    const int tt=ebase>>lc, eib=ebase-(tt<<lc);
    const int inode=tt*NINT + xwoff + (eib>>2);
    const int par=ebase>>2;
    #pragma unroll
    for(int ni=0;ni<4;++ni){
      const int col=n0+wc+ni*16+lr;
      const float base=bias[col]+XWf[(size_t)inode*512+col];
      const size_t chbase=((size_t)tt*NPT+start_ch+eib)*HD+col;
      float s=0.f, hsv=0.f;
      #pragma unroll
      for(int r=0;r<4;++r){
        const size_t ci=chbase+(size_t)r*HD;
        float fv=sigm(acc[mi][ni][r]+base);
        s+=fv*cbuf[ci];
        hsv+=(float)hhi[ci]+(float)hlo[ci];
      }
      csum[(size_t)par*HD+col]=s;
      hs_hi[(size_t)par*HD+col]=(bf16)hsv;
    }
  }
}

// ---------------- final head ----------------
__global__ __launch_bounds__(256)
void k_final2(const bf16* __restrict__ hhi, const bf16* __restrict__ hlo,
              const float* __restrict__ Wy, const float* __restrict__ gamma,
              const float* __restrict__ beta, float* __restrict__ out0, int Nn)
{
  const int gtid=blockIdx.x*256+threadIdx.x;
  const int node=gtid>>6, lane=gtid&63;
  if(node>=Nn) return;
  const size_t base=(size_t)node*HD+lane*8;
  bf16x8 hv=*(const bf16x8*)(hhi+base);
  bf16x8 lv=*(const bf16x8*)(hlo+base);
  float hf[8];
  #pragma unroll
  for(int e=0;e<8;++e) hf[e]=(float)hv[e]+(float)lv[e];
  float y[4];
  #pragma unroll
  for(int jj=0;jj<4;++jj){
    const float* wp=Wy+jj*HD+lane*8;
    float s=0.f;
    #pragma unroll
    for(int e=0;e<8;++e) s+=hf[e]*wp[e];
    #pragma unroll
    for(int off=32;off>=1;off>>=1) s+=__shfl_xor(s,off,64);
    y[jj]=s;
  }
  if(lane==0){
    float mu=0.25f*(y[0]+y[1]+y[2]+y[3]);
    float var=0.f;
    #pragma unroll
    for(int jj=0;jj<4;++jj){ float d=y[jj]-mu; var+=d*d; }
    var*=0.25f;
    float rs=rsqrtf(var+1e-6f);
    float z[4], zmax=-1e30f;
    #pragma unroll
    for(int jj=0;jj<4;++jj){ z[jj]=(y[jj]-mu)*rs*gamma[jj]+beta[jj]; zmax=fmaxf(zmax,z[jj]); }
    float es=0.f;
    #pragma unroll
    for(int jj=0;jj<4;++jj){ z[jj]=__expf(z[jj]-zmax); es+=z[jj]; }
    float inv=1.f/es;
    #pragma unroll
    for(int jj=0;jj<4;++jj) out0[(size_t)node*4+jj]=z[jj]*inv;
  }
}

// ---------------- root head ----------------
__global__ __launch_bounds__(256)
void k_root(const bf16* __restrict__ hhi, const bf16* __restrict__ hlo,
            const float* __restrict__ Wff, float* __restrict__ out1)
{
  const int gtid=blockIdx.x*256+threadIdx.x;
  const int tt=gtid>>6, lane=gtid&63;
  if(tt>=64) return;
  const size_t base=((size_t)tt*NPT+1364)*HD+lane*8;
  bf16x8 hv=*(const bf16x8*)(hhi+base);
  bf16x8 lv=*(const bf16x8*)(hlo+base);
  float hf[8];
  #pragma unroll
  for(int e=0;e<8;++e) hf[e]=(float)hv[e]+(float)lv[e];
  float y[4];
  #pragma unroll
  for(int jj=0;jj<4;++jj){
    const float* wp=Wff+jj*HD+lane*8;
    float s=0.f;
    #pragma unroll
    for(int e=0;e<8;++e) s+=hf[e]*wp[e];
    #pragma unroll
    for(int off=32;off>=1;off>>=1) s+=__shfl_xor(s,off,64);
    y[jj]=s;
  }
  if(lane==0){
    float zmax=fmaxf(fmaxf(y[0],y[1]),fmaxf(y[2],y[3]));
    float es=0.f, z[4];
    #pragma unroll
    for(int jj=0;jj<4;++jj){ z[jj]=__expf(y[jj]-zmax); es+=z[jj]; }
    float inv=1.f/es;
    #pragma unroll
    for(int jj=0;jj<4;++jj) out1[(size_t)tt*4+jj]=z[jj]*inv;
  }
}

extern "C" void kernel_launch(void* const* d_in, const int* in_sizes, int n_in,
                              void* d_out, int out_size, void* d_ws, size_t ws_size,
                              hipStream_t stream)
{
  const float* features=(const float*)d_in[0];
  const float* W_iou=(const float*)d_in[6];
  const float* b_iou=(const float*)d_in[7];
  const float* U_iou=(const float*)d_in[8];
  const float* W_f  =(const float*)d_in[9];
  const float* b_f  =(const float*)d_in[10];
  const float* U_f  =(const float*)d_in[11];
  const float* W_ff =(const float*)d_in[12];
  const float* W_sd =(const float*)d_in[13];
  const float* W_sd2=(const float*)d_in[14];
  const float* W_sf =(const float*)d_in[15];
  const float* ln_g =(const float*)d_in[16];
  const float* ln_b =(const float*)d_in[17];

  const int N=in_sizes[0]/768;   // 87360
  const int T=N/NPT;             // 64
  const int MINT=T*NINT;         // 21824

  float* out0=(float*)d_out;
  float* out1=out0+(size_t)N*4;
  float* cbuf=out1+(size_t)T*4;  // c output region (live c-state)

  char* p=(char*)d_ws;
  auto alloc=[&](size_t bytes){ char* r=p; p+=((bytes+255)&~(size_t)255); return r; };
  bf16*  f_hi =(bf16*) alloc((size_t)N*768*2);
  bf16*  f_lo =(bf16*) alloc((size_t)N*768*2);
  bf16*  hs_hi=(bf16*) alloc((size_t)16384*HD*2);
  float* csum =(float*)alloc((size_t)16384*HD*4);
  bf16*  h_hi =(bf16*) alloc((size_t)N*HD*2);
  bf16*  h_lo =(bf16*) alloc((size_t)N*HD*2);
  bf16*  WilL =(bf16*) alloc((size_t)1536*1536*2);
  bf16*  WilI =(bf16*) alloc((size_t)1536*2048*2);
  bf16*  WcatI=(bf16*) alloc((size_t)1536*3840*2);
  bf16*  Wfc  =(bf16*) alloc((size_t)512*1536*2);
  bf16*  Ufc  =(bf16*) alloc((size_t)512*1024*2);
  float* Wcomb=(float*)alloc((size_t)512*512*4);
  float* Wy   =(float*)alloc((size_t)4*512*4);
  float* XWf  =(float*)alloc((size_t)MINT*512*4);

  // conversions / weight prep
  { size_t n8=(size_t)N*768/8;  k_split8<<<(int)((n8+255)/256),256,0,stream>>>(features,f_hi,f_lo,n8); }
  { size_t n=(size_t)1536*1536; k_wil<<<(int)((n+255)/256),256,0,stream>>>(W_iou,U_iou,WilL,0); }
  { size_t n=(size_t)1536*2048; k_wil<<<(int)((n+255)/256),256,0,stream>>>(W_iou,U_iou,WilI,1); }
  { size_t n=(size_t)1536*3840; k_concatHL3840<<<(int)((n+255)/256),256,0,stream>>>(W_iou,U_iou,WcatI,1536); }
  { size_t n=(size_t)512*1536;  k_catHL<<<(int)((n+255)/256),256,0,stream>>>(W_f,Wfc,512,768); }
  { size_t n=(size_t)512*1024;  k_catHL<<<(int)((n+255)/256),256,0,stream>>>(U_f,Ufc,512,512); }
  { dim3 g(8,8); k_wcomb<<<g,256,0,stream>>>(W_sd2,W_sd,Wcomb); }
  { k_wy<<<8,256,0,stream>>>(W_sf,Wcomb,Wy); }

  // upfront: XWf for all internal nodes (pipelined, 1D grid)
  { int nb=4*((MINT+127)/128);
    k_xwf128p<<<nb,256,G128_LDS,stream>>>(f_hi,f_lo,Wfc,XWf,MINT); }

  static const int starts[6]={0,1024,1280,1344,1360,1364};
  static const int csh[6]  ={10,8,6,4,2,0};
  static const int counts[6]={1024,256,64,16,4,1};
  static const int xwoffs[6]={0,0,256,320,336,340};

  // level 0 (leaves): XCD-chunked 1D grid
  { int nb=8*((T*1024)/128);
    k_iou128p<<<nb,256,IOU_LDS,stream>>>(f_hi,f_lo,hs_hi,WilL,b_iou,csum,h_hi,h_lo,cbuf,0,10,0); }

  for(int n=1;n<6;++n){
    int P=T*counts[n], E=T*counts[n-1];
    { int nb=4*(E/128);
      k_uh128p<<<nb,256,G128_LDS,stream>>>(h_hi,h_lo,Ufc,b_f,XWf,cbuf,csum,hs_hi,
                                           starts[n-1],csh[n-1],xwoffs[n]); }
    if(P>=128){
      int nb=8*(P/128);
      k_iou128p<<<nb,256,IOU_LDS,stream>>>(f_hi,f_lo,hs_hi,WilI,b_iou,csum,h_hi,h_lo,cbuf,starts[n],csh[n],1);
    }else{
      dim3 g(P/64,8);
      k_iou<<<g,256,0,stream>>>(f_hi,f_lo,hs_hi,WcatI,b_iou,csum,h_hi,h_lo,cbuf,starts[n],csh[n],2048,3840,1);
    }
  }

  // heads (stance folded into Wy)
  { int th=N*64; k_final2<<<(th+255)/256,256,0,stream>>>(h_hi,h_lo,Wy,ln_g,ln_b,out0,N); }
  { k_root<<<16,256,0,stream>>>(h_hi,h_lo,W_ff,out1); }
}

// Round 20
// 1267.136 us; speedup vs baseline: 1.9412x; 1.0336x over previous
//
#include <hip/hip_runtime.h>
#include <hip/hip_bf16.h>
#include <math.h>

typedef __bf16 bf16;
typedef bf16 bf16x8 __attribute__((ext_vector_type(8)));
typedef float f32x4 __attribute__((ext_vector_type(4)));

#define NPT 1365
#define HD 512
#define NINT 341   // internal nodes per tree (256+64+16+4+1)
#define IOU_LDS (2*128*64*2 + 2*192*64*2)   // 81920 B -> 2 blocks/CU
#define G128_LDS (2*128*64*2 + 2*128*64*2)  // 65536 B -> 2 blocks/CU

__device__ __forceinline__ float frcp(float x){ return __builtin_amdgcn_rcpf(x); }
// fast sigmoid/tanh via v_exp + v_rcp (~1e-6 rel err vs 0.035 accuracy budget)
__device__ __forceinline__ float sigm(float x){ return frcp(1.0f+__expf(-x)); }
__device__ __forceinline__ float ftanh(float x){
  float e=__expf(2.f*fabsf(x));
  float t=1.f-2.f*frcp(e+1.f);
  return copysignf(t,x);
}

__device__ __forceinline__ void gll16(const void* g, void* l){
  __builtin_amdgcn_global_load_lds((const __attribute__((address_space(1))) void*)g,
                                   (__attribute__((address_space(3))) void*)l, 16, 0, 0);
}

// XCD-chunked bijection: phys%8 = XCD; each XCD gets a contiguous y-range with all x.
__device__ __forceinline__ void xcd_map(int phys, int nb, int xdim, int& x, int& my){
  int ytiles = nb / xdim;
  if((ytiles & 7)==0){
    int k = phys & 7, i = phys >> 3;
    my = k * (ytiles >> 3) + i / xdim;
    x  = i % xdim;
  }else{
    x  = phys % xdim;
    my = phys / xdim;
  }
}

// ---------------- split fp32 -> bf16 hi/lo, 8 elems/thread ----------------
__global__ void k_split8(const float* __restrict__ s, bf16* __restrict__ hi,
                         bf16* __restrict__ lo, size_t n8){
  size_t i=(size_t)blockIdx.x*blockDim.x+threadIdx.x;
  if(i>=n8) return;
  const float4* sp=(const float4*)(s+i*8);
  float4 a=sp[0], b=sp[1];
  float v[8]={a.x,a.y,a.z,a.w,b.x,b.y,b.z,b.w};
  bf16x8 h,l;
  #pragma unroll
  for(int e=0;e<8;++e){ bf16 hh=(bf16)v[e]; h[e]=hh; l[e]=(bf16)(v[e]-(float)hh); }
  *(bf16x8*)(hi+i*8)=h;
  *(bf16x8*)(lo+i*8)=l;
}

// ---------------- generic [hi|lo] row concat ----------------
__global__ void k_catHL(const float* __restrict__ S, bf16* __restrict__ d,
                        int rows, int Ksrc){
  size_t i=(size_t)blockIdx.x*blockDim.x+threadIdx.x;
  int K=2*Ksrc;
  size_t tot=(size_t)rows*K;
  if(i>=tot) return;
  int r=(int)(i/K); int k=(int)(i-(size_t)r*K);
  float v=S[(size_t)r*Ksrc + (k<Ksrc?k:k-Ksrc)];
  bf16 h=(bf16)v;
  d[i]=(k<Ksrc)? h : (bf16)(v-(float)h);
}

// ---------------- gate-interleaved iou weights ----------------
// leaf   (K=1536): [Whi | Whi]       -- fH*Whi + fL*Whi
// intern (K=2048): [Whi | Whi | Uhi] -- fH*Whi + fL*Whi + hsH*Uhi
__global__ void k_wil(const float* __restrict__ W, const float* __restrict__ U,
                      bf16* __restrict__ d, int internal){
  const int K = internal? 2048 : 1536;
  size_t i=(size_t)blockIdx.x*blockDim.x+threadIdx.x;
  size_t tot=(size_t)1536*K;
  if(i>=tot) return;
  int rp=(int)(i/K); int k=(int)(i-(size_t)rp*K);
  int f=rp>>4, rr=rp&15;
  int g=f%3, cgrp=f/3;
  int orig=g*512+cgrp*16+rr;
  float v;
  if(internal){
    if(k<768)        v=W[(size_t)orig*768+k];
    else if(k<1536)  v=W[(size_t)orig*768+(k-768)];
    else             v=U[(size_t)orig*512+(k-1536)];
  }else{
    int kk=(k<768)?k:k-768;
    v=W[(size_t)orig*768+kk];
  }
  d[i]=(bf16)v;
}

// ---------------- gate-major concat K=2048 (level-5 64-tile iou) ----------------
// row r in [0,1536): [Whi(768)|Whi(768)|Uhi(512)]
__global__ void k_concat2048(const float* __restrict__ W, const float* __restrict__ U,
                             bf16* __restrict__ d, int rows){
  size_t i=(size_t)blockIdx.x*blockDim.x+threadIdx.x;
  const int K=2048;
  size_t tot=(size_t)rows*K;
  if(i>=tot) return;
  int r=(int)(i/K); int k=(int)(i-(size_t)r*K);
  float v;
  if(k<768)        v=W[(size_t)r*768+k];
  else if(k<1536)  v=W[(size_t)r*768+(k-768)];
  else             v=U[(size_t)r*512+(k-1536)];
  d[i]=(bf16)v;
}

// ---------------- Wcomb = W_sd2 @ W_sd  (512x512, fp32 exact) ----------------
__global__ __launch_bounds__(256)
void k_wcomb(const float* __restrict__ W2, const float* __restrict__ W1,
             float* __restrict__ out){
  __shared__ float As[64][33];
  __shared__ float Bs[32][65];
  const int tid=threadIdx.x;
  const int i0=blockIdx.x*64, j0=blockIdx.y*64;
  const int tr=(tid>>4)*4, tc=(tid&15)*4;
  float acc[4][4];
  #pragma unroll
  for(int x=0;x<4;++x)
    #pragma unroll
    for(int y=0;y<4;++y) acc[x][y]=0.f;
  for(int k0=0;k0<1024;k0+=32){
    for(int l=tid;l<64*32;l+=256){ int r=l>>5,c=l&31; As[r][c]=W2[(size_t)(i0+r)*1024+k0+c]; }
    for(int l=tid;l<32*64;l+=256){ int r=l>>6,c=l&63; Bs[r][c]=W1[(size_t)(k0+r)*512+j0+c]; }
    __syncthreads();
    #pragma unroll 8
    for(int k=0;k<32;++k){
      float a[4],b[4];
      #pragma unroll
      for(int x=0;x<4;++x){ a[x]=As[tr+x][k]; b[x]=Bs[k][tc+x]; }
      #pragma unroll
      for(int x=0;x<4;++x)
        #pragma unroll
        for(int y=0;y<4;++y) acc[x][y]+=a[x]*b[y];
    }
    __syncthreads();
  }
  #pragma unroll
  for(int x=0;x<4;++x)
    #pragma unroll
    for(int y=0;y<4;++y) out[(size_t)(i0+tr+x)*512+j0+tc+y]=acc[x][y];
}

// ---------------- Wy[j,c] = Wsf[j,c] + sum_d Wsf[j,d]*Wcomb[d,c] ----------------
__global__ void k_wy(const float* __restrict__ Wsf, const float* __restrict__ Wcomb,
                     float* __restrict__ Wy){
  int idx=blockIdx.x*256+threadIdx.x;
  if(idx>=2048) return;
  int j=idx>>9, c=idx&511;
  float s=Wsf[j*512+c];
  for(int d=0;d<512;++d) s+=Wsf[j*512+d]*Wcomb[(size_t)d*512+c];
  Wy[(size_t)j*512+c]=s;
}

// ================= iou GEMM: 128 x 192, dbuf + counted vmcnt + setprio, XCD-chunked =================
__global__ __launch_bounds__(256,2)
void k_iou128p(const bf16* __restrict__ fH, const bf16* __restrict__ fL,
               const bf16* __restrict__ hsH,
               const bf16* __restrict__ Wil, const float* __restrict__ bias,
               const float* __restrict__ csum, bf16* __restrict__ hbuf,
               bf16* __restrict__ hlo, float* __restrict__ cbuf,
               int start_n, int shift, int internal)
{
  extern __shared__ char sm[];                 // A: 2x16384, B: 2x24576
  char* Abase=sm;
  char* Bbase=sm+32768;
  const int tid=threadIdx.x;
  const int w=tid>>6, lane=tid&63;
  int x, my;
  xcd_map(blockIdx.x, gridDim.x, 8, x, my);
  const int m0=my*128;
  const int K = internal? 2048 : 1536;
  const int NT = K>>6;

  unsigned fofs[4], hofs[4];
  #pragma unroll
  for(int i=0;i<4;++i){
    int r=w*32+i*8+(lane>>3);
    int m=m0+r;
    int t_=m>>shift, j=m-(t_<<shift);
    fofs[i]=(unsigned)(((size_t)t_*NPT+start_n+j)*768);
    hofs[i]=(unsigned)m*512u;
  }
  unsigned bofs[6];
  #pragma unroll
  for(int i=0;i<6;++i){
    int r=x*192+w*48+i*8+(lane>>3);
    bofs[i]=(unsigned)r*(unsigned)K;
  }
  const unsigned swz=8u*((unsigned)(lane&7)^(unsigned)(lane>>3));

  f32x4 acc[4][6];
  #pragma unroll
  for(int mi=0;mi<4;++mi)
    #pragma unroll
    for(int ni=0;ni<6;++ni) acc[mi][ni]=(f32x4){0.f,0.f,0.f,0.f};

  const int wr=(w>>1)*64;
  const int wcF=(w&1)*6;
  const int lr=lane&15, lg=lane>>4;

  auto STAGE=[&](int buf, int t){
    const bf16* base; int kt; bool useF;
    if(internal){
      if(t<12){ base=fH; kt=t;    useF=true; }
      else if(t<24){ base=fL; kt=t-12; useF=true; }
      else        { base=hsH; kt=t-24; useF=false; }
    }else{
      if(t<12){ base=fH; kt=t;    useF=true; }
      else    { base=fL; kt=t-12; useF=true; }
    }
    const unsigned kofs=(unsigned)kt*64u+swz;
    char* Ad=Abase+(size_t)buf*16384;
    #pragma unroll
    for(int i=0;i<4;++i){
      const bf16* g=base+(useF?fofs[i]:hofs[i])+kofs;
      gll16(g, Ad+(w*32+i*8)*128);
    }
    const unsigned bk=(unsigned)t*64u+swz;
    char* Bd=Bbase+(size_t)buf*24576;
    #pragma unroll
    for(int i=0;i<6;++i){
      gll16(Wil+bofs[i]+bk, Bd+(w*48+i*8)*128);
    }
  };

  auto COMPUTE=[&](int cur){
    const char* Ab=Abase+(size_t)cur*16384;
    const char* Bb=Bbase+(size_t)cur*24576;
    #pragma unroll
    for(int ks=0;ks<2;++ks){
      const unsigned cb=((unsigned)(ks*64+lg*16)) ^ ((unsigned)(lr&7)<<4);
      bf16x8 av[4], bv[6];
      #pragma unroll
      for(int mi=0;mi<4;++mi)
        av[mi]=*(const bf16x8*)(Ab+(unsigned)(wr+mi*16+lr)*128u+cb);
      #pragma unroll
      for(int ni=0;ni<6;++ni)
        bv[ni]=*(const bf16x8*)(Bb+(unsigned)((wcF+ni)*16+lr)*128u+cb);
      __builtin_amdgcn_s_setprio(1);
      #pragma unroll
      for(int ni=0;ni<6;++ni)
        #pragma unroll
        for(int mi=0;mi<4;++mi)
          acc[mi][ni]=__builtin_amdgcn_mfma_f32_16x16x32_bf16(av[mi],bv[ni],acc[mi][ni],0,0,0);
      __builtin_amdgcn_s_setprio(0);
    }
  };

  STAGE(0,0);
  STAGE(1,1);
  asm volatile("s_waitcnt vmcnt(10)" ::: "memory");
  __builtin_amdgcn_s_barrier();
  __builtin_amdgcn_sched_barrier(0);

  for(int t=0;t<NT;++t){
    COMPUTE(t&1);
    if(t+1<NT){
      __builtin_amdgcn_sched_barrier(0);
      __builtin_amdgcn_s_barrier();
      __builtin_amdgcn_sched_barrier(0);
      if(t+2<NT){
        STAGE(t&1, t+2);
        asm volatile("s_waitcnt vmcnt(10)" ::: "memory");
      }else{
        asm volatile("s_waitcnt vmcnt(0)" ::: "memory");
      }
      __builtin_amdgcn_s_barrier();
      __builtin_amdgcn_sched_barrier(0);
    }
  }

  #pragma unroll
  for(int mi=0;mi<4;++mi){
    #pragma unroll
    for(int cg=0;cg<2;++cg){
      const int col = x*64 + ((w&1)*2+cg)*16 + lr;
      const float bi=bias[col], bo=bias[col+512], bu=bias[col+1024];
      #pragma unroll
      for(int r=0;r<4;++r){
        const int mm=m0+wr+mi*16+lg*4+r;
        float iv=acc[mi][3*cg+0][r]+bi;
        float ov=acc[mi][3*cg+1][r]+bo;
        float uv=acc[mi][3*cg+2][r]+bu;
        float cn=sigm(iv)*ftanh(uv);
        if(internal) cn+=csum[(size_t)mm*HD+col];
        float hn=sigm(ov)*ftanh(cn);
        const int tt=mm>>shift, jj=mm-(tt<<shift);
        const size_t nd=((size_t)tt*NPT+start_n+jj)*HD+col;
        cbuf[nd]=cn;
        bf16 hh=(bf16)hn;
        hbuf[nd]=hh;
        hlo[nd]=(bf16)(hn-(float)hh);
      }
    }
  }
}

// ---------------- old 64-tile iou (level 5 only, P=64; K=2048 gate-major layout) ----------------
__global__ __launch_bounds__(256)
void k_iou(const bf16* __restrict__ fH, const bf16* __restrict__ fL,
           const bf16* __restrict__ hsH,
           const bf16* __restrict__ Wcat, const float* __restrict__ bias,
           const float* __restrict__ csum, bf16* __restrict__ hbuf,
           bf16* __restrict__ hlo, float* __restrict__ cbuf,
           int start_n, int shift, int K, int KB, int internal)
{
  __shared__ bf16 As[64][40];
  __shared__ bf16 Bs[3][64][40];
  const int tid=threadIdx.x;
  const int m0=blockIdx.x*64, n0=blockIdx.y*64;
  const int srow=tid>>2, skc=(tid&3)*8;
  const int m=m0+srow;
  const int t=m>>shift, j=m-(t<<shift);
  const size_t frow=((size_t)t*NPT+start_n+j)*768;
  const bf16* aFH=fH+frow;
  const bf16* aFL=fL+frow;
  const bf16* aHH=hsH+(size_t)m*HD;
  const bf16* bp0=Wcat+(size_t)(n0+srow)*KB;
  const bf16* bp1=Wcat+(size_t)(512+n0+srow)*KB;
  const bf16* bp2=Wcat+(size_t)(1024+n0+srow)*KB;

  f32x4 acc[3][2][2];
  #pragma unroll
  for(int g=0;g<3;++g)
    #pragma unroll
    for(int mi=0;mi<2;++mi)
      #pragma unroll
      for(int ni=0;ni<2;++ni) acc[g][mi][ni]=(f32x4){0.f,0.f,0.f,0.f};

  const int w=tid>>6, lane=tid&63;
  const int wr=(w>>1)*32, wc=(w&1)*32;
  const int lr=lane&15, lg=lane>>4;

  for(int k0=0;k0<K;k0+=32){
    const bf16* ap;
    if(internal){
      if(k0<768)        ap=aFH+k0;
      else if(k0<1536)  ap=aFL+(k0-768);
      else              ap=aHH+(k0-1536);
    }else{
      ap=(k0<768)? (aFH+k0) : (aFL+(k0-768));
    }
    *(bf16x8*)&As[srow][skc]=*(const bf16x8*)(ap+skc);
    *(bf16x8*)&Bs[0][srow][skc]=*(const bf16x8*)(bp0+k0+skc);
    *(bf16x8*)&Bs[1][srow][skc]=*(const bf16x8*)(bp1+k0+skc);
    *(bf16x8*)&Bs[2][srow][skc]=*(const bf16x8*)(bp2+k0+skc);
    __syncthreads();
    bf16x8 a0=*(bf16x8*)&As[wr+lr][lg*8];
    bf16x8 a1=*(bf16x8*)&As[wr+16+lr][lg*8];
    #pragma unroll
    for(int g=0;g<3;++g){
      #pragma unroll
      for(int ni=0;ni<2;++ni){
        bf16x8 bv=*(bf16x8*)&Bs[g][wc+ni*16+lr][lg*8];
        acc[g][0][ni]=__builtin_amdgcn_mfma_f32_16x16x32_bf16(a0,bv,acc[g][0][ni],0,0,0);
        acc[g][1][ni]=__builtin_amdgcn_mfma_f32_16x16x32_bf16(a1,bv,acc[g][1][ni],0,0,0);
      }
    }
    __syncthreads();
  }

  #pragma unroll
  for(int mi=0;mi<2;++mi){
    #pragma unroll
    for(int ni=0;ni<2;++ni){
      const int col=n0+wc+ni*16+lr;
      const float bi=bias[col], bo=bias[col+512], bu=bias[col+1024];
      #pragma unroll
      for(int r=0;r<4;++r){
        const int mm=m0+wr+mi*16+lg*4+r;
        float iv=acc[0][mi][ni][r]+bi;
        float ov=acc[1][mi][ni][r]+bo;
        float uv=acc[2][mi][ni][r]+bu;
        float cn=sigm(iv)*ftanh(uv);
        if(internal) cn+=csum[(size_t)mm*HD+col];
        float hn=sigm(ov)*ftanh(cn);
        const int tt=mm>>shift, jj=mm-(tt<<shift);
        const size_t nd=((size_t)tt*NPT+start_n+jj)*HD+col;
        cbuf[nd]=cn;
        bf16 hh=(bf16)hn;
        hbuf[nd]=hh;
        hlo[nd]=(bf16)(hn-(float)hh);
      }
    }
  }
}

// ================= XWf: pipelined 128x128 (NT=24), 1D grid =================
__global__ __launch_bounds__(256,2)
void k_xwf128p(const bf16* __restrict__ fH, const bf16* __restrict__ fL,
               const bf16* __restrict__ Wfc, float* __restrict__ XWf, int Mtot)
{
  extern __shared__ char sm[];     // A: 2x16384, B: 2x16384
  char* Abase=sm;
  char* Bbase=sm+32768;
  const int tid=threadIdx.x;
  const int w=tid>>6, lane=tid&63;
  int xb, my;
  xcd_map(blockIdx.x, gridDim.x, 4, xb, my);
  const int m0=my*128, n0=xb*128;
  const int NT=24;

  unsigned fofs[4];
  #pragma unroll
  for(int i=0;i<4;++i){
    int r=w*32+i*8+(lane>>3);
    int m=m0+r; if(m>=Mtot) m=Mtot-1;
    int t=m/NINT; int j=1024+(m-t*NINT);
    fofs[i]=(unsigned)(((size_t)t*NPT+j)*768);
  }
  unsigned bofs[4];
  #pragma unroll
  for(int i=0;i<4;++i){
    int r=n0+w*32+i*8+(lane>>3);
    bofs[i]=(unsigned)r*1536u;
  }
  const unsigned swz=8u*((unsigned)(lane&7)^(unsigned)(lane>>3));

  f32x4 acc[4][4];
  #pragma unroll
  for(int mi=0;mi<4;++mi)
    #pragma unroll
    for(int ni=0;ni<4;++ni) acc[mi][ni]=(f32x4){0.f,0.f,0.f,0.f};

  const int wr=(w>>1)*64, wc=(w&1)*64;
  const int lr=lane&15, lg=lane>>4;

  auto STAGE=[&](int buf, int t){
    const bf16* Abuf; unsigned ak, bk;
    if(t<12){ Abuf=fH; ak=(unsigned)t*64u; bk=(unsigned)t*64u; }
    else    { Abuf=fL; ak=(unsigned)(t-12)*64u; bk=(unsigned)(t-12)*64u; }
    char* Ad=Abase+(size_t)buf*16384;
    #pragma unroll
    for(int i=0;i<4;++i)
      gll16(Abuf+fofs[i]+ak+swz, Ad+(w*32+i*8)*128);
    char* Bd=Bbase+(size_t)buf*16384;
    #pragma unroll
    for(int i=0;i<4;++i)
      gll16(Wfc+bofs[i]+bk+swz, Bd+(w*32+i*8)*128);
  };

  auto COMPUTE=[&](int cur){
    const char* Ab=Abase+(size_t)cur*16384;
    const char* Bb=Bbase+(size_t)cur*16384;
    #pragma unroll
    for(int ks=0;ks<2;++ks){
      const unsigned cb=((unsigned)(ks*64+lg*16)) ^ ((unsigned)(lr&7)<<4);
      bf16x8 av[4], bv[4];
      #pragma unroll
      for(int mi=0;mi<4;++mi)
        av[mi]=*(const bf16x8*)(Ab+(unsigned)(wr+mi*16+lr)*128u+cb);
      #pragma unroll
      for(int ni=0;ni<4;++ni)
        bv[ni]=*(const bf16x8*)(Bb+(unsigned)((wc+ni*16)+lr)*128u+cb);
      __builtin_amdgcn_s_setprio(1);
      #pragma unroll
      for(int ni=0;ni<4;++ni)
        #pragma unroll
        for(int mi=0;mi<4;++mi)
          acc[mi][ni]=__builtin_amdgcn_mfma_f32_16x16x32_bf16(av[mi],bv[ni],acc[mi][ni],0,0,0);
      __builtin_amdgcn_s_setprio(0);
    }
  };

  STAGE(0,0);
  STAGE(1,1);
  asm volatile("s_waitcnt vmcnt(8)" ::: "memory");
  __builtin_amdgcn_s_barrier();
  __builtin_amdgcn_sched_barrier(0);

  for(int t=0;t<NT;++t){
    COMPUTE(t&1);
    if(t+1<NT){
      __builtin_amdgcn_sched_barrier(0);
      __builtin_amdgcn_s_barrier();
      __builtin_amdgcn_sched_barrier(0);
      if(t+2<NT){
        STAGE(t&1, t+2);
        asm volatile("s_waitcnt vmcnt(8)" ::: "memory");
      }else{
        asm volatile("s_waitcnt vmcnt(0)" ::: "memory");
      }
      __builtin_amdgcn_s_barrier();
      __builtin_amdgcn_sched_barrier(0);
    }
  }

  #pragma unroll
  for(int mi=0;mi<4;++mi){
    #pragma unroll
    for(int ni=0;ni<4;++ni){
      const int col=n0+wc+ni*16+lr;
      #pragma unroll
      for(int r=0;r<4;++r){
        const int mm=m0+wr+mi*16+lg*4+r;
        if(mm<Mtot) XWf[(size_t)mm*512+col]=acc[mi][ni][r];
      }
    }
  }
}

// ================= Uh forget-gate: pipelined 128x128 (NT=8, hi-only) + fused csum/hsum =================
__global__ __launch_bounds__(256,2)
void k_uh128p(const bf16* __restrict__ hhi, const bf16* __restrict__ hlo,
              const bf16* __restrict__ Ufc, const float* __restrict__ bias,
              const float* __restrict__ XWf, const float* __restrict__ cbuf,
              float* __restrict__ csum, bf16* __restrict__ hs_hi,
              int start_ch, int lc, int xwoff)
{
  extern __shared__ char sm[];     // A: 2x16384, B: 2x16384
  char* Abase=sm;
  char* Bbase=sm+32768;
  const int tid=threadIdx.x;
  const int w=tid>>6, lane=tid&63;
  int xb, my;
  xcd_map(blockIdx.x, gridDim.x, 4, xb, my);
  const int e0=my*128, n0=xb*128;
  const int NT=8;

  unsigned hofs[4];
  #pragma unroll
  for(int i=0;i<4;++i){
    int r=w*32+i*8+(lane>>3);
    int e=e0+r;
    int t=e>>lc, ei=e-(t<<lc);
    hofs[i]=(unsigned)(((size_t)t*NPT+start_ch+ei)*HD);
  }
  unsigned bofs[4];
  #pragma unroll
  for(int i=0;i<4;++i){
    int r=n0+w*32+i*8+(lane>>3);
    bofs[i]=(unsigned)r*1024u;
  }
  const unsigned swz=8u*((unsigned)(lane&7)^(unsigned)(lane>>3));

  f32x4 acc[4][4];
  #pragma unroll
  for(int mi=0;mi<4;++mi)
    #pragma unroll
    for(int ni=0;ni<4;++ni) acc[mi][ni]=(f32x4){0.f,0.f,0.f,0.f};

  const int wr=(w>>1)*64, wc=(w&1)*64;
  const int lr=lane&15, lg=lane>>4;

  auto STAGE=[&](int buf, int t){
    const unsigned ak=(unsigned)t*64u, bk=(unsigned)t*64u;
    char* Ad=Abase+(size_t)buf*16384;
    #pragma unroll
    for(int i=0;i<4;++i)
      gll16(hhi+hofs[i]+ak+swz, Ad+(w*32+i*8)*128);
    char* Bd=Bbase+(size_t)buf*16384;
    #pragma unroll
    for(int i=0;i<4;++i)
      gll16(Ufc+bofs[i]+bk+swz, Bd+(w*32+i*8)*128);
  };

  auto COMPUTE=[&](int cur){
    const char* Ab=Abase+(size_t)cur*16384;
    const char* Bb=Bbase+(size_t)cur*16384;
    #pragma unroll
    for(int ks=0;ks<2;++ks){
      const unsigned cb=((unsigned)(ks*64+lg*16)) ^ ((unsigned)(lr&7)<<4);
      bf16x8 av[4], bv[4];
      #pragma unroll
      for(int mi=0;mi<4;++mi)
        av[mi]=*(const bf16x8*)(Ab+(unsigned)(wr+mi*16+lr)*128u+cb);
      #pragma unroll
      for(int ni=0;ni<4;++ni)
        bv[ni]=*(const bf16x8*)(Bb+(unsigned)((wc+ni*16)+lr)*128u+cb);
      __builtin_amdgcn_s_setprio(1);
      #pragma unroll
      for(int ni=0;ni<4;++ni)
        #pragma unroll
        for(int mi=0;mi<4;++mi)
          acc[mi][ni]=__builtin_amdgcn_mfma_f32_16x16x32_bf16(av[mi],bv[ni],acc[mi][ni],0,0,0);
      __builtin_amdgcn_s_setprio(0);
    }
  };

  STAGE(0,0);
  STAGE(1,1);
  asm volatile("s_waitcnt vmcnt(8)" ::: "memory");
  __builtin_amdgcn_s_barrier();
  __builtin_amdgcn_sched_barrier(0);

  for(int t=0;t<NT;++t){
    COMPUTE(t&1);
    if(t+1<NT){
      __builtin_amdgcn_sched_barrier(0);
      __builtin_amdgcn_s_barrier();
      __builtin_amdgcn_sched_barrier(0);
      if(t+2<NT){
        STAGE(t&1, t+2);
        asm volatile("s_waitcnt vmcnt(8)" ::: "memory");
      }else{
        asm volatile("s_waitcnt vmcnt(0)" ::: "memory");
      }
      __builtin_amdgcn_s_barrier();
      __builtin_amdgcn_sched_barrier(0);
    }
  }

  #pragma unroll
  for(int mi=0;mi<4;++mi){
    const int ebase=e0+wr+mi*16+lg*4;
    const int tt=ebase>>lc, eib=ebase-(tt<<lc);
    const int inode=tt*NINT + xwoff + (eib>>2);
    const int par=ebase>>2;
    #pragma unroll
    for(int ni=0;ni<4;++ni){
      const int col=n0+wc+ni*16+lr;
      const float base=bias[col]+XWf[(size_t)inode*512+col];
      const size_t chbase=((size_t)tt*NPT+start_ch+eib)*HD+col;
      float s=0.f, hsv=0.f;
      #pragma unroll
      for(int r=0;r<4;++r){
        const size_t ci=chbase+(size_t)r*HD;
        float fv=sigm(acc[mi][ni][r]+base);
        s+=fv*cbuf[ci];
        hsv+=(float)hhi[ci]+(float)hlo[ci];
      }
      csum[(size_t)par*HD+col]=s;
      hs_hi[(size_t)par*HD+col]=(bf16)hsv;
    }
  }
}

// ---------------- final head ----------------
__global__ __launch_bounds__(256)
void k_final2(const bf16* __restrict__ hhi, const bf16* __restrict__ hlo,
              const float* __restrict__ Wy, const float* __restrict__ gamma,
              const float* __restrict__ beta, float* __restrict__ out0, int Nn)
{
  const int gtid=blockIdx.x*256+threadIdx.x;
  const int node=gtid>>6, lane=gtid&63;
  if(node>=Nn) return;
  const size_t base=(size_t)node*HD+lane*8;
  bf16x8 hv=*(const bf16x8*)(hhi+base);
  bf16x8 lv=*(const bf16x8*)(hlo+base);
  float hf[8];
  #pragma unroll
  for(int e=0;e<8;++e) hf[e]=(float)hv[e]+(float)lv[e];
  float y[4];
  #pragma unroll
  for(int jj=0;jj<4;++jj){
    const float* wp=Wy+jj*HD+lane*8;
    float s=0.f;
    #pragma unroll
    for(int e=0;e<8;++e) s+=hf[e]*wp[e];
    #pragma unroll
    for(int off=32;off>=1;off>>=1) s+=__shfl_xor(s,off,64);
    y[jj]=s;
  }
  if(lane==0){
    float mu=0.25f*(y[0]+y[1]+y[2]+y[3]);
    float var=0.f;
    #pragma unroll
    for(int jj=0;jj<4;++jj){ float d=y[jj]-mu; var+=d*d; }
    var*=0.25f;
    float rs=rsqrtf(var+1e-6f);
    float z[4], zmax=-1e30f;
    #pragma unroll
    for(int jj=0;jj<4;++jj){ z[jj]=(y[jj]-mu)*rs*gamma[jj]+beta[jj]; zmax=fmaxf(zmax,z[jj]); }
    float es=0.f;
    #pragma unroll
    for(int jj=0;jj<4;++jj){ z[jj]=__expf(z[jj]-zmax); es+=z[jj]; }
    float inv=1.f/es;
    #pragma unroll
    for(int jj=0;jj<4;++jj) out0[(size_t)node*4+jj]=z[jj]*inv;
  }
}

// ---------------- root head ----------------
__global__ __launch_bounds__(256)
void k_root(const bf16* __restrict__ hhi, const bf16* __restrict__ hlo,
            const float* __restrict__ Wff, float* __restrict__ out1)
{
  const int gtid=blockIdx.x*256+threadIdx.x;
  const int tt=gtid>>6, lane=gtid&63;
  if(tt>=64) return;
  const size_t base=((size_t)tt*NPT+1364)*HD+lane*8;
  bf16x8 hv=*(const bf16x8*)(hhi+base);
  bf16x8 lv=*(const bf16x8*)(hlo+base);
  float hf[8];
  #pragma unroll
  for(int e=0;e<8;++e) hf[e]=(float)hv[e]+(float)lv[e];
  float y[4];
  #pragma unroll
  for(int jj=0;jj<4;++jj){
    const float* wp=Wff+jj*HD+lane*8;
    float s=0.f;
    #pragma unroll
    for(int e=0;e<8;++e) s+=hf[e]*wp[e];
    #pragma unroll
    for(int off=32;off>=1;off>>=1) s+=__shfl_xor(s,off,64);
    y[jj]=s;
  }
  if(lane==0){
    float zmax=fmaxf(fmaxf(y[0],y[1]),fmaxf(y[2],y[3]));
    float es=0.f, z[4];
    #pragma unroll
    for(int jj=0;jj<4;++jj){ z[jj]=__expf(y[jj]-zmax); es+=z[jj]; }
    float inv=1.f/es;
    #pragma unroll
    for(int jj=0;jj<4;++jj) out1[(size_t)tt*4+jj]=z[jj]*inv;
  }
}

extern "C" void kernel_launch(void* const* d_in, const int* in_sizes, int n_in,
                              void* d_out, int out_size, void* d_ws, size_t ws_size,
                              hipStream_t stream)
{
  const float* features=(const float*)d_in[0];
  const float* W_iou=(const float*)d_in[6];
  const float* b_iou=(const float*)d_in[7];
  const float* U_iou=(const float*)d_in[8];
  const float* W_f  =(const float*)d_in[9];
  const float* b_f  =(const float*)d_in[10];
  const float* U_f  =(const float*)d_in[11];
  const float* W_ff =(const float*)d_in[12];
  const float* W_sd =(const float*)d_in[13];
  const float* W_sd2=(const float*)d_in[14];
  const float* W_sf =(const float*)d_in[15];
  const float* ln_g =(const float*)d_in[16];
  const float* ln_b =(const float*)d_in[17];

  const int N=in_sizes[0]/768;   // 87360
  const int T=N/NPT;             // 64
  const int MINT=T*NINT;         // 21824

  float* out0=(float*)d_out;
  float* out1=out0+(size_t)N*4;
  float* cbuf=out1+(size_t)T*4;  // c output region (live c-state)

  char* p=(char*)d_ws;
  auto alloc=[&](size_t bytes){ char* r=p; p+=((bytes+255)&~(size_t)255); return r; };
  bf16*  f_hi =(bf16*) alloc((size_t)N*768*2);
  bf16*  f_lo =(bf16*) alloc((size_t)N*768*2);
  bf16*  hs_hi=(bf16*) alloc((size_t)16384*HD*2);
  float* csum =(float*)alloc((size_t)16384*HD*4);
  bf16*  h_hi =(bf16*) alloc((size_t)N*HD*2);
  bf16*  h_lo =(bf16*) alloc((size_t)N*HD*2);
  bf16*  WilL =(bf16*) alloc((size_t)1536*1536*2);
  bf16*  WilI =(bf16*) alloc((size_t)1536*2048*2);
  bf16*  Wcat2=(bf16*) alloc((size_t)1536*2048*2);   // level-5 64-tile layout
  bf16*  Wfc  =(bf16*) alloc((size_t)512*1536*2);
  bf16*  Ufc  =(bf16*) alloc((size_t)512*1024*2);
  float* Wcomb=(float*)alloc((size_t)512*512*4);
  float* Wy   =(float*)alloc((size_t)4*512*4);
  float* XWf  =(float*)alloc((size_t)MINT*512*4);

  // conversions / weight prep
  { size_t n8=(size_t)N*768/8;  k_split8<<<(int)((n8+255)/256),256,0,stream>>>(features,f_hi,f_lo,n8); }
  { size_t n=(size_t)1536*1536; k_wil<<<(int)((n+255)/256),256,0,stream>>>(W_iou,U_iou,WilL,0); }
  { size_t n=(size_t)1536*2048; k_wil<<<(int)((n+255)/256),256,0,stream>>>(W_iou,U_iou,WilI,1); }
  { size_t n=(size_t)1536*2048; k_concat2048<<<(int)((n+255)/256),256,0,stream>>>(W_iou,U_iou,Wcat2,1536); }
  { size_t n=(size_t)512*1536;  k_catHL<<<(int)((n+255)/256),256,0,stream>>>(W_f,Wfc,512,768); }
  { size_t n=(size_t)512*1024;  k_catHL<<<(int)((n+255)/256),256,0,stream>>>(U_f,Ufc,512,512); }
  { dim3 g(8,8); k_wcomb<<<g,256,0,stream>>>(W_sd2,W_sd,Wcomb); }
  { k_wy<<<8,256,0,stream>>>(W_sf,Wcomb,Wy); }

  // upfront: XWf for all internal nodes (pipelined, 1D grid)
  { int nb=4*((MINT+127)/128);
    k_xwf128p<<<nb,256,G128_LDS,stream>>>(f_hi,f_lo,Wfc,XWf,MINT); }

  static const int starts[6]={0,1024,1280,1344,1360,1364};
  static const int csh[6]  ={10,8,6,4,2,0};
  static const int counts[6]={1024,256,64,16,4,1};
  static const int xwoffs[6]={0,0,256,320,336,340};

  // level 0 (leaves): XCD-chunked 1D grid
  { int nb=8*((T*1024)/128);
    k_iou128p<<<nb,256,IOU_LDS,stream>>>(f_hi,f_lo,hs_hi,WilL,b_iou,csum,h_hi,h_lo,cbuf,0,10,0); }

  for(int n=1;n<6;++n){
    int P=T*counts[n], E=T*counts[n-1];
    { int nb=4*(E/128);
      k_uh128p<<<nb,256,G128_LDS,stream>>>(h_hi,h_lo,Ufc,b_f,XWf,cbuf,csum,hs_hi,
                                           starts[n-1],csh[n-1],xwoffs[n]); }
    if(P>=128){
      int nb=8*(P/128);
      k_iou128p<<<nb,256,IOU_LDS,stream>>>(f_hi,f_lo,hs_hi,WilI,b_iou,csum,h_hi,h_lo,cbuf,starts[n],csh[n],1);
    }else{
      dim3 g(P/64,8);
      k_iou<<<g,256,0,stream>>>(f_hi,f_lo,hs_hi,Wcat2,b_iou,csum,h_hi,h_lo,cbuf,starts[n],csh[n],2048,2048,1);
    }
  }

  // heads (stance folded into Wy)
  { int th=N*64; k_final2<<<(th+255)/256,256,0,stream>>>(h_hi,h_lo,Wy,ln_g,ln_b,out0,N); }
  { k_root<<<16,256,0,stream>>>(h_hi,h_lo,W_ff,out1); }
}

// Round 21
// 984.747 us; speedup vs baseline: 2.4978x; 1.2868x over previous
//
#include <hip/hip_runtime.h>
#include <hip/hip_bf16.h>
#include <math.h>

typedef _Float16 f16;
typedef f16 f16x8 __attribute__((ext_vector_type(8)));
typedef float f32x4 __attribute__((ext_vector_type(4)));

#define NPT 1365
#define HD 512
#define NINT 341   // internal nodes per tree (256+64+16+4+1)
#define IOU_LDS (2*128*64*2 + 2*192*64*2)   // 81920 B -> 2 blocks/CU
#define G128_LDS (2*128*64*2 + 2*128*64*2)  // 65536 B -> 2 blocks/CU

__device__ __forceinline__ float frcp(float x){ return __builtin_amdgcn_rcpf(x); }
__device__ __forceinline__ float sigm(float x){ return frcp(1.0f+__expf(-x)); }
__device__ __forceinline__ float ftanh(float x){
  float e=__expf(2.f*fabsf(x));
  float t=1.f-2.f*frcp(e+1.f);
  return copysignf(t,x);
}

__device__ __forceinline__ void gll16(const void* g, void* l){
  __builtin_amdgcn_global_load_lds((const __attribute__((address_space(1))) void*)g,
                                   (__attribute__((address_space(3))) void*)l, 16, 0, 0);
}

// XCD-chunked bijection: phys%8 = XCD; each XCD gets a contiguous y-range with all x.
__device__ __forceinline__ void xcd_map(int phys, int nb, int xdim, int& x, int& my){
  int ytiles = nb / xdim;
  if((ytiles & 7)==0){
    int k = phys & 7, i = phys >> 3;
    my = k * (ytiles >> 3) + i / xdim;
    x  = i % xdim;
  }else{
    x  = phys % xdim;
    my = phys / xdim;
  }
}

// ---------------- fp32 -> f16 cast, 8 elems/thread ----------------
__global__ void k_cvt16(const float* __restrict__ s, f16* __restrict__ d, size_t n8){
  size_t i=(size_t)blockIdx.x*blockDim.x+threadIdx.x;
  if(i>=n8) return;
  const float4* sp=(const float4*)(s+i*8);
  float4 a=sp[0], b=sp[1];
  float v[8]={a.x,a.y,a.z,a.w,b.x,b.y,b.z,b.w};
  f16x8 h;
  #pragma unroll
  for(int e=0;e<8;++e) h[e]=(f16)v[e];
  *(f16x8*)(d+i*8)=h;
}

// ---------------- gate-interleaved iou weights (f16) ----------------
// leaf   (K=768):  [W]      ; intern (K=1280): [W(768)|U(512)]
__global__ void k_wil(const float* __restrict__ W, const float* __restrict__ U,
                      f16* __restrict__ d, int internal){
  const int K = internal? 1280 : 768;
  size_t i=(size_t)blockIdx.x*blockDim.x+threadIdx.x;
  size_t tot=(size_t)1536*K;
  if(i>=tot) return;
  int rp=(int)(i/K); int k=(int)(i-(size_t)rp*K);
  int f=rp>>4, rr=rp&15;
  int g=f%3, cgrp=f/3;
  int orig=g*512+cgrp*16+rr;
  float v;
  if(internal) v = (k<768)? W[(size_t)orig*768+k] : U[(size_t)orig*512+(k-768)];
  else         v = W[(size_t)orig*768+k];
  d[i]=(f16)v;
}

// ---------------- gate-major concat K=1280 (level-5 64-tile iou), f16 ----------------
__global__ void k_concat1280(const float* __restrict__ W, const float* __restrict__ U,
                             f16* __restrict__ d, int rows){
  size_t i=(size_t)blockIdx.x*blockDim.x+threadIdx.x;
  const int K=1280;
  size_t tot=(size_t)rows*K;
  if(i>=tot) return;
  int r=(int)(i/K); int k=(int)(i-(size_t)r*K);
  float v = (k<768)? W[(size_t)r*768+k] : U[(size_t)r*512+(k-768)];
  d[i]=(f16)v;
}

// ---------------- Wcomb = W_sd2 @ W_sd  (512x512, fp32 exact) ----------------
__global__ __launch_bounds__(256)
void k_wcomb(const float* __restrict__ W2, const float* __restrict__ W1,
             float* __restrict__ out){
  __shared__ float As[64][33];
  __shared__ float Bs[32][65];
  const int tid=threadIdx.x;
  const int i0=blockIdx.x*64, j0=blockIdx.y*64;
  const int tr=(tid>>4)*4, tc=(tid&15)*4;
  float acc[4][4];
  #pragma unroll
  for(int x=0;x<4;++x)
    #pragma unroll
    for(int y=0;y<4;++y) acc[x][y]=0.f;
  for(int k0=0;k0<1024;k0+=32){
    for(int l=tid;l<64*32;l+=256){ int r=l>>5,c=l&31; As[r][c]=W2[(size_t)(i0+r)*1024+k0+c]; }
    for(int l=tid;l<32*64;l+=256){ int r=l>>6,c=l&63; Bs[r][c]=W1[(size_t)(k0+r)*512+j0+c]; }
    __syncthreads();
    #pragma unroll 8
    for(int k=0;k<32;++k){
      float a[4],b[4];
      #pragma unroll
      for(int x=0;x<4;++x){ a[x]=As[tr+x][k]; b[x]=Bs[k][tc+x]; }
      #pragma unroll
      for(int x=0;x<4;++x)
        #pragma unroll
        for(int y=0;y<4;++y) acc[x][y]+=a[x]*b[y];
    }
    __syncthreads();
  }
  #pragma unroll
  for(int x=0;x<4;++x)
    #pragma unroll
    for(int y=0;y<4;++y) out[(size_t)(i0+tr+x)*512+j0+tc+y]=acc[x][y];
}

// ---------------- Wy[j,c] = Wsf[j,c] + sum_d Wsf[j,d]*Wcomb[d,c] ----------------
__global__ void k_wy(const float* __restrict__ Wsf, const float* __restrict__ Wcomb,
                     float* __restrict__ Wy){
  int idx=blockIdx.x*256+threadIdx.x;
  if(idx>=2048) return;
  int j=idx>>9, c=idx&511;
  float s=Wsf[j*512+c];
  for(int d=0;d<512;++d) s+=Wsf[j*512+d]*Wcomb[(size_t)d*512+c];
  Wy[(size_t)j*512+c]=s;
}

// ================= iou GEMM: 128 x 192, f16, dbuf + counted vmcnt + setprio, XCD-chunked =================
__global__ __launch_bounds__(256,2)
void k_iou128p(const f16* __restrict__ fx, const f16* __restrict__ hs16,
               const f16* __restrict__ Wil, const float* __restrict__ bias,
               const float* __restrict__ csum, f16* __restrict__ h16,
               float* __restrict__ cbuf,
               int start_n, int shift, int internal)
{
  extern __shared__ char sm[];                 // A: 2x16384, B: 2x24576
  char* Abase=sm;
  char* Bbase=sm+32768;
  const int tid=threadIdx.x;
  const int w=tid>>6, lane=tid&63;
  int x, my;
  xcd_map(blockIdx.x, gridDim.x, 8, x, my);
  const int m0=my*128;
  const int K = internal? 1280 : 768;
  const int NT = K>>6;

  unsigned fofs[4], hofs[4];
  #pragma unroll
  for(int i=0;i<4;++i){
    int r=w*32+i*8+(lane>>3);
    int m=m0+r;
    int t_=m>>shift, j=m-(t_<<shift);
    fofs[i]=(unsigned)(((size_t)t_*NPT+start_n+j)*768);
    hofs[i]=(unsigned)m*512u;
  }
  unsigned bofs[6];
  #pragma unroll
  for(int i=0;i<6;++i){
    int r=x*192+w*48+i*8+(lane>>3);
    bofs[i]=(unsigned)r*(unsigned)K;
  }
  const unsigned swz=8u*((unsigned)(lane&7)^(unsigned)(lane>>3));

  f32x4 acc[4][6];
  #pragma unroll
  for(int mi=0;mi<4;++mi)
    #pragma unroll
    for(int ni=0;ni<6;++ni) acc[mi][ni]=(f32x4){0.f,0.f,0.f,0.f};

  const int wr=(w>>1)*64;
  const int wcF=(w&1)*6;
  const int lr=lane&15, lg=lane>>4;

  auto STAGE=[&](int buf, int t){
    const f16* base; int kt; bool useF;
    if(internal){
      if(t<12){ base=fx;   kt=t;    useF=true;  }
      else    { base=hs16; kt=t-12; useF=false; }
    }else{
      base=fx; kt=t; useF=true;
    }
    const unsigned kofs=(unsigned)kt*64u+swz;
    char* Ad=Abase+(size_t)buf*16384;
    #pragma unroll
    for(int i=0;i<4;++i){
      const f16* g=base+(useF?fofs[i]:hofs[i])+kofs;
      gll16(g, Ad+(w*32+i*8)*128);
    }
    const unsigned bk=(unsigned)t*64u+swz;
    char* Bd=Bbase+(size_t)buf*24576;
    #pragma unroll
    for(int i=0;i<6;++i){
      gll16(Wil+bofs[i]+bk, Bd+(w*48+i*8)*128);
    }
  };

  auto COMPUTE=[&](int cur){
    const char* Ab=Abase+(size_t)cur*16384;
    const char* Bb=Bbase+(size_t)cur*24576;
    #pragma unroll
    for(int ks=0;ks<2;++ks){
      const unsigned cb=((unsigned)(ks*64+lg*16)) ^ ((unsigned)(lr&7)<<4);
      f16x8 av[4], bv[6];
      #pragma unroll
      for(int mi=0;mi<4;++mi)
        av[mi]=*(const f16x8*)(Ab+(unsigned)(wr+mi*16+lr)*128u+cb);
      #pragma unroll
      for(int ni=0;ni<6;++ni)
        bv[ni]=*(const f16x8*)(Bb+(unsigned)((wcF+ni)*16+lr)*128u+cb);
      __builtin_amdgcn_s_setprio(1);
      #pragma unroll
      for(int ni=0;ni<6;++ni)
        #pragma unroll
        for(int mi=0;mi<4;++mi)
          acc[mi][ni]=__builtin_amdgcn_mfma_f32_16x16x32_f16(av[mi],bv[ni],acc[mi][ni],0,0,0);
      __builtin_amdgcn_s_setprio(0);
    }
  };

  STAGE(0,0);
  STAGE(1,1);
  asm volatile("s_waitcnt vmcnt(10)" ::: "memory");
  __builtin_amdgcn_s_barrier();
  __builtin_amdgcn_sched_barrier(0);

  for(int t=0;t<NT;++t){
    COMPUTE(t&1);
    if(t+1<NT){
      __builtin_amdgcn_sched_barrier(0);
      __builtin_amdgcn_s_barrier();
      __builtin_amdgcn_sched_barrier(0);
      if(t+2<NT){
        STAGE(t&1, t+2);
        asm volatile("s_waitcnt vmcnt(10)" ::: "memory");
      }else{
        asm volatile("s_waitcnt vmcnt(0)" ::: "memory");
      }
      __builtin_amdgcn_s_barrier();
      __builtin_amdgcn_sched_barrier(0);
    }
  }

  #pragma unroll
  for(int mi=0;mi<4;++mi){
    #pragma unroll
    for(int cg=0;cg<2;++cg){
      const int col = x*64 + ((w&1)*2+cg)*16 + lr;
      const float bi=bias[col], bo=bias[col+512], bu=bias[col+1024];
      #pragma unroll
      for(int r=0;r<4;++r){
        const int mm=m0+wr+mi*16+lg*4+r;
        float iv=acc[mi][3*cg+0][r]+bi;
        float ov=acc[mi][3*cg+1][r]+bo;
        float uv=acc[mi][3*cg+2][r]+bu;
        float cn=sigm(iv)*ftanh(uv);
        if(internal) cn+=csum[(size_t)mm*HD+col];
        float hn=sigm(ov)*ftanh(cn);
        const int tt=mm>>shift, jj=mm-(tt<<shift);
        const size_t nd=((size_t)tt*NPT+start_n+jj)*HD+col;
        cbuf[nd]=cn;
        h16[nd]=(f16)hn;
      }
    }
  }
}

// ---------------- old 64-tile iou (level 5 only, P=64; K=1280 gate-major layout, f16) ----------------
__global__ __launch_bounds__(256)
void k_iou(const f16* __restrict__ fx, const f16* __restrict__ hs16,
           const f16* __restrict__ Wcat, const float* __restrict__ bias,
           const float* __restrict__ csum, f16* __restrict__ h16,
           float* __restrict__ cbuf,
           int start_n, int shift, int K, int KB, int internal)
{
  __shared__ f16 As[64][40];
  __shared__ f16 Bs[3][64][40];
  const int tid=threadIdx.x;
  const int m0=blockIdx.x*64, n0=blockIdx.y*64;
  const int srow=tid>>2, skc=(tid&3)*8;
  const int m=m0+srow;
  const int t=m>>shift, j=m-(t<<shift);
  const size_t frow=((size_t)t*NPT+start_n+j)*768;
  const f16* aF=fx+frow;
  const f16* aH=hs16+(size_t)m*HD;
  const f16* bp0=Wcat+(size_t)(n0+srow)*KB;
  const f16* bp1=Wcat+(size_t)(512+n0+srow)*KB;
  const f16* bp2=Wcat+(size_t)(1024+n0+srow)*KB;

  f32x4 acc[3][2][2];
  #pragma unroll
  for(int g=0;g<3;++g)
    #pragma unroll
    for(int mi=0;mi<2;++mi)
      #pragma unroll
      for(int ni=0;ni<2;++ni) acc[g][mi][ni]=(f32x4){0.f,0.f,0.f,0.f};

  const int w=tid>>6, lane=tid&63;
  const int wr=(w>>1)*32, wc=(w&1)*32;
  const int lr=lane&15, lg=lane>>4;

  for(int k0=0;k0<K;k0+=32){
    const f16* ap = (k0<768)? (aF+k0) : (aH+(k0-768));
    *(f16x8*)&As[srow][skc]=*(const f16x8*)(ap+skc);
    *(f16x8*)&Bs[0][srow][skc]=*(const f16x8*)(bp0+k0+skc);
    *(f16x8*)&Bs[1][srow][skc]=*(const f16x8*)(bp1+k0+skc);
    *(f16x8*)&Bs[2][srow][skc]=*(const f16x8*)(bp2+k0+skc);
    __syncthreads();
    f16x8 a0=*(f16x8*)&As[wr+lr][lg*8];
    f16x8 a1=*(f16x8*)&As[wr+16+lr][lg*8];
    #pragma unroll
    for(int g=0;g<3;++g){
      #pragma unroll
      for(int ni=0;ni<2;++ni){
        f16x8 bv=*(f16x8*)&Bs[g][wc+ni*16+lr][lg*8];
        acc[g][0][ni]=__builtin_amdgcn_mfma_f32_16x16x32_f16(a0,bv,acc[g][0][ni],0,0,0);
        acc[g][1][ni]=__builtin_amdgcn_mfma_f32_16x16x32_f16(a1,bv,acc[g][1][ni],0,0,0);
      }
    }
    __syncthreads();
  }

  #pragma unroll
  for(int mi=0;mi<2;++mi){
    #pragma unroll
    for(int ni=0;ni<2;++ni){
      const int col=n0+wc+ni*16+lr;
      const float bi=bias[col], bo=bias[col+512], bu=bias[col+1024];
      #pragma unroll
      for(int r=0;r<4;++r){
        const int mm=m0+wr+mi*16+lg*4+r;
        float iv=acc[0][mi][ni][r]+bi;
        float ov=acc[1][mi][ni][r]+bo;
        float uv=acc[2][mi][ni][r]+bu;
        float cn=sigm(iv)*ftanh(uv);
        if(internal) cn+=csum[(size_t)mm*HD+col];
        float hn=sigm(ov)*ftanh(cn);
        const int tt=mm>>shift, jj=mm-(tt<<shift);
        const size_t nd=((size_t)tt*NPT+start_n+jj)*HD+col;
        cbuf[nd]=cn;
        h16[nd]=(f16)hn;
      }
    }
  }
}

// ================= XWf: pipelined 128x128 (NT=12, f16), 1D grid =================
__global__ __launch_bounds__(256,2)
void k_xwf128p(const f16* __restrict__ fx,
               const f16* __restrict__ Wfc, float* __restrict__ XWf, int Mtot)
{
  extern __shared__ char sm[];     // A: 2x16384, B: 2x16384
  char* Abase=sm;
  char* Bbase=sm+32768;
  const int tid=threadIdx.x;
  const int w=tid>>6, lane=tid&63;
  int xb, my;
  xcd_map(blockIdx.x, gridDim.x, 4, xb, my);
  const int m0=my*128, n0=xb*128;
  const int NT=12;

  unsigned fofs[4];
  #pragma unroll
  for(int i=0;i<4;++i){
    int r=w*32+i*8+(lane>>3);
    int m=m0+r; if(m>=Mtot) m=Mtot-1;
    int t=m/NINT; int j=1024+(m-t*NINT);
    fofs[i]=(unsigned)(((size_t)t*NPT+j)*768);
  }
  unsigned bofs[4];
  #pragma unroll
  for(int i=0;i<4;++i){
    int r=n0+w*32+i*8+(lane>>3);
    bofs[i]=(unsigned)r*768u;
  }
  const unsigned swz=8u*((unsigned)(lane&7)^(unsigned)(lane>>3));

  f32x4 acc[4][4];
  #pragma unroll
  for(int mi=0;mi<4;++mi)
    #pragma unroll
    for(int ni=0;ni<4;++ni) acc[mi][ni]=(f32x4){0.f,0.f,0.f,0.f};

  const int wr=(w>>1)*64, wc=(w&1)*64;
  const int lr=lane&15, lg=lane>>4;

  auto STAGE=[&](int buf, int t){
    const unsigned ak=(unsigned)t*64u, bk=(unsigned)t*64u;
    char* Ad=Abase+(size_t)buf*16384;
    #pragma unroll
    for(int i=0;i<4;++i)
      gll16(fx+fofs[i]+ak+swz, Ad+(w*32+i*8)*128);
    char* Bd=Bbase+(size_t)buf*16384;
    #pragma unroll
    for(int i=0;i<4;++i)
      gll16(Wfc+bofs[i]+bk+swz, Bd+(w*32+i*8)*128);
  };

  auto COMPUTE=[&](int cur){
    const char* Ab=Abase+(size_t)cur*16384;
    const char* Bb=Bbase+(size_t)cur*16384;
    #pragma unroll
    for(int ks=0;ks<2;++ks){
      const unsigned cb=((unsigned)(ks*64+lg*16)) ^ ((unsigned)(lr&7)<<4);
      f16x8 av[4], bv[4];
      #pragma unroll
      for(int mi=0;mi<4;++mi)
        av[mi]=*(const f16x8*)(Ab+(unsigned)(wr+mi*16+lr)*128u+cb);
      #pragma unroll
      for(int ni=0;ni<4;++ni)
        bv[ni]=*(const f16x8*)(Bb+(unsigned)((wc+ni*16)+lr)*128u+cb);
      __builtin_amdgcn_s_setprio(1);
      #pragma unroll
      for(int ni=0;ni<4;++ni)
        #pragma unroll
        for(int mi=0;mi<4;++mi)
          acc[mi][ni]=__builtin_amdgcn_mfma_f32_16x16x32_f16(av[mi],bv[ni],acc[mi][ni],0,0,0);
      __builtin_amdgcn_s_setprio(0);
    }
  };

  STAGE(0,0);
  STAGE(1,1);
  asm volatile("s_waitcnt vmcnt(8)" ::: "memory");
  __builtin_amdgcn_s_barrier();
  __builtin_amdgcn_sched_barrier(0);

  for(int t=0;t<NT;++t){
    COMPUTE(t&1);
    if(t+1<NT){
      __builtin_amdgcn_sched_barrier(0);
      __builtin_amdgcn_s_barrier();
      __builtin_amdgcn_sched_barrier(0);
      if(t+2<NT){
        STAGE(t&1, t+2);
        asm volatile("s_waitcnt vmcnt(8)" ::: "memory");
      }else{
        asm volatile("s_waitcnt vmcnt(0)" ::: "memory");
      }
      __builtin_amdgcn_s_barrier();
      __builtin_amdgcn_sched_barrier(0);
    }
  }

  #pragma unroll
  for(int mi=0;mi<4;++mi){
    #pragma unroll
    for(int ni=0;ni<4;++ni){
      const int col=n0+wc+ni*16+lr;
      #pragma unroll
      for(int r=0;r<4;++r){
        const int mm=m0+wr+mi*16+lg*4+r;
        if(mm<Mtot) XWf[(size_t)mm*512+col]=acc[mi][ni][r];
      }
    }
  }
}

// ================= Uh forget-gate: pipelined 128x128 (NT=8, f16) + fused csum/hsum =================
__global__ __launch_bounds__(256,2)
void k_uh128p(const f16* __restrict__ h16,
              const f16* __restrict__ Ufc, const float* __restrict__ bias,
              const float* __restrict__ XWf, const float* __restrict__ cbuf,
              float* __restrict__ csum, f16* __restrict__ hs16,
              int start_ch, int lc, int xwoff)
{
  extern __shared__ char sm[];     // A: 2x16384, B: 2x16384
  char* Abase=sm;
  char* Bbase=sm+32768;
  const int tid=threadIdx.x;
  const int w=tid>>6, lane=tid&63;
  int xb, my;
  xcd_map(blockIdx.x, gridDim.x, 4, xb, my);
  const int e0=my*128, n0=xb*128;
  const int NT=8;

  unsigned hofs[4];
  #pragma unroll
  for(int i=0;i<4;++i){
    int r=w*32+i*8+(lane>>3);
    int e=e0+r;
    int t=e>>lc, ei=e-(t<<lc);
    hofs[i]=(unsigned)(((size_t)t*NPT+start_ch+ei)*HD);
  }
  unsigned bofs[4];
  #pragma unroll
  for(int i=0;i<4;++i){
    int r=n0+w*32+i*8+(lane>>3);
    bofs[i]=(unsigned)r*512u;
  }
  const unsigned swz=8u*((unsigned)(lane&7)^(unsigned)(lane>>3));

  f32x4 acc[4][4];
  #pragma unroll
  for(int mi=0;mi<4;++mi)
    #pragma unroll
    for(int ni=0;ni<4;++ni) acc[mi][ni]=(f32x4){0.f,0.f,0.f,0.f};

  const int wr=(w>>1)*64, wc=(w&1)*64;
  const int lr=lane&15, lg=lane>>4;

  auto STAGE=[&](int buf, int t){
    const unsigned ak=(unsigned)t*64u, bk=(unsigned)t*64u;
    char* Ad=Abase+(size_t)buf*16384;
    #pragma unroll
    for(int i=0;i<4;++i)
      gll16(h16+hofs[i]+ak+swz, Ad+(w*32+i*8)*128);
    char* Bd=Bbase+(size_t)buf*16384;
    #pragma unroll
    for(int i=0;i<4;++i)
      gll16(Ufc+bofs[i]+bk+swz, Bd+(w*32+i*8)*128);
  };

  auto COMPUTE=[&](int cur){
    const char* Ab=Abase+(size_t)cur*16384;
    const char* Bb=Bbase+(size_t)cur*16384;
    #pragma unroll
    for(int ks=0;ks<2;++ks){
      const unsigned cb=((unsigned)(ks*64+lg*16)) ^ ((unsigned)(lr&7)<<4);
      f16x8 av[4], bv[4];
      #pragma unroll
      for(int mi=0;mi<4;++mi)
        av[mi]=*(const f16x8*)(Ab+(unsigned)(wr+mi*16+lr)*128u+cb);
      #pragma unroll
      for(int ni=0;ni<4;++ni)
        bv[ni]=*(const f16x8*)(Bb+(unsigned)((wc+ni*16)+lr)*128u+cb);
      __builtin_amdgcn_s_setprio(1);
      #pragma unroll
      for(int ni=0;ni<4;++ni)
        #pragma unroll
        for(int mi=0;mi<4;++mi)
          acc[mi][ni]=__builtin_amdgcn_mfma_f32_16x16x32_f16(av[mi],bv[ni],acc[mi][ni],0,0,0);
      __builtin_amdgcn_s_setprio(0);
    }
  };

  STAGE(0,0);
  STAGE(1,1);
  asm volatile("s_waitcnt vmcnt(8)" ::: "memory");
  __builtin_amdgcn_s_barrier();
  __builtin_amdgcn_sched_barrier(0);

  for(int t=0;t<NT;++t){
    COMPUTE(t&1);
    if(t+1<NT){
      __builtin_amdgcn_sched_barrier(0);
      __builtin_amdgcn_s_barrier();
      __builtin_amdgcn_sched_barrier(0);
      if(t+2<NT){
        STAGE(t&1, t+2);
        asm volatile("s_waitcnt vmcnt(8)" ::: "memory");
      }else{
        asm volatile("s_waitcnt vmcnt(0)" ::: "memory");
      }
      __builtin_amdgcn_s_barrier();
      __builtin_amdgcn_sched_barrier(0);
    }
  }

  #pragma unroll
  for(int mi=0;mi<4;++mi){
    const int ebase=e0+wr+mi*16+lg*4;
    const int tt=ebase>>lc, eib=ebase-(tt<<lc);
    const int inode=tt*NINT + xwoff + (eib>>2);
    const int par=ebase>>2;
    #pragma unroll
    for(int ni=0;ni<4;++ni){
      const int col=n0+wc+ni*16+lr;
      const float base=bias[col]+XWf[(size_t)inode*512+col];
      const size_t chbase=((size_t)tt*NPT+start_ch+eib)*HD+col;
      float s=0.f, hsv=0.f;
      #pragma unroll
      for(int r=0;r<4;++r){
        const size_t ci=chbase+(size_t)r*HD;
        float fv=sigm(acc[mi][ni][r]+base);
        s+=fv*cbuf[ci];
        hsv+=(float)h16[ci];
      }
      csum[(size_t)par*HD+col]=s;
      hs16[(size_t)par*HD+col]=(f16)hsv;
    }
  }
}

// ---------------- final head ----------------
__global__ __launch_bounds__(256)
void k_final2(const f16* __restrict__ h16,
              const float* __restrict__ Wy, const float* __restrict__ gamma,
              const float* __restrict__ beta, float* __restrict__ out0, int Nn)
{
  const int gtid=blockIdx.x*256+threadIdx.x;
  const int node=gtid>>6, lane=gtid&63;
  if(node>=Nn) return;
  const size_t base=(size_t)node*HD+lane*8;
  f16x8 hv=*(const f16x8*)(h16+base);
  float hf[8];
  #pragma unroll
  for(int e=0;e<8;++e) hf[e]=(float)hv[e];
  float y[4];
  #pragma unroll
  for(int jj=0;jj<4;++jj){
    const float* wp=Wy+jj*HD+lane*8;
    float s=0.f;
    #pragma unroll
    for(int e=0;e<8;++e) s+=hf[e]*wp[e];
    #pragma unroll
    for(int off=32;off>=1;off>>=1) s+=__shfl_xor(s,off,64);
    y[jj]=s;
  }
  if(lane==0){
    float mu=0.25f*(y[0]+y[1]+y[2]+y[3]);
    float var=0.f;
    #pragma unroll
    for(int jj=0;jj<4;++jj){ float d=y[jj]-mu; var+=d*d; }
    var*=0.25f;
    float rs=rsqrtf(var+1e-6f);
    float z[4], zmax=-1e30f;
    #pragma unroll
    for(int jj=0;jj<4;++jj){ z[jj]=(y[jj]-mu)*rs*gamma[jj]+beta[jj]; zmax=fmaxf(zmax,z[jj]); }
    float es=0.f;
    #pragma unroll
    for(int jj=0;jj<4;++jj){ z[jj]=__expf(z[jj]-zmax); es+=z[jj]; }
    float inv=1.f/es;
    #pragma unroll
    for(int jj=0;jj<4;++jj) out0[(size_t)node*4+jj]=z[jj]*inv;
  }
}

// ---------------- root head ----------------
__global__ __launch_bounds__(256)
void k_root(const f16* __restrict__ h16,
            const float* __restrict__ Wff, float* __restrict__ out1)
{
  const int gtid=blockIdx.x*256+threadIdx.x;
  const int tt=gtid>>6, lane=gtid&63;
  if(tt>=64) return;
  const size_t base=((size_t)tt*NPT+1364)*HD+lane*8;
  f16x8 hv=*(const f16x8*)(h16+base);
  float hf[8];
  #pragma unroll
  for(int e=0;e<8;++e) hf[e]=(float)hv[e];
  float y[4];
  #pragma unroll
  for(int jj=0;jj<4;++jj){
    const float* wp=Wff+jj*HD+lane*8;
    float s=0.f;
    #pragma unroll
    for(int e=0;e<8;++e) s+=hf[e]*wp[e];
    #pragma unroll
    for(int off=32;off>=1;off>>=1) s+=__shfl_xor(s,off,64);
    y[jj]=s;
  }
  if(lane==0){
    float zmax=fmaxf(fmaxf(y[0],y[1]),fmaxf(y[2],y[3]));
    float es=0.f, z[4];
    #pragma unroll
    for(int jj=0;jj<4;++jj){ z[jj]=__expf(y[jj]-zmax); es+=z[jj]; }
    float inv=1.f/es;
    #pragma unroll
    for(int jj=0;jj<4;++jj) out1[(size_t)tt*4+jj]=z[jj]*inv;
  }
}

extern "C" void kernel_launch(void* const* d_in, const int* in_sizes, int n_in,
                              void* d_out, int out_size, void* d_ws, size_t ws_size,
                              hipStream_t stream)
{
  const float* features=(const float*)d_in[0];
  const float* W_iou=(const float*)d_in[6];
  const float* b_iou=(const float*)d_in[7];
  const float* U_iou=(const float*)d_in[8];
  const float* W_f  =(const float*)d_in[9];
  const float* b_f  =(const float*)d_in[10];
  const float* U_f  =(const float*)d_in[11];
  const float* W_ff =(const float*)d_in[12];
  const float* W_sd =(const float*)d_in[13];
  const float* W_sd2=(const float*)d_in[14];
  const float* W_sf =(const float*)d_in[15];
  const float* ln_g =(const float*)d_in[16];
  const float* ln_b =(const float*)d_in[17];

  const int N=in_sizes[0]/768;   // 87360
  const int T=N/NPT;             // 64
  const int MINT=T*NINT;         // 21824

  float* out0=(float*)d_out;
  float* out1=out0+(size_t)N*4;
  float* cbuf=out1+(size_t)T*4;  // c output region (live c-state)

  char* p=(char*)d_ws;
  auto alloc=[&](size_t bytes){ char* r=p; p+=((bytes+255)&~(size_t)255); return r; };
  f16*   fx   =(f16*)  alloc((size_t)N*768*2);
  f16*   hs16 =(f16*)  alloc((size_t)16384*HD*2);
  float* csum =(float*)alloc((size_t)16384*HD*4);
  f16*   h16  =(f16*)  alloc((size_t)N*HD*2);
  f16*   WilL =(f16*)  alloc((size_t)1536*768*2);
  f16*   WilI =(f16*)  alloc((size_t)1536*1280*2);
  f16*   Wcat2=(f16*)  alloc((size_t)1536*1280*2);   // level-5 64-tile layout
  f16*   Wfc  =(f16*)  alloc((size_t)512*768*2);
  f16*   Ufc  =(f16*)  alloc((size_t)512*512*2);
  float* Wcomb=(float*)alloc((size_t)512*512*4);
  float* Wy   =(float*)alloc((size_t)4*512*4);
  float* XWf  =(float*)alloc((size_t)MINT*512*4);

  // conversions / weight prep
  { size_t n8=(size_t)N*768/8;    k_cvt16<<<(int)((n8+255)/256),256,0,stream>>>(features,fx,n8); }
  { size_t n=(size_t)1536*768;    k_wil<<<(int)((n+255)/256),256,0,stream>>>(W_iou,U_iou,WilL,0); }
  { size_t n=(size_t)1536*1280;   k_wil<<<(int)((n+255)/256),256,0,stream>>>(W_iou,U_iou,WilI,1); }
  { size_t n=(size_t)1536*1280;   k_concat1280<<<(int)((n+255)/256),256,0,stream>>>(W_iou,U_iou,Wcat2,1536); }
  { size_t n8=(size_t)512*768/8;  k_cvt16<<<(int)((n8+255)/256),256,0,stream>>>(W_f,Wfc,n8); }
  { size_t n8=(size_t)512*512/8;  k_cvt16<<<(int)((n8+255)/256),256,0,stream>>>(U_f,Ufc,n8); }
  { dim3 g(8,8); k_wcomb<<<g,256,0,stream>>>(W_sd2,W_sd,Wcomb); }
  { k_wy<<<8,256,0,stream>>>(W_sf,Wcomb,Wy); }

  // upfront: XWf for all internal nodes (pipelined, 1D grid)
  { int nb=4*((MINT+127)/128);
    k_xwf128p<<<nb,256,G128_LDS,stream>>>(fx,Wfc,XWf,MINT); }

  static const int starts[6]={0,1024,1280,1344,1360,1364};
  static const int csh[6]  ={10,8,6,4,2,0};
  static const int counts[6]={1024,256,64,16,4,1};
  static const int xwoffs[6]={0,0,256,320,336,340};

  // level 0 (leaves): XCD-chunked 1D grid
  { int nb=8*((T*1024)/128);
    k_iou128p<<<nb,256,IOU_LDS,stream>>>(fx,hs16,WilL,b_iou,csum,h16,cbuf,0,10,0); }

  for(int n=1;n<6;++n){
    int P=T*counts[n], E=T*counts[n-1];
    { int nb=4*(E/128);
      k_uh128p<<<nb,256,G128_LDS,stream>>>(h16,Ufc,b_f,XWf,cbuf,csum,hs16,
                                           starts[n-1],csh[n-1],xwoffs[n]); }
    if(P>=128){
      int nb=8*(P/128);
      k_iou128p<<<nb,256,IOU_LDS,stream>>>(fx,hs16,WilI,b_iou,csum,h16,cbuf,starts[n],csh[n],1);
    }else{
      dim3 g(P/64,8);
      k_iou<<<g,256,0,stream>>>(fx,hs16,Wcat2,b_iou,csum,h16,cbuf,starts[n],csh[n],1280,1280,1);
    }
  }

  // heads (stance folded into Wy)
  { int th=N*64; k_final2<<<(th+255)/256,256,0,stream>>>(h16,Wy,ln_g,ln_b,out0,N); }
  { k_root<<<16,256,0,stream>>>(h16,W_ff,out1); }
}

// Round 22
// 807.798 us; speedup vs baseline: 3.0450x; 1.2191x over previous
//
#include <hip/hip_runtime.h>
#include <hip/hip_bf16.h>
#include <math.h>

typedef _Float16 f16;
typedef f16 f16x8 __attribute__((ext_vector_type(8)));
typedef float f32x4 __attribute__((ext_vector_type(4)));

#define NPT 1365
#define HD 512
#define NINT 341   // internal nodes per tree (256+64+16+4+1)
#define IOU_LDS (2*128*64*2 + 2*192*64*2)   // 81920 B -> 2 blocks/CU
#define G128_LDS (2*128*64*2 + 2*128*64*2)  // 65536 B -> 2 blocks/CU

__device__ __forceinline__ float frcp(float x){ return __builtin_amdgcn_rcpf(x); }
__device__ __forceinline__ float sigm(float x){ return frcp(1.0f+__expf(-x)); }
__device__ __forceinline__ float ftanh(float x){
  float e=__expf(2.f*fabsf(x));
  float t=1.f-2.f*frcp(e+1.f);
  return copysignf(t,x);
}

__device__ __forceinline__ void gll16(const void* g, void* l){
  __builtin_amdgcn_global_load_lds((const __attribute__((address_space(1))) void*)g,
                                   (__attribute__((address_space(3))) void*)l, 16, 0, 0);
}

// XCD-chunked bijection: phys%8 = XCD; each XCD gets a contiguous y-range with all x.
__device__ __forceinline__ void xcd_map(int phys, int nb, int xdim, int& x, int& my){
  int ytiles = nb / xdim;
  if((ytiles & 7)==0){
    int k = phys & 7, i = phys >> 3;
    my = k * (ytiles >> 3) + i / xdim;
    x  = i % xdim;
  }else{
    x  = phys % xdim;
    my = phys / xdim;
  }
}

// ---------------- fp32 -> f16 cast, 8 elems/thread ----------------
__global__ void k_cvt16(const float* __restrict__ s, f16* __restrict__ d, size_t n8){
  size_t i=(size_t)blockIdx.x*blockDim.x+threadIdx.x;
  if(i>=n8) return;
  const float4* sp=(const float4*)(s+i*8);
  float4 a=sp[0], b=sp[1];
  float v[8]={a.x,a.y,a.z,a.w,b.x,b.y,b.z,b.w};
  f16x8 h;
  #pragma unroll
  for(int e=0;e<8;++e) h[e]=(f16)v[e];
  *(f16x8*)(d+i*8)=h;
}

// ---------------- gate-interleaved iou weights (f16) ----------------
// leaf   (K=768):  [W]      ; intern (K=1280): [W(768)|U(512)]
__global__ void k_wil(const float* __restrict__ W, const float* __restrict__ U,
                      f16* __restrict__ d, int internal){
  const int K = internal? 1280 : 768;
  size_t i=(size_t)blockIdx.x*blockDim.x+threadIdx.x;
  size_t tot=(size_t)1536*K;
  if(i>=tot) return;
  int rp=(int)(i/K); int k=(int)(i-(size_t)rp*K);
  int f=rp>>4, rr=rp&15;
  int g=f%3, cgrp=f/3;
  int orig=g*512+cgrp*16+rr;
  float v;
  if(internal) v = (k<768)? W[(size_t)orig*768+k] : U[(size_t)orig*512+(k-768)];
  else         v = W[(size_t)orig*768+k];
  d[i]=(f16)v;
}

// ---------------- gate-major concat K=1280 (level-5 64-tile iou), f16 ----------------
__global__ void k_concat1280(const float* __restrict__ W, const float* __restrict__ U,
                             f16* __restrict__ d, int rows){
  size_t i=(size_t)blockIdx.x*blockDim.x+threadIdx.x;
  const int K=1280;
  size_t tot=(size_t)rows*K;
  if(i>=tot) return;
  int r=(int)(i/K); int k=(int)(i-(size_t)r*K);
  float v = (k<768)? W[(size_t)r*768+k] : U[(size_t)r*512+(k-768)];
  d[i]=(f16)v;
}

// ---------------- tmp[j][e] = sum_d Wsf[j][d] * W_sd2[d][e]  (4 x 1024, fp32) ----------------
__global__ void k_tmp4(const float* __restrict__ Wsf, const float* __restrict__ Wsd2,
                       float* __restrict__ tmp){
  int idx=blockIdx.x*256+threadIdx.x;
  if(idx>=4096) return;
  int j=idx>>10, e=idx&1023;
  float s=0.f;
  #pragma unroll 8
  for(int d=0;d<512;++d) s+=Wsf[j*512+d]*Wsd2[(size_t)d*1024+e];
  tmp[(size_t)j*1024+e]=s;
}

// ---------------- Wy[j][c] = Wsf[j][c] + sum_e tmp[j][e] * W_sd[e][c]  (4 x 512) ----------------
__global__ void k_wy2(const float* __restrict__ Wsf, const float* __restrict__ tmp,
                      const float* __restrict__ Wsd, float* __restrict__ Wy){
  int idx=blockIdx.x*256+threadIdx.x;
  if(idx>=2048) return;
  int j=idx>>9, c=idx&511;
  float s=Wsf[j*512+c];
  #pragma unroll 8
  for(int e=0;e<1024;++e) s+=tmp[j*1024+e]*Wsd[(size_t)e*512+c];
  Wy[(size_t)j*512+c]=s;
}

// ================= iou GEMM: 128 x 192, f16, dbuf + counted vmcnt + setprio, XCD-chunked =================
__global__ __launch_bounds__(256,2)
void k_iou128p(const f16* __restrict__ fx, const f16* __restrict__ hs16,
               const f16* __restrict__ Wil, const float* __restrict__ bias,
               const float* __restrict__ csum, f16* __restrict__ h16,
               float* __restrict__ cbuf,
               int start_n, int shift, int internal)
{
  extern __shared__ char sm[];                 // A: 2x16384, B: 2x24576
  char* Abase=sm;
  char* Bbase=sm+32768;
  const int tid=threadIdx.x;
  const int w=tid>>6, lane=tid&63;
  int x, my;
  xcd_map(blockIdx.x, gridDim.x, 8, x, my);
  const int m0=my*128;
  const int K = internal? 1280 : 768;
  const int NT = K>>6;

  unsigned fofs[4], hofs[4];
  #pragma unroll
  for(int i=0;i<4;++i){
    int r=w*32+i*8+(lane>>3);
    int m=m0+r;
    int t_=m>>shift, j=m-(t_<<shift);
    fofs[i]=(unsigned)(((size_t)t_*NPT+start_n+j)*768);
    hofs[i]=(unsigned)m*512u;
  }
  unsigned bofs[6];
  #pragma unroll
  for(int i=0;i<6;++i){
    int r=x*192+w*48+i*8+(lane>>3);
    bofs[i]=(unsigned)r*(unsigned)K;
  }
  const unsigned swz=8u*((unsigned)(lane&7)^(unsigned)(lane>>3));

  f32x4 acc[4][6];
  #pragma unroll
  for(int mi=0;mi<4;++mi)
    #pragma unroll
    for(int ni=0;ni<6;++ni) acc[mi][ni]=(f32x4){0.f,0.f,0.f,0.f};

  const int wr=(w>>1)*64;
  const int wcF=(w&1)*6;
  const int lr=lane&15, lg=lane>>4;

  auto STAGE=[&](int buf, int t){
    const f16* base; int kt; bool useF;
    if(internal){
      if(t<12){ base=fx;   kt=t;    useF=true;  }
      else    { base=hs16; kt=t-12; useF=false; }
    }else{
      base=fx; kt=t; useF=true;
    }
    const unsigned kofs=(unsigned)kt*64u+swz;
    char* Ad=Abase+(size_t)buf*16384;
    #pragma unroll
    for(int i=0;i<4;++i){
      const f16* g=base+(useF?fofs[i]:hofs[i])+kofs;
      gll16(g, Ad+(w*32+i*8)*128);
    }
    const unsigned bk=(unsigned)t*64u+swz;
    char* Bd=Bbase+(size_t)buf*24576;
    #pragma unroll
    for(int i=0;i<6;++i){
      gll16(Wil+bofs[i]+bk, Bd+(w*48+i*8)*128);
    }
  };

  auto COMPUTE=[&](int cur){
    const char* Ab=Abase+(size_t)cur*16384;
    const char* Bb=Bbase+(size_t)cur*24576;
    #pragma unroll
    for(int ks=0;ks<2;++ks){
      const unsigned cb=((unsigned)(ks*64+lg*16)) ^ ((unsigned)(lr&7)<<4);
      f16x8 av[4], bv[6];
      #pragma unroll
      for(int mi=0;mi<4;++mi)
        av[mi]=*(const f16x8*)(Ab+(unsigned)(wr+mi*16+lr)*128u+cb);
      #pragma unroll
      for(int ni=0;ni<6;++ni)
        bv[ni]=*(const f16x8*)(Bb+(unsigned)((wcF+ni)*16+lr)*128u+cb);
      __builtin_amdgcn_s_setprio(1);
      #pragma unroll
      for(int ni=0;ni<6;++ni)
        #pragma unroll
        for(int mi=0;mi<4;++mi)
          acc[mi][ni]=__builtin_amdgcn_mfma_f32_16x16x32_f16(av[mi],bv[ni],acc[mi][ni],0,0,0);
      __builtin_amdgcn_s_setprio(0);
    }
  };

  STAGE(0,0);
  STAGE(1,1);
  asm volatile("s_waitcnt vmcnt(10)" ::: "memory");
  __builtin_amdgcn_s_barrier();
  __builtin_amdgcn_sched_barrier(0);

  for(int t=0;t<NT;++t){
    COMPUTE(t&1);
    if(t+1<NT){
      __builtin_amdgcn_sched_barrier(0);
      __builtin_amdgcn_s_barrier();
      __builtin_amdgcn_sched_barrier(0);
      if(t+2<NT){
        STAGE(t&1, t+2);
        asm volatile("s_waitcnt vmcnt(10)" ::: "memory");
      }else{
        asm volatile("s_waitcnt vmcnt(0)" ::: "memory");
      }
      __builtin_amdgcn_s_barrier();
      __builtin_amdgcn_sched_barrier(0);
    }
  }

  #pragma unroll
  for(int mi=0;mi<4;++mi){
    #pragma unroll
    for(int cg=0;cg<2;++cg){
      const int col = x*64 + ((w&1)*2+cg)*16 + lr;
      const float bi=bias[col], bo=bias[col+512], bu=bias[col+1024];
      #pragma unroll
      for(int r=0;r<4;++r){
        const int mm=m0+wr+mi*16+lg*4+r;
        float iv=acc[mi][3*cg+0][r]+bi;
        float ov=acc[mi][3*cg+1][r]+bo;
        float uv=acc[mi][3*cg+2][r]+bu;
        float cn=sigm(iv)*ftanh(uv);
        if(internal) cn+=csum[(size_t)mm*HD+col];
        float hn=sigm(ov)*ftanh(cn);
        const int tt=mm>>shift, jj=mm-(tt<<shift);
        const size_t nd=((size_t)tt*NPT+start_n+jj)*HD+col;
        cbuf[nd]=cn;
        h16[nd]=(f16)hn;
      }
    }
  }
}

// ---------------- old 64-tile iou (level 5 only, P=64; K=1280 gate-major layout, f16) ----------------
__global__ __launch_bounds__(256)
void k_iou(const f16* __restrict__ fx, const f16* __restrict__ hs16,
           const f16* __restrict__ Wcat, const float* __restrict__ bias,
           const float* __restrict__ csum, f16* __restrict__ h16,
           float* __restrict__ cbuf,
           int start_n, int shift, int K, int KB, int internal)
{
  __shared__ f16 As[64][40];
  __shared__ f16 Bs[3][64][40];
  const int tid=threadIdx.x;
  const int m0=blockIdx.x*64, n0=blockIdx.y*64;
  const int srow=tid>>2, skc=(tid&3)*8;
  const int m=m0+srow;
  const int t=m>>shift, j=m-(t<<shift);
  const size_t frow=((size_t)t*NPT+start_n+j)*768;
  const f16* aF=fx+frow;
  const f16* aH=hs16+(size_t)m*HD;
  const f16* bp0=Wcat+(size_t)(n0+srow)*KB;
  const f16* bp1=Wcat+(size_t)(512+n0+srow)*KB;
  const f16* bp2=Wcat+(size_t)(1024+n0+srow)*KB;

  f32x4 acc[3][2][2];
  #pragma unroll
  for(int g=0;g<3;++g)
    #pragma unroll
    for(int mi=0;mi<2;++mi)
      #pragma unroll
      for(int ni=0;ni<2;++ni) acc[g][mi][ni]=(f32x4){0.f,0.f,0.f,0.f};

  const int w=tid>>6, lane=tid&63;
  const int wr=(w>>1)*32, wc=(w&1)*32;
  const int lr=lane&15, lg=lane>>4;

  for(int k0=0;k0<K;k0+=32){
    const f16* ap = (k0<768)? (aF+k0) : (aH+(k0-768));
    *(f16x8*)&As[srow][skc]=*(const f16x8*)(ap+skc);
    *(f16x8*)&Bs[0][srow][skc]=*(const f16x8*)(bp0+k0+skc);
    *(f16x8*)&Bs[1][srow][skc]=*(const f16x8*)(bp1+k0+skc);
    *(f16x8*)&Bs[2][srow][skc]=*(const f16x8*)(bp2+k0+skc);
    __syncthreads();
    f16x8 a0=*(f16x8*)&As[wr+lr][lg*8];
    f16x8 a1=*(f16x8*)&As[wr+16+lr][lg*8];
    #pragma unroll
    for(int g=0;g<3;++g){
      #pragma unroll
      for(int ni=0;ni<2;++ni){
        f16x8 bv=*(f16x8*)&Bs[g][wc+ni*16+lr][lg*8];
        acc[g][0][ni]=__builtin_amdgcn_mfma_f32_16x16x32_f16(a0,bv,acc[g][0][ni],0,0,0);
        acc[g][1][ni]=__builtin_amdgcn_mfma_f32_16x16x32_f16(a1,bv,acc[g][1][ni],0,0,0);
      }
    }
    __syncthreads();
  }

  #pragma unroll
  for(int mi=0;mi<2;++mi){
    #pragma unroll
    for(int ni=0;ni<2;++ni){
      const int col=n0+wc+ni*16+lr;
      const float bi=bias[col], bo=bias[col+512], bu=bias[col+1024];
      #pragma unroll
      for(int r=0;r<4;++r){
        const int mm=m0+wr+mi*16+lg*4+r;
        float iv=acc[0][mi][ni][r]+bi;
        float ov=acc[1][mi][ni][r]+bo;
        float uv=acc[2][mi][ni][r]+bu;
        float cn=sigm(iv)*ftanh(uv);
        if(internal) cn+=csum[(size_t)mm*HD+col];
        float hn=sigm(ov)*ftanh(cn);
        const int tt=mm>>shift, jj=mm-(tt<<shift);
        const size_t nd=((size_t)tt*NPT+start_n+jj)*HD+col;
        cbuf[nd]=cn;
        h16[nd]=(f16)hn;
      }
    }
  }
}

// ================= XWf: pipelined 128x128 (NT=12, f16), 1D grid =================
__global__ __launch_bounds__(256,2)
void k_xwf128p(const f16* __restrict__ fx,
               const f16* __restrict__ Wfc, float* __restrict__ XWf, int Mtot)
{
  extern __shared__ char sm[];     // A: 2x16384, B: 2x16384
  char* Abase=sm;
  char* Bbase=sm+32768;
  const int tid=threadIdx.x;
  const int w=tid>>6, lane=tid&63;
  int xb, my;
  xcd_map(blockIdx.x, gridDim.x, 4, xb, my);
  const int m0=my*128, n0=xb*128;
  const int NT=12;

  unsigned fofs[4];
  #pragma unroll
  for(int i=0;i<4;++i){
    int r=w*32+i*8+(lane>>3);
    int m=m0+r; if(m>=Mtot) m=Mtot-1;
    int t=m/NINT; int j=1024+(m-t*NINT);
    fofs[i]=(unsigned)(((size_t)t*NPT+j)*768);
  }
  unsigned bofs[4];
  #pragma unroll
  for(int i=0;i<4;++i){
    int r=n0+w*32+i*8+(lane>>3);
    bofs[i]=(unsigned)r*768u;
  }
  const unsigned swz=8u*((unsigned)(lane&7)^(unsigned)(lane>>3));

  f32x4 acc[4][4];
  #pragma unroll
  for(int mi=0;mi<4;++mi)
    #pragma unroll
    for(int ni=0;ni<4;++ni) acc[mi][ni]=(f32x4){0.f,0.f,0.f,0.f};

  const int wr=(w>>1)*64, wc=(w&1)*64;
  const int lr=lane&15, lg=lane>>4;

  auto STAGE=[&](int buf, int t){
    const unsigned ak=(unsigned)t*64u, bk=(unsigned)t*64u;
    char* Ad=Abase+(size_t)buf*16384;
    #pragma unroll
    for(int i=0;i<4;++i)
      gll16(fx+fofs[i]+ak+swz, Ad+(w*32+i*8)*128);
    char* Bd=Bbase+(size_t)buf*16384;
    #pragma unroll
    for(int i=0;i<4;++i)
      gll16(Wfc+bofs[i]+bk+swz, Bd+(w*32+i*8)*128);
  };

  auto COMPUTE=[&](int cur){
    const char* Ab=Abase+(size_t)cur*16384;
    const char* Bb=Bbase+(size_t)cur*16384;
    #pragma unroll
    for(int ks=0;ks<2;++ks){
      const unsigned cb=((unsigned)(ks*64+lg*16)) ^ ((unsigned)(lr&7)<<4);
      f16x8 av[4], bv[4];
      #pragma unroll
      for(int mi=0;mi<4;++mi)
        av[mi]=*(const f16x8*)(Ab+(unsigned)(wr+mi*16+lr)*128u+cb);
      #pragma unroll
      for(int ni=0;ni<4;++ni)
        bv[ni]=*(const f16x8*)(Bb+(unsigned)((wc+ni*16)+lr)*128u+cb);
      __builtin_amdgcn_s_setprio(1);
      #pragma unroll
      for(int ni=0;ni<4;++ni)
        #pragma unroll
        for(int mi=0;mi<4;++mi)
          acc[mi][ni]=__builtin_amdgcn_mfma_f32_16x16x32_f16(av[mi],bv[ni],acc[mi][ni],0,0,0);
      __builtin_amdgcn_s_setprio(0);
    }
  };

  STAGE(0,0);
  STAGE(1,1);
  asm volatile("s_waitcnt vmcnt(8)" ::: "memory");
  __builtin_amdgcn_s_barrier();
  __builtin_amdgcn_sched_barrier(0);

  for(int t=0;t<NT;++t){
    COMPUTE(t&1);
    if(t+1<NT){
      __builtin_amdgcn_sched_barrier(0);
      __builtin_amdgcn_s_barrier();
      __builtin_amdgcn_sched_barrier(0);
      if(t+2<NT){
        STAGE(t&1, t+2);
        asm volatile("s_waitcnt vmcnt(8)" ::: "memory");
      }else{
        asm volatile("s_waitcnt vmcnt(0)" ::: "memory");
      }
      __builtin_amdgcn_s_barrier();
      __builtin_amdgcn_sched_barrier(0);
    }
  }

  #pragma unroll
  for(int mi=0;mi<4;++mi){
    #pragma unroll
    for(int ni=0;ni<4;++ni){
      const int col=n0+wc+ni*16+lr;
      #pragma unroll
      for(int r=0;r<4;++r){
        const int mm=m0+wr+mi*16+lg*4+r;
        if(mm<Mtot) XWf[(size_t)mm*512+col]=acc[mi][ni][r];
      }
    }
  }
}

// ================= Uh forget-gate: pipelined 128x128 (NT=8, f16) + fused csum/hsum =================
__global__ __launch_bounds__(256,2)
void k_uh128p(const f16* __restrict__ h16,
              const f16* __restrict__ Ufc, const float* __restrict__ bias,
              const float* __restrict__ XWf, const float* __restrict__ cbuf,
              float* __restrict__ csum, f16* __restrict__ hs16,
              int start_ch, int lc, int xwoff)
{
  extern __shared__ char sm[];     // A: 2x16384, B: 2x16384
  char* Abase=sm;
  char* Bbase=sm+32768;
  const int tid=threadIdx.x;
  const int w=tid>>6, lane=tid&63;
  int xb, my;
  xcd_map(blockIdx.x, gridDim.x, 4, xb, my);
  const int e0=my*128, n0=xb*128;
  const int NT=8;

  unsigned hofs[4];
  #pragma unroll
  for(int i=0;i<4;++i){
    int r=w*32+i*8+(lane>>3);
    int e=e0+r;
    int t=e>>lc, ei=e-(t<<lc);
    hofs[i]=(unsigned)(((size_t)t*NPT+start_ch+ei)*HD);
  }
  unsigned bofs[4];
  #pragma unroll
  for(int i=0;i<4;++i){
    int r=n0+w*32+i*8+(lane>>3);
    bofs[i]=(unsigned)r*512u;
  }
  const unsigned swz=8u*((unsigned)(lane&7)^(unsigned)(lane>>3));

  f32x4 acc[4][4];
  #pragma unroll
  for(int mi=0;mi<4;++mi)
    #pragma unroll
    for(int ni=0;ni<4;++ni) acc[mi][ni]=(f32x4){0.f,0.f,0.f,0.f};

  const int wr=(w>>1)*64, wc=(w&1)*64;
  const int lr=lane&15, lg=lane>>4;

  auto STAGE=[&](int buf, int t){
    const unsigned ak=(unsigned)t*64u, bk=(unsigned)t*64u;
    char* Ad=Abase+(size_t)buf*16384;
    #pragma unroll
    for(int i=0;i<4;++i)
      gll16(h16+hofs[i]+ak+swz, Ad+(w*32+i*8)*128);
    char* Bd=Bbase+(size_t)buf*16384;
    #pragma unroll
    for(int i=0;i<4;++i)
      gll16(Ufc+bofs[i]+bk+swz, Bd+(w*32+i*8)*128);
  };

  auto COMPUTE=[&](int cur){
    const char* Ab=Abase+(size_t)cur*16384;
    const char* Bb=Bbase+(size_t)cur*16384;
    #pragma unroll
    for(int ks=0;ks<2;++ks){
      const unsigned cb=((unsigned)(ks*64+lg*16)) ^ ((unsigned)(lr&7)<<4);
      f16x8 av[4], bv[4];
      #pragma unroll
      for(int mi=0;mi<4;++mi)
        av[mi]=*(const f16x8*)(Ab+(unsigned)(wr+mi*16+lr)*128u+cb);
      #pragma unroll
      for(int ni=0;ni<4;++ni)
        bv[ni]=*(const f16x8*)(Bb+(unsigned)((wc+ni*16)+lr)*128u+cb);
      __builtin_amdgcn_s_setprio(1);
      #pragma unroll
      for(int ni=0;ni<4;++ni)
        #pragma unroll
        for(int mi=0;mi<4;++mi)
          acc[mi][ni]=__builtin_amdgcn_mfma_f32_16x16x32_f16(av[mi],bv[ni],acc[mi][ni],0,0,0);
      __builtin_amdgcn_s_setprio(0);
    }
  };

  STAGE(0,0);
  STAGE(1,1);
  asm volatile("s_waitcnt vmcnt(8)" ::: "memory");
  __builtin_amdgcn_s_barrier();
  __builtin_amdgcn_sched_barrier(0);

  for(int t=0;t<NT;++t){
    COMPUTE(t&1);
    if(t+1<NT){
      __builtin_amdgcn_sched_barrier(0);
      __builtin_amdgcn_s_barrier();
      __builtin_amdgcn_sched_barrier(0);
      if(t+2<NT){
        STAGE(t&1, t+2);
        asm volatile("s_waitcnt vmcnt(8)" ::: "memory");
      }else{
        asm volatile("s_waitcnt vmcnt(0)" ::: "memory");
      }
      __builtin_amdgcn_s_barrier();
      __builtin_amdgcn_sched_barrier(0);
    }
  }

  #pragma unroll
  for(int mi=0;mi<4;++mi){
    const int ebase=e0+wr+mi*16+lg*4;
    const int tt=ebase>>lc, eib=ebase-(tt<<lc);
    const int inode=tt*NINT + xwoff + (eib>>2);
    const int par=ebase>>2;
    #pragma unroll
    for(int ni=0;ni<4;++ni){
      const int col=n0+wc+ni*16+lr;
      const float base=bias[col]+XWf[(size_t)inode*512+col];
      const size_t chbase=((size_t)tt*NPT+start_ch+eib)*HD+col;
      float s=0.f, hsv=0.f;
      #pragma unroll
      for(int r=0;r<4;++r){
        const size_t ci=chbase+(size_t)r*HD;
        float fv=sigm(acc[mi][ni][r]+base);
        s+=fv*cbuf[ci];
        hsv+=(float)h16[ci];
      }
      csum[(size_t)par*HD+col]=s;
      hs16[(size_t)par*HD+col]=(f16)hsv;
    }
  }
}

// ---------------- final head ----------------
__global__ __launch_bounds__(256)
void k_final2(const f16* __restrict__ h16,
              const float* __restrict__ Wy, const float* __restrict__ gamma,
              const float* __restrict__ beta, float* __restrict__ out0, int Nn)
{
  const int gtid=blockIdx.x*256+threadIdx.x;
  const int node=gtid>>6, lane=gtid&63;
  if(node>=Nn) return;
  const size_t base=(size_t)node*HD+lane*8;
  f16x8 hv=*(const f16x8*)(h16+base);
  float hf[8];
  #pragma unroll
  for(int e=0;e<8;++e) hf[e]=(float)hv[e];
  float y[4];
  #pragma unroll
  for(int jj=0;jj<4;++jj){
    const float* wp=Wy+jj*HD+lane*8;
    float s=0.f;
    #pragma unroll
    for(int e=0;e<8;++e) s+=hf[e]*wp[e];
    #pragma unroll
    for(int off=32;off>=1;off>>=1) s+=__shfl_xor(s,off,64);
    y[jj]=s;
  }
  if(lane==0){
    float mu=0.25f*(y[0]+y[1]+y[2]+y[3]);
    float var=0.f;
    #pragma unroll
    for(int jj=0;jj<4;++jj){ float d=y[jj]-mu; var+=d*d; }
    var*=0.25f;
    float rs=rsqrtf(var+1e-6f);
    float z[4], zmax=-1e30f;
    #pragma unroll
    for(int jj=0;jj<4;++jj){ z[jj]=(y[jj]-mu)*rs*gamma[jj]+beta[jj]; zmax=fmaxf(zmax,z[jj]); }
    float es=0.f;
    #pragma unroll
    for(int jj=0;jj<4;++jj){ z[jj]=__expf(z[jj]-zmax); es+=z[jj]; }
    float inv=1.f/es;
    #pragma unroll
    for(int jj=0;jj<4;++jj) out0[(size_t)node*4+jj]=z[jj]*inv;
  }
}

// ---------------- root head ----------------
__global__ __launch_bounds__(256)
void k_root(const f16* __restrict__ h16,
            const float* __restrict__ Wff, float* __restrict__ out1)
{
  const int gtid=blockIdx.x*256+threadIdx.x;
  const int tt=gtid>>6, lane=gtid&63;
  if(tt>=64) return;
  const size_t base=((size_t)tt*NPT+1364)*HD+lane*8;
  f16x8 hv=*(const f16x8*)(h16+base);
  float hf[8];
  #pragma unroll
  for(int e=0;e<8;++e) hf[e]=(float)hv[e];
  float y[4];
  #pragma unroll
  for(int jj=0;jj<4;++jj){
    const float* wp=Wff+jj*HD+lane*8;
    float s=0.f;
    #pragma unroll
    for(int e=0;e<8;++e) s+=hf[e]*wp[e];
    #pragma unroll
    for(int off=32;off>=1;off>>=1) s+=__shfl_xor(s,off,64);
    y[jj]=s;
  }
  if(lane==0){
    float zmax=fmaxf(fmaxf(y[0],y[1]),fmaxf(y[2],y[3]));
    float es=0.f, z[4];
    #pragma unroll
    for(int jj=0;jj<4;++jj){ z[jj]=__expf(y[jj]-zmax); es+=z[jj]; }
    float inv=1.f/es;
    #pragma unroll
    for(int jj=0;jj<4;++jj) out1[(size_t)tt*4+jj]=z[jj]*inv;
  }
}

extern "C" void kernel_launch(void* const* d_in, const int* in_sizes, int n_in,
                              void* d_out, int out_size, void* d_ws, size_t ws_size,
                              hipStream_t stream)
{
  const float* features=(const float*)d_in[0];
  const float* W_iou=(const float*)d_in[6];
  const float* b_iou=(const float*)d_in[7];
  const float* U_iou=(const float*)d_in[8];
  const float* W_f  =(const float*)d_in[9];
  const float* b_f  =(const float*)d_in[10];
  const float* U_f  =(const float*)d_in[11];
  const float* W_ff =(const float*)d_in[12];
  const float* W_sd =(const float*)d_in[13];
  const float* W_sd2=(const float*)d_in[14];
  const float* W_sf =(const float*)d_in[15];
  const float* ln_g =(const float*)d_in[16];
  const float* ln_b =(const float*)d_in[17];

  const int N=in_sizes[0]/768;   // 87360
  const int T=N/NPT;             // 64
  const int MINT=T*NINT;         // 21824

  float* out0=(float*)d_out;
  float* out1=out0+(size_t)N*4;
  float* cbuf=out1+(size_t)T*4;  // c output region (live c-state)

  char* p=(char*)d_ws;
  auto alloc=[&](size_t bytes){ char* r=p; p+=((bytes+255)&~(size_t)255); return r; };
  f16*   fx   =(f16*)  alloc((size_t)N*768*2);
  f16*   hs16 =(f16*)  alloc((size_t)16384*HD*2);
  float* csum =(float*)alloc((size_t)16384*HD*4);
  f16*   h16  =(f16*)  alloc((size_t)N*HD*2);
  f16*   WilL =(f16*)  alloc((size_t)1536*768*2);
  f16*   WilI =(f16*)  alloc((size_t)1536*1280*2);
  f16*   Wcat2=(f16*)  alloc((size_t)1536*1280*2);   // level-5 64-tile layout
  f16*   Wfc  =(f16*)  alloc((size_t)512*768*2);
  f16*   Ufc  =(f16*)  alloc((size_t)512*512*2);
  float* tmp4 =(float*)alloc((size_t)4*1024*4);
  float* Wy   =(float*)alloc((size_t)4*512*4);
  float* XWf  =(float*)alloc((size_t)MINT*512*4);

  // conversions / weight prep
  { size_t n8=(size_t)N*768/8;    k_cvt16<<<(int)((n8+255)/256),256,0,stream>>>(features,fx,n8); }
  { size_t n=(size_t)1536*768;    k_wil<<<(int)((n+255)/256),256,0,stream>>>(W_iou,U_iou,WilL,0); }
  { size_t n=(size_t)1536*1280;   k_wil<<<(int)((n+255)/256),256,0,stream>>>(W_iou,U_iou,WilI,1); }
  { size_t n=(size_t)1536*1280;   k_concat1280<<<(int)((n+255)/256),256,0,stream>>>(W_iou,U_iou,Wcat2,1536); }
  { size_t n8=(size_t)512*768/8;  k_cvt16<<<(int)((n8+255)/256),256,0,stream>>>(W_f,Wfc,n8); }
  { size_t n8=(size_t)512*512/8;  k_cvt16<<<(int)((n8+255)/256),256,0,stream>>>(U_f,Ufc,n8); }
  { k_tmp4<<<16,256,0,stream>>>(W_sf,W_sd2,tmp4); }
  { k_wy2<<<8,256,0,stream>>>(W_sf,tmp4,W_sd,Wy); }

  // upfront: XWf for all internal nodes (pipelined, 1D grid)
  { int nb=4*((MINT+127)/128);
    k_xwf128p<<<nb,256,G128_LDS,stream>>>(fx,Wfc,XWf,MINT); }

  static const int starts[6]={0,1024,1280,1344,1360,1364};
  static const int csh[6]  ={10,8,6,4,2,0};
  static const int counts[6]={1024,256,64,16,4,1};
  static const int xwoffs[6]={0,0,256,320,336,340};

  // level 0 (leaves): XCD-chunked 1D grid
  { int nb=8*((T*1024)/128);
    k_iou128p<<<nb,256,IOU_LDS,stream>>>(fx,hs16,WilL,b_iou,csum,h16,cbuf,0,10,0); }

  for(int n=1;n<6;++n){
    int P=T*counts[n], E=T*counts[n-1];
    { int nb=4*(E/128);
      k_uh128p<<<nb,256,G128_LDS,stream>>>(h16,Ufc,b_f,XWf,cbuf,csum,hs16,
                                           starts[n-1],csh[n-1],xwoffs[n]); }
    if(P>=128){
      int nb=8*(P/128);
      k_iou128p<<<nb,256,IOU_LDS,stream>>>(fx,hs16,WilI,b_iou,csum,h16,cbuf,starts[n],csh[n],1);
    }else{
      dim3 g(P/64,8);
      k_iou<<<g,256,0,stream>>>(fx,hs16,Wcat2,b_iou,csum,h16,cbuf,starts[n],csh[n],1280,1280,1);
    }
  }

  // heads (stance folded into Wy)
  { int th=N*64; k_final2<<<(th+255)/256,256,0,stream>>>(h16,Wy,ln_g,ln_b,out0,N); }
  { k_root<<<16,256,0,stream>>>(h16,W_ff,out1); }
}

// Round 23
// 733.056 us; speedup vs baseline: 3.3554x; 1.1020x over previous
//
#include <hip/hip_runtime.h>
#include <hip/hip_bf16.h>
#include <math.h>

typedef _Float16 f16;
typedef f16 f16x8 __attribute__((ext_vector_type(8)));
typedef float f32x4 __attribute__((ext_vector_type(4)));

#define NPT 1365
#define HD 512
#define NINT 341   // internal nodes per tree (256+64+16+4+1)
#define IOU_LDS (2*128*64*2 + 2*192*64*2)   // 81920 B -> 2 blocks/CU
#define G128_LDS (2*128*64*2 + 2*128*64*2)  // 65536 B -> 2 blocks/CU

__device__ __forceinline__ float frcp(float x){ return __builtin_amdgcn_rcpf(x); }
__device__ __forceinline__ float sigm(float x){ return frcp(1.0f+__expf(-x)); }
__device__ __forceinline__ float ftanh(float x){
  float e=__expf(2.f*fabsf(x));
  float t=1.f-2.f*frcp(e+1.f);
  return copysignf(t,x);
}

__device__ __forceinline__ void gll16(const void* g, void* l){
  __builtin_amdgcn_global_load_lds((const __attribute__((address_space(1))) void*)g,
                                   (__attribute__((address_space(3))) void*)l, 16, 0, 0);
}

// XCD-chunked bijection: phys%8 = XCD; each XCD gets a contiguous y-range with all x.
__device__ __forceinline__ void xcd_map(int phys, int nb, int xdim, int& x, int& my){
  int ytiles = nb / xdim;
  if((ytiles & 7)==0){
    int k = phys & 7, i = phys >> 3;
    my = k * (ytiles >> 3) + i / xdim;
    x  = i % xdim;
  }else{
    x  = phys % xdim;
    my = phys / xdim;
  }
}

// ================= fused prep: all elementwise weight/feature conversions =================
// seg0: features->fx (n8 threads, 8 elems each)
// seg1: WilL (leaf gate-interleaved, K=768)
// seg2: WilI (internal gate-interleaved, K=1280)
// seg3: Wcat2 (gate-major K=1280, level-5)
// seg4: W_f->Wfc (8 elems)
// seg5: U_f->Ufc (8 elems)
// seg6: tmp4[j][e] = Wsf[j]·W_sd2[:,e]
__global__ void k_prep(const float* __restrict__ features,
                       const float* __restrict__ W_iou, const float* __restrict__ U_iou,
                       const float* __restrict__ W_f, const float* __restrict__ U_f,
                       const float* __restrict__ Wsf, const float* __restrict__ Wsd2,
                       f16* __restrict__ fx, f16* __restrict__ WilL, f16* __restrict__ WilI,
                       f16* __restrict__ Wcat2, f16* __restrict__ Wfc, f16* __restrict__ Ufc,
                       float* __restrict__ tmp4, size_t nfeat8)
{
  size_t gid=(size_t)blockIdx.x*256+threadIdx.x;
  const size_t n0=nfeat8;
  const size_t n1=n0+(size_t)1536*768;
  const size_t n2=n1+(size_t)1536*1280;
  const size_t n3=n2+(size_t)1536*1280;
  const size_t n4=n3+(size_t)512*768/8;
  const size_t n5=n4+(size_t)512*512/8;
  const size_t n6=n5+4096;
  if(gid<n0){
    size_t i=gid;
    const float4* sp=(const float4*)(features+i*8);
    float4 a=sp[0], b=sp[1];
    float v[8]={a.x,a.y,a.z,a.w,b.x,b.y,b.z,b.w};
    f16x8 h;
    #pragma unroll
    for(int e=0;e<8;++e) h[e]=(f16)v[e];
    *(f16x8*)(fx+i*8)=h;
  }else if(gid<n1){
    size_t i=gid-n0;
    int rp=(int)(i/768); int k=(int)(i-(size_t)rp*768);
    int f=rp>>4, rr=rp&15;
    int orig=(f%3)*512+(f/3)*16+rr;
    WilL[i]=(f16)W_iou[(size_t)orig*768+k];
  }else if(gid<n2){
    size_t i=gid-n1;
    int rp=(int)(i/1280); int k=(int)(i-(size_t)rp*1280);
    int f=rp>>4, rr=rp&15;
    int orig=(f%3)*512+(f/3)*16+rr;
    float v=(k<768)? W_iou[(size_t)orig*768+k] : U_iou[(size_t)orig*512+(k-768)];
    WilI[i]=(f16)v;
  }else if(gid<n3){
    size_t i=gid-n2;
    int r=(int)(i/1280); int k=(int)(i-(size_t)r*1280);
    float v=(k<768)? W_iou[(size_t)r*768+k] : U_iou[(size_t)r*512+(k-768)];
    Wcat2[i]=(f16)v;
  }else if(gid<n4){
    size_t i=gid-n3;
    const float4* sp=(const float4*)(W_f+i*8);
    float4 a=sp[0], b=sp[1];
    float v[8]={a.x,a.y,a.z,a.w,b.x,b.y,b.z,b.w};
    f16x8 h;
    #pragma unroll
    for(int e=0;e<8;++e) h[e]=(f16)v[e];
    *(f16x8*)(Wfc+i*8)=h;
  }else if(gid<n5){
    size_t i=gid-n4;
    const float4* sp=(const float4*)(U_f+i*8);
    float4 a=sp[0], b=sp[1];
    float v[8]={a.x,a.y,a.z,a.w,b.x,b.y,b.z,b.w};
    f16x8 h;
    #pragma unroll
    for(int e=0;e<8;++e) h[e]=(f16)v[e];
    *(f16x8*)(Ufc+i*8)=h;
  }else if(gid<n6){
    int idx=(int)(gid-n5);
    int j=idx>>10, e=idx&1023;
    float s=0.f;
    #pragma unroll 8
    for(int d=0;d<512;++d) s+=Wsf[j*512+d]*Wsd2[(size_t)d*1024+e];
    tmp4[(size_t)j*1024+e]=s;
  }
}

// ---------------- Wy[j][c] = Wsf[j][c] + sum_e tmp[j][e] * W_sd[e][c]  (4 x 512) ----------------
__global__ void k_wy2(const float* __restrict__ Wsf, const float* __restrict__ tmp,
                      const float* __restrict__ Wsd, float* __restrict__ Wy){
  int idx=blockIdx.x*256+threadIdx.x;
  if(idx>=2048) return;
  int j=idx>>9, c=idx&511;
  float s=Wsf[j*512+c];
  #pragma unroll 8
  for(int e=0;e<1024;++e) s+=tmp[j*1024+e]*Wsd[(size_t)e*512+c];
  Wy[(size_t)j*512+c]=s;
}

// ================= fused leaf iou + XWf (independent fx-consumers, one launch) =================
__global__ __launch_bounds__(256,2)
void k_leafxwf(const f16* __restrict__ fx, const f16* __restrict__ WilL,
               const float* __restrict__ bias, f16* __restrict__ h16,
               float* __restrict__ cbuf,
               const f16* __restrict__ Wfc, float* __restrict__ XWf,
               int nbLeaf, int Mtot)
{
  extern __shared__ char sm[];
  const int tid=threadIdx.x;
  const int w=tid>>6, lane=tid&63;
  const int lr=lane&15, lg=lane>>4;
  const unsigned swz=8u*((unsigned)(lane&7)^(unsigned)(lane>>3));

  if((int)blockIdx.x < nbLeaf){
    // ---------- leaf iou: 128 x 192, K=768, NT=12 ----------
    char* Abase=sm;
    char* Bbase=sm+32768;
    int x, my;
    xcd_map(blockIdx.x, nbLeaf, 8, x, my);
    const int m0=my*128;
    const int NT=12;

    unsigned fofs[4];
    #pragma unroll
    for(int i=0;i<4;++i){
      int r=w*32+i*8+(lane>>3);
      int m=m0+r;
      int t_=m>>10, j=m-(t_<<10);
      fofs[i]=(unsigned)(((size_t)t_*NPT+j)*768);
    }
    unsigned bofs[6];
    #pragma unroll
    for(int i=0;i<6;++i){
      int r=x*192+w*48+i*8+(lane>>3);
      bofs[i]=(unsigned)r*768u;
    }

    f32x4 acc[4][6];
    #pragma unroll
    for(int mi=0;mi<4;++mi)
      #pragma unroll
      for(int ni=0;ni<6;++ni) acc[mi][ni]=(f32x4){0.f,0.f,0.f,0.f};

    const int wr=(w>>1)*64;
    const int wcF=(w&1)*6;

    auto STAGE=[&](int buf, int t){
      const unsigned kofs=(unsigned)t*64u+swz;
      char* Ad=Abase+(size_t)buf*16384;
      #pragma unroll
      for(int i=0;i<4;++i)
        gll16(fx+fofs[i]+kofs, Ad+(w*32+i*8)*128);
      char* Bd=Bbase+(size_t)buf*24576;
      #pragma unroll
      for(int i=0;i<6;++i)
        gll16(WilL+bofs[i]+kofs, Bd+(w*48+i*8)*128);
    };

    auto COMPUTE=[&](int cur){
      const char* Ab=Abase+(size_t)cur*16384;
      const char* Bb=Bbase+(size_t)cur*24576;
      #pragma unroll
      for(int ks=0;ks<2;++ks){
        const unsigned cb=((unsigned)(ks*64+lg*16)) ^ ((unsigned)(lr&7)<<4);
        f16x8 av[4], bv[6];
        #pragma unroll
        for(int mi=0;mi<4;++mi)
          av[mi]=*(const f16x8*)(Ab+(unsigned)(wr+mi*16+lr)*128u+cb);
        #pragma unroll
        for(int ni=0;ni<6;++ni)
          bv[ni]=*(const f16x8*)(Bb+(unsigned)((wcF+ni)*16+lr)*128u+cb);
        __builtin_amdgcn_s_setprio(1);
        #pragma unroll
        for(int ni=0;ni<6;++ni)
          #pragma unroll
          for(int mi=0;mi<4;++mi)
            acc[mi][ni]=__builtin_amdgcn_mfma_f32_16x16x32_f16(av[mi],bv[ni],acc[mi][ni],0,0,0);
        __builtin_amdgcn_s_setprio(0);
      }
    };

    STAGE(0,0);
    STAGE(1,1);
    asm volatile("s_waitcnt vmcnt(10)" ::: "memory");
    __builtin_amdgcn_s_barrier();
    __builtin_amdgcn_sched_barrier(0);

    for(int t=0;t<NT;++t){
      COMPUTE(t&1);
      if(t+1<NT){
        __builtin_amdgcn_sched_barrier(0);
        __builtin_amdgcn_s_barrier();
        __builtin_amdgcn_sched_barrier(0);
        if(t+2<NT){
          STAGE(t&1, t+2);
          asm volatile("s_waitcnt vmcnt(10)" ::: "memory");
        }else{
          asm volatile("s_waitcnt vmcnt(0)" ::: "memory");
        }
        __builtin_amdgcn_s_barrier();
        __builtin_amdgcn_sched_barrier(0);
      }
    }

    #pragma unroll
    for(int mi=0;mi<4;++mi){
      #pragma unroll
      for(int cg=0;cg<2;++cg){
        const int col = x*64 + ((w&1)*2+cg)*16 + lr;
        const float bi=bias[col], bo=bias[col+512], bu=bias[col+1024];
        #pragma unroll
        for(int r=0;r<4;++r){
          const int mm=m0+wr+mi*16+lg*4+r;
          float iv=acc[mi][3*cg+0][r]+bi;
          float ov=acc[mi][3*cg+1][r]+bo;
          float uv=acc[mi][3*cg+2][r]+bu;
          float cn=sigm(iv)*ftanh(uv);
          float hn=sigm(ov)*ftanh(cn);
          const int tt=mm>>10, jj=mm-(tt<<10);
          const size_t nd=((size_t)tt*NPT+jj)*HD+col;
          cbuf[nd]=cn;
          h16[nd]=(f16)hn;
        }
      }
    }
  } else {
    // ---------- XWf: 128x128, K=768, NT=12 ----------
    char* Abase=sm;
    char* Bbase=sm+32768;
    int phys=(int)blockIdx.x-nbLeaf;
    int nb=(int)gridDim.x-nbLeaf;
    int xb, my;
    xcd_map(phys, nb, 4, xb, my);
    const int m0=my*128, n0=xb*128;
    const int NT=12;

    unsigned fofs[4];
    #pragma unroll
    for(int i=0;i<4;++i){
      int r=w*32+i*8+(lane>>3);
      int m=m0+r; if(m>=Mtot) m=Mtot-1;
      int t=m/NINT; int j=1024+(m-t*NINT);
      fofs[i]=(unsigned)(((size_t)t*NPT+j)*768);
    }
    unsigned bofs[4];
    #pragma unroll
    for(int i=0;i<4;++i){
      int r=n0+w*32+i*8+(lane>>3);
      bofs[i]=(unsigned)r*768u;
    }

    f32x4 acc[4][4];
    #pragma unroll
    for(int mi=0;mi<4;++mi)
      #pragma unroll
      for(int ni=0;ni<4;++ni) acc[mi][ni]=(f32x4){0.f,0.f,0.f,0.f};

    const int wr=(w>>1)*64, wc=(w&1)*64;

    auto STAGE=[&](int buf, int t){
      const unsigned ak=(unsigned)t*64u+swz;
      char* Ad=Abase+(size_t)buf*16384;
      #pragma unroll
      for(int i=0;i<4;++i)
        gll16(fx+fofs[i]+ak, Ad+(w*32+i*8)*128);
      char* Bd=Bbase+(size_t)buf*16384;
      #pragma unroll
      for(int i=0;i<4;++i)
        gll16(Wfc+bofs[i]+ak, Bd+(w*32+i*8)*128);
    };

    auto COMPUTE=[&](int cur){
      const char* Ab=Abase+(size_t)cur*16384;
      const char* Bb=Bbase+(size_t)cur*16384;
      #pragma unroll
      for(int ks=0;ks<2;++ks){
        const unsigned cb=((unsigned)(ks*64+lg*16)) ^ ((unsigned)(lr&7)<<4);
        f16x8 av[4], bv[4];
        #pragma unroll
        for(int mi=0;mi<4;++mi)
          av[mi]=*(const f16x8*)(Ab+(unsigned)(wr+mi*16+lr)*128u+cb);
        #pragma unroll
        for(int ni=0;ni<4;++ni)
          bv[ni]=*(const f16x8*)(Bb+(unsigned)((wc+ni*16)+lr)*128u+cb);
        __builtin_amdgcn_s_setprio(1);
        #pragma unroll
        for(int ni=0;ni<4;++ni)
          #pragma unroll
          for(int mi=0;mi<4;++mi)
            acc[mi][ni]=__builtin_amdgcn_mfma_f32_16x16x32_f16(av[mi],bv[ni],acc[mi][ni],0,0,0);
        __builtin_amdgcn_s_setprio(0);
      }
    };

    STAGE(0,0);
    STAGE(1,1);
    asm volatile("s_waitcnt vmcnt(8)" ::: "memory");
    __builtin_amdgcn_s_barrier();
    __builtin_amdgcn_sched_barrier(0);

    for(int t=0;t<NT;++t){
      COMPUTE(t&1);
      if(t+1<NT){
        __builtin_amdgcn_sched_barrier(0);
        __builtin_amdgcn_s_barrier();
        __builtin_amdgcn_sched_barrier(0);
        if(t+2<NT){
          STAGE(t&1, t+2);
          asm volatile("s_waitcnt vmcnt(8)" ::: "memory");
        }else{
          asm volatile("s_waitcnt vmcnt(0)" ::: "memory");
        }
        __builtin_amdgcn_s_barrier();
        __builtin_amdgcn_sched_barrier(0);
      }
    }

    #pragma unroll
    for(int mi=0;mi<4;++mi){
      #pragma unroll
      for(int ni=0;ni<4;++ni){
        const int col=n0+wc+ni*16+lr;
        #pragma unroll
        for(int r=0;r<4;++r){
          const int mm=m0+wr+mi*16+lg*4+r;
          if(mm<Mtot) XWf[(size_t)mm*512+col]=acc[mi][ni][r];
        }
      }
    }
  }
}

// ================= internal iou GEMM: 128 x 192, f16, XCD-chunked =================
__global__ __launch_bounds__(256,2)
void k_iou128p(const f16* __restrict__ fx, const f16* __restrict__ hs16,
               const f16* __restrict__ Wil, const float* __restrict__ bias,
               const float* __restrict__ csum, f16* __restrict__ h16,
               float* __restrict__ cbuf,
               int start_n, int shift)
{
  extern __shared__ char sm[];                 // A: 2x16384, B: 2x24576
  char* Abase=sm;
  char* Bbase=sm+32768;
  const int tid=threadIdx.x;
  const int w=tid>>6, lane=tid&63;
  int x, my;
  xcd_map(blockIdx.x, gridDim.x, 8, x, my);
  const int m0=my*128;
  const int K=1280;
  const int NT=20;

  unsigned fofs[4], hofs[4];
  #pragma unroll
  for(int i=0;i<4;++i){
    int r=w*32+i*8+(lane>>3);
    int m=m0+r;
    int t_=m>>shift, j=m-(t_<<shift);
    fofs[i]=(unsigned)(((size_t)t_*NPT+start_n+j)*768);
    hofs[i]=(unsigned)m*512u;
  }
  unsigned bofs[6];
  #pragma unroll
  for(int i=0;i<6;++i){
    int r=x*192+w*48+i*8+(lane>>3);
    bofs[i]=(unsigned)r*(unsigned)K;
  }
  const unsigned swz=8u*((unsigned)(lane&7)^(unsigned)(lane>>3));

  f32x4 acc[4][6];
  #pragma unroll
  for(int mi=0;mi<4;++mi)
    #pragma unroll
    for(int ni=0;ni<6;++ni) acc[mi][ni]=(f32x4){0.f,0.f,0.f,0.f};

  const int wr=(w>>1)*64;
  const int wcF=(w&1)*6;
  const int lr=lane&15, lg=lane>>4;

  auto STAGE=[&](int buf, int t){
    const f16* base; int kt; bool useF;
    if(t<12){ base=fx;   kt=t;    useF=true;  }
    else    { base=hs16; kt=t-12; useF=false; }
    const unsigned kofs=(unsigned)kt*64u+swz;
    char* Ad=Abase+(size_t)buf*16384;
    #pragma unroll
    for(int i=0;i<4;++i){
      const f16* g=base+(useF?fofs[i]:hofs[i])+kofs;
      gll16(g, Ad+(w*32+i*8)*128);
    }
    const unsigned bk=(unsigned)t*64u+swz;
    char* Bd=Bbase+(size_t)buf*24576;
    #pragma unroll
    for(int i=0;i<6;++i){
      gll16(Wil+bofs[i]+bk, Bd+(w*48+i*8)*128);
    }
  };

  auto COMPUTE=[&](int cur){
    const char* Ab=Abase+(size_t)cur*16384;
    const char* Bb=Bbase+(size_t)cur*24576;
    #pragma unroll
    for(int ks=0;ks<2;++ks){
      const unsigned cb=((unsigned)(ks*64+lg*16)) ^ ((unsigned)(lr&7)<<4);
      f16x8 av[4], bv[6];
      #pragma unroll
      for(int mi=0;mi<4;++mi)
        av[mi]=*(const f16x8*)(Ab+(unsigned)(wr+mi*16+lr)*128u+cb);
      #pragma unroll
      for(int ni=0;ni<6;++ni)
        bv[ni]=*(const f16x8*)(Bb+(unsigned)((wcF+ni)*16+lr)*128u+cb);
      __builtin_amdgcn_s_setprio(1);
      #pragma unroll
      for(int ni=0;ni<6;++ni)
        #pragma unroll
        for(int mi=0;mi<4;++mi)
          acc[mi][ni]=__builtin_amdgcn_mfma_f32_16x16x32_f16(av[mi],bv[ni],acc[mi][ni],0,0,0);
      __builtin_amdgcn_s_setprio(0);
    }
  };

  STAGE(0,0);
  STAGE(1,1);
  asm volatile("s_waitcnt vmcnt(10)" ::: "memory");
  __builtin_amdgcn_s_barrier();
  __builtin_amdgcn_sched_barrier(0);

  for(int t=0;t<NT;++t){
    COMPUTE(t&1);
    if(t+1<NT){
      __builtin_amdgcn_sched_barrier(0);
      __builtin_amdgcn_s_barrier();
      __builtin_amdgcn_sched_barrier(0);
      if(t+2<NT){
        STAGE(t&1, t+2);
        asm volatile("s_waitcnt vmcnt(10)" ::: "memory");
      }else{
        asm volatile("s_waitcnt vmcnt(0)" ::: "memory");
      }
      __builtin_amdgcn_s_barrier();
      __builtin_amdgcn_sched_barrier(0);
    }
  }

  #pragma unroll
  for(int mi=0;mi<4;++mi){
    #pragma unroll
    for(int cg=0;cg<2;++cg){
      const int col = x*64 + ((w&1)*2+cg)*16 + lr;
      const float bi=bias[col], bo=bias[col+512], bu=bias[col+1024];
      #pragma unroll
      for(int r=0;r<4;++r){
        const int mm=m0+wr+mi*16+lg*4+r;
        float iv=acc[mi][3*cg+0][r]+bi;
        float ov=acc[mi][3*cg+1][r]+bo;
        float uv=acc[mi][3*cg+2][r]+bu;
        float cn=sigm(iv)*ftanh(uv);
        cn+=csum[(size_t)mm*HD+col];
        float hn=sigm(ov)*ftanh(cn);
        const int tt=mm>>shift, jj=mm-(tt<<shift);
        const size_t nd=((size_t)tt*NPT+start_n+jj)*HD+col;
        cbuf[nd]=cn;
        h16[nd]=(f16)hn;
      }
    }
  }
}

// ---------------- old 64-tile iou (level 5 only, P=64; K=1280 gate-major layout, f16) ----------------
__global__ __launch_bounds__(256)
void k_iou(const f16* __restrict__ fx, const f16* __restrict__ hs16,
           const f16* __restrict__ Wcat, const float* __restrict__ bias,
           const float* __restrict__ csum, f16* __restrict__ h16,
           float* __restrict__ cbuf,
           int start_n, int shift, int K, int KB)
{
  __shared__ f16 As[64][40];
  __shared__ f16 Bs[3][64][40];
  const int tid=threadIdx.x;
  const int m0=blockIdx.x*64, n0=blockIdx.y*64;
  const int srow=tid>>2, skc=(tid&3)*8;
  const int m=m0+srow;
  const int t=m>>shift, j=m-(t<<shift);
  const size_t frow=((size_t)t*NPT+start_n+j)*768;
  const f16* aF=fx+frow;
  const f16* aH=hs16+(size_t)m*HD;
  const f16* bp0=Wcat+(size_t)(n0+srow)*KB;
  const f16* bp1=Wcat+(size_t)(512+n0+srow)*KB;
  const f16* bp2=Wcat+(size_t)(1024+n0+srow)*KB;

  f32x4 acc[3][2][2];
  #pragma unroll
  for(int g=0;g<3;++g)
    #pragma unroll
    for(int mi=0;mi<2;++mi)
      #pragma unroll
      for(int ni=0;ni<2;++ni) acc[g][mi][ni]=(f32x4){0.f,0.f,0.f,0.f};

  const int w=tid>>6, lane=tid&63;
  const int wr=(w>>1)*32, wc=(w&1)*32;
  const int lr=lane&15, lg=lane>>4;

  for(int k0=0;k0<K;k0+=32){
    const f16* ap = (k0<768)? (aF+k0) : (aH+(k0-768));
    *(f16x8*)&As[srow][skc]=*(const f16x8*)(ap+skc);
    *(f16x8*)&Bs[0][srow][skc]=*(const f16x8*)(bp0+k0+skc);
    *(f16x8*)&Bs[1][srow][skc]=*(const f16x8*)(bp1+k0+skc);
    *(f16x8*)&Bs[2][srow][skc]=*(const f16x8*)(bp2+k0+skc);
    __syncthreads();
    f16x8 a0=*(f16x8*)&As[wr+lr][lg*8];
    f16x8 a1=*(f16x8*)&As[wr+16+lr][lg*8];
    #pragma unroll
    for(int g=0;g<3;++g){
      #pragma unroll
      for(int ni=0;ni<2;++ni){
        f16x8 bv=*(f16x8*)&Bs[g][wc+ni*16+lr][lg*8];
        acc[g][0][ni]=__builtin_amdgcn_mfma_f32_16x16x32_f16(a0,bv,acc[g][0][ni],0,0,0);
        acc[g][1][ni]=__builtin_amdgcn_mfma_f32_16x16x32_f16(a1,bv,acc[g][1][ni],0,0,0);
      }
    }
    __syncthreads();
  }

  #pragma unroll
  for(int mi=0;mi<2;++mi){
    #pragma unroll
    for(int ni=0;ni<2;++ni){
      const int col=n0+wc+ni*16+lr;
      const float bi=bias[col], bo=bias[col+512], bu=bias[col+1024];
      #pragma unroll
      for(int r=0;r<4;++r){
        const int mm=m0+wr+mi*16+lg*4+r;
        float iv=acc[0][mi][ni][r]+bi;
        float ov=acc[1][mi][ni][r]+bo;
        float uv=acc[2][mi][ni][r]+bu;
        float cn=sigm(iv)*ftanh(uv);
        cn+=csum[(size_t)mm*HD+col];
        float hn=sigm(ov)*ftanh(cn);
        const int tt=mm>>shift, jj=mm-(tt<<shift);
        const size_t nd=((size_t)tt*NPT+start_n+jj)*HD+col;
        cbuf[nd]=cn;
        h16[nd]=(f16)hn;
      }
    }
  }
}

// ================= Uh forget-gate: pipelined 128x128 (NT=8, f16) + fused csum/hsum =================
__global__ __launch_bounds__(256,2)
void k_uh128p(const f16* __restrict__ h16,
              const f16* __restrict__ Ufc, const float* __restrict__ bias,
              const float* __restrict__ XWf, const float* __restrict__ cbuf,
              float* __restrict__ csum, f16* __restrict__ hs16,
              int start_ch, int lc, int xwoff)
{
  extern __shared__ char sm[];     // A: 2x16384, B: 2x16384
  char* Abase=sm;
  char* Bbase=sm+32768;
  const int tid=threadIdx.x;
  const int w=tid>>6, lane=tid&63;
  int xb, my;
  xcd_map(blockIdx.x, gridDim.x, 4, xb, my);
  const int e0=my*128, n0=xb*128;
  const int NT=8;

  unsigned hofs[4];
  #pragma unroll
  for(int i=0;i<4;++i){
    int r=w*32+i*8+(lane>>3);
    int e=e0+r;
    int t=e>>lc, ei=e-(t<<lc);
    hofs[i]=(unsigned)(((size_t)t*NPT+start_ch+ei)*HD);
  }
  unsigned bofs[4];
  #pragma unroll
  for(int i=0;i<4;++i){
    int r=n0+w*32+i*8+(lane>>3);
    bofs[i]=(unsigned)r*512u;
  }
  const unsigned swz=8u*((unsigned)(lane&7)^(unsigned)(lane>>3));

  f32x4 acc[4][4];
  #pragma unroll
  for(int mi=0;mi<4;++mi)
    #pragma unroll
    for(int ni=0;ni<4;++ni) acc[mi][ni]=(f32x4){0.f,0.f,0.f,0.f};

  const int wr=(w>>1)*64, wc=(w&1)*64;
  const int lr=lane&15, lg=lane>>4;

  auto STAGE=[&](int buf, int t){
    const unsigned ak=(unsigned)t*64u+swz;
    char* Ad=Abase+(size_t)buf*16384;
    #pragma unroll
    for(int i=0;i<4;++i)
      gll16(h16+hofs[i]+ak, Ad+(w*32+i*8)*128);
    char* Bd=Bbase+(size_t)buf*16384;
    #pragma unroll
    for(int i=0;i<4;++i)
      gll16(Ufc+bofs[i]+ak, Bd+(w*32+i*8)*128);
  };

  auto COMPUTE=[&](int cur){
    const char* Ab=Abase+(size_t)cur*16384;
    const char* Bb=Bbase+(size_t)cur*16384;
    #pragma unroll
    for(int ks=0;ks<2;++ks){
      const unsigned cb=((unsigned)(ks*64+lg*16)) ^ ((unsigned)(lr&7)<<4);
      f16x8 av[4], bv[4];
      #pragma unroll
      for(int mi=0;mi<4;++mi)
        av[mi]=*(const f16x8*)(Ab+(unsigned)(wr+mi*16+lr)*128u+cb);
      #pragma unroll
      for(int ni=0;ni<4;++ni)
        bv[ni]=*(const f16x8*)(Bb+(unsigned)((wc+ni*16)+lr)*128u+cb);
      __builtin_amdgcn_s_setprio(1);
      #pragma unroll
      for(int ni=0;ni<4;++ni)
        #pragma unroll
        for(int mi=0;mi<4;++mi)
          acc[mi][ni]=__builtin_amdgcn_mfma_f32_16x16x32_f16(av[mi],bv[ni],acc[mi][ni],0,0,0);
      __builtin_amdgcn_s_setprio(0);
    }
  };

  STAGE(0,0);
  STAGE(1,1);
  asm volatile("s_waitcnt vmcnt(8)" ::: "memory");
  __builtin_amdgcn_s_barrier();
  __builtin_amdgcn_sched_barrier(0);

  for(int t=0;t<NT;++t){
    COMPUTE(t&1);
    if(t+1<NT){
      __builtin_amdgcn_sched_barrier(0);
      __builtin_amdgcn_s_barrier();
      __builtin_amdgcn_sched_barrier(0);
      if(t+2<NT){
        STAGE(t&1, t+2);
        asm volatile("s_waitcnt vmcnt(8)" ::: "memory");
      }else{
        asm volatile("s_waitcnt vmcnt(0)" ::: "memory");
      }
      __builtin_amdgcn_s_barrier();
      __builtin_amdgcn_sched_barrier(0);
    }
  }

  #pragma unroll
  for(int mi=0;mi<4;++mi){
    const int ebase=e0+wr+mi*16+lg*4;
    const int tt=ebase>>lc, eib=ebase-(tt<<lc);
    const int inode=tt*NINT + xwoff + (eib>>2);
    const int par=ebase>>2;
    #pragma unroll
    for(int ni=0;ni<4;++ni){
      const int col=n0+wc+ni*16+lr;
      const float base=bias[col]+XWf[(size_t)inode*512+col];
      const size_t chbase=((size_t)tt*NPT+start_ch+eib)*HD+col;
      float s=0.f, hsv=0.f;
      #pragma unroll
      for(int r=0;r<4;++r){
        const size_t ci=chbase+(size_t)r*HD;
        float fv=sigm(acc[mi][ni][r]+base);
        s+=fv*cbuf[ci];
        hsv+=(float)h16[ci];
      }
      csum[(size_t)par*HD+col]=s;
      hs16[(size_t)par*HD+col]=(f16)hsv;
    }
  }
}

// ---------------- final heads: h_st softmax (+root blocks appended) ----------------
__global__ __launch_bounds__(256)
void k_final2(const f16* __restrict__ h16,
              const float* __restrict__ Wy, const float* __restrict__ gamma,
              const float* __restrict__ beta, float* __restrict__ out0,
              const float* __restrict__ Wff, float* __restrict__ out1,
              int Nn, int nbMain)
{
  const int tid=threadIdx.x;
  if((int)blockIdx.x < nbMain){
    const int gtid=blockIdx.x*256+tid;
    const int node=gtid>>6, lane=gtid&63;
    if(node>=Nn) return;
    const size_t base=(size_t)node*HD+lane*8;
    f16x8 hv=*(const f16x8*)(h16+base);
    float hf[8];
    #pragma unroll
    for(int e=0;e<8;++e) hf[e]=(float)hv[e];
    float y[4];
    #pragma unroll
    for(int jj=0;jj<4;++jj){
      const float* wp=Wy+jj*HD+lane*8;
      float s=0.f;
      #pragma unroll
      for(int e=0;e<8;++e) s+=hf[e]*wp[e];
      #pragma unroll
      for(int off=32;off>=1;off>>=1) s+=__shfl_xor(s,off,64);
      y[jj]=s;
    }
    if(lane==0){
      float mu=0.25f*(y[0]+y[1]+y[2]+y[3]);
      float var=0.f;
      #pragma unroll
      for(int jj=0;jj<4;++jj){ float d=y[jj]-mu; var+=d*d; }
      var*=0.25f;
      float rs=rsqrtf(var+1e-6f);
      float z[4], zmax=-1e30f;
      #pragma unroll
      for(int jj=0;jj<4;++jj){ z[jj]=(y[jj]-mu)*rs*gamma[jj]+beta[jj]; zmax=fmaxf(zmax,z[jj]); }
      float es=0.f;
      #pragma unroll
      for(int jj=0;jj<4;++jj){ z[jj]=__expf(z[jj]-zmax); es+=z[jj]; }
      float inv=frcp(es);
      #pragma unroll
      for(int jj=0;jj<4;++jj) out0[(size_t)node*4+jj]=z[jj]*inv;
    }
  } else {
    const int gtid=((int)blockIdx.x-nbMain)*256+tid;
    const int tt=gtid>>6, lane=gtid&63;
    if(tt>=64) return;
    const size_t base=((size_t)tt*NPT+1364)*HD+lane*8;
    f16x8 hv=*(const f16x8*)(h16+base);
    float hf[8];
    #pragma unroll
    for(int e=0;e<8;++e) hf[e]=(float)hv[e];
    float y[4];
    #pragma unroll
    for(int jj=0;jj<4;++jj){
      const float* wp=Wff+jj*HD+lane*8;
      float s=0.f;
      #pragma unroll
      for(int e=0;e<8;++e) s+=hf[e]*wp[e];
      #pragma unroll
      for(int off=32;off>=1;off>>=1) s+=__shfl_xor(s,off,64);
      y[jj]=s;
    }
    if(lane==0){
      float zmax=fmaxf(fmaxf(y[0],y[1]),fmaxf(y[2],y[3]));
      float es=0.f, z[4];
      #pragma unroll
      for(int jj=0;jj<4;++jj){ z[jj]=__expf(y[jj]-zmax); es+=z[jj]; }
      float inv=frcp(es);
      #pragma unroll
      for(int jj=0;jj<4;++jj) out1[(size_t)tt*4+jj]=z[jj]*inv;
    }
  }
}

extern "C" void kernel_launch(void* const* d_in, const int* in_sizes, int n_in,
                              void* d_out, int out_size, void* d_ws, size_t ws_size,
                              hipStream_t stream)
{
  const float* features=(const float*)d_in[0];
  const float* W_iou=(const float*)d_in[6];
  const float* b_iou=(const float*)d_in[7];
  const float* U_iou=(const float*)d_in[8];
  const float* W_f  =(const float*)d_in[9];
  const float* b_f  =(const float*)d_in[10];
  const float* U_f  =(const float*)d_in[11];
  const float* W_ff =(const float*)d_in[12];
  const float* W_sd =(const float*)d_in[13];
  const float* W_sd2=(const float*)d_in[14];
  const float* W_sf =(const float*)d_in[15];
  const float* ln_g =(const float*)d_in[16];
  const float* ln_b =(const float*)d_in[17];

  const int N=in_sizes[0]/768;   // 87360
  const int T=N/NPT;             // 64
  const int MINT=T*NINT;         // 21824

  float* out0=(float*)d_out;
  float* out1=out0+(size_t)N*4;
  float* cbuf=out1+(size_t)T*4;  // c output region (live c-state)

  char* p=(char*)d_ws;
  auto alloc=[&](size_t bytes){ char* r=p; p+=((bytes+255)&~(size_t)255); return r; };
  f16*   fx   =(f16*)  alloc((size_t)N*768*2);
  f16*   hs16 =(f16*)  alloc((size_t)16384*HD*2);
  float* csum =(float*)alloc((size_t)16384*HD*4);
  f16*   h16  =(f16*)  alloc((size_t)N*HD*2);
  f16*   WilL =(f16*)  alloc((size_t)1536*768*2);
  f16*   WilI =(f16*)  alloc((size_t)1536*1280*2);
  f16*   Wcat2=(f16*)  alloc((size_t)1536*1280*2);   // level-5 64-tile layout
  f16*   Wfc  =(f16*)  alloc((size_t)512*768*2);
  f16*   Ufc  =(f16*)  alloc((size_t)512*512*2);
  float* tmp4 =(float*)alloc((size_t)4*1024*4);
  float* Wy   =(float*)alloc((size_t)4*512*4);
  float* XWf  =(float*)alloc((size_t)MINT*512*4);

  // fused prep (all elementwise conversions + tmp4), then Wy
  {
    size_t nfeat8=(size_t)N*768/8;
    size_t tot=nfeat8+(size_t)1536*768+(size_t)1536*1280*2+(size_t)512*768/8+(size_t)512*512/8+4096;
    int nb=(int)((tot+255)/256);
    k_prep<<<nb,256,0,stream>>>(features,W_iou,U_iou,W_f,U_f,W_sf,W_sd2,
                                fx,WilL,WilI,Wcat2,Wfc,Ufc,tmp4,nfeat8);
  }
  { k_wy2<<<8,256,0,stream>>>(W_sf,tmp4,W_sd,Wy); }

  static const int starts[6]={0,1024,1280,1344,1360,1364};
  static const int csh[6]  ={10,8,6,4,2,0};
  static const int counts[6]={1024,256,64,16,4,1};
  static const int xwoffs[6]={0,0,256,320,336,340};

  // fused leaf iou + XWf (independent, one launch)
  {
    int nbLeaf=8*((T*1024)/128);             // 4096
    int nbXwf=4*((MINT+127)/128);            // 684
    k_leafxwf<<<nbLeaf+nbXwf,256,IOU_LDS,stream>>>(fx,WilL,b_iou,h16,cbuf,Wfc,XWf,nbLeaf,MINT);
  }

  for(int n=1;n<6;++n){
    int P=T*counts[n], E=T*counts[n-1];
    { int nb=4*(E/128);
      k_uh128p<<<nb,256,G128_LDS,stream>>>(h16,Ufc,b_f,XWf,cbuf,csum,hs16,
                                           starts[n-1],csh[n-1],xwoffs[n]); }
    if(P>=128){
      int nb=8*(P/128);
      k_iou128p<<<nb,256,IOU_LDS,stream>>>(fx,hs16,WilI,b_iou,csum,h16,cbuf,starts[n],csh[n]);
    }else{
      dim3 g(P/64,8);
      k_iou<<<g,256,0,stream>>>(fx,hs16,Wcat2,b_iou,csum,h16,cbuf,starts[n],csh[n],1280,1280);
    }
  }

  // heads (stance folded into Wy; root appended to final2 launch)
  {
    int nbMain=(N*64+255)/256;
    k_final2<<<nbMain+16,256,0,stream>>>(h16,Wy,ln_g,ln_b,out0,W_ff,out1,N,nbMain);
  }
}